// Round 1
// baseline (3551.263 us; speedup 1.0000x reference)
//
#include <hip/hip_runtime.h>
#include <math.h>

#define LQ 24480

// ---------------------------------------------------------------------------
// Generic f32 GEMM: C[M,N] = (A (+A2)) @ W^T + bias, optional ReLU.
// A: [M,K] row-major, W: [N,K] row-major. N%64==0, K%16==0 guaranteed here.
// Block 16x16 threads, 64x64 tile, 4x4 per thread, K-chunk 16.
// ---------------------------------------------------------------------------
template <int RELU>
__global__ __launch_bounds__(256) void gemm_f32(
    const float* __restrict__ A, const float* __restrict__ A2,
    const float* __restrict__ W, const float* __restrict__ bias,
    float* __restrict__ C, int M, int N, int K)
{
    __shared__ float As[64][17];
    __shared__ float Ws[64][17];
    const int tid = threadIdx.y * 16 + threadIdx.x;
    const int row0 = blockIdx.y * 64;
    const int col0 = blockIdx.x * 64;
    float acc[4][4] = {};

    for (int kk = 0; kk < K; kk += 16) {
#pragma unroll
        for (int i = 0; i < 4; ++i) {
            int idx = tid + i * 256;       // 0..1023
            int r = idx >> 4, cc = idx & 15;
            int gr = row0 + r;
            float av = 0.f;
            if (gr < M) {
                av = A[(size_t)gr * K + kk + cc];
                if (A2) av += A2[(size_t)gr * K + kk + cc];
            }
            As[r][cc] = av;
            Ws[r][cc] = W[(size_t)(col0 + r) * K + kk + cc];
        }
        __syncthreads();
#pragma unroll
        for (int k = 0; k < 16; ++k) {
            float a[4], w[4];
#pragma unroll
            for (int i = 0; i < 4; ++i) a[i] = As[threadIdx.y * 4 + i][k];
#pragma unroll
            for (int j = 0; j < 4; ++j) w[j] = Ws[threadIdx.x * 4 + j][k];
#pragma unroll
            for (int i = 0; i < 4; ++i)
#pragma unroll
                for (int j = 0; j < 4; ++j) acc[i][j] += a[i] * w[j];
        }
        __syncthreads();
    }

#pragma unroll
    for (int i = 0; i < 4; ++i) {
        int gr = row0 + threadIdx.y * 4 + i;
        if (gr >= M) break;
#pragma unroll
        for (int j = 0; j < 4; ++j) {
            int gc = col0 + threadIdx.x * 4 + j;
            float v = acc[i][j] + bias[gc];
            if (RELU) v = fmaxf(v, 0.f);
            C[(size_t)gr * N + gc] = v;
        }
    }
}

// ---------------------------------------------------------------------------
// Deformable attention core. One block per query; 8 heads x 32 channels.
// Computes softmax over 56 logits per head (wave-parallel), sampling
// locations from samp/tsamp + analytic reference points, bilinear gathers
// from value, accumulates 32-ch output per head.
// ---------------------------------------------------------------------------
__global__ __launch_bounds__(256) void deform_kernel(
    const float* __restrict__ value,   // [LQ,256] = [LQ,8,32]
    const float* __restrict__ samp,    // [LQ,256] = [LQ,8,4,4,2]
    const float* __restrict__ tsamp,   // [LQ,640] = [LQ,8,4,5,2,2]
    const float* __restrict__ logits,  // [LQ,448] = [LQ,8,56]
    const float* __restrict__ vr,      // [4,2] valid_ratios (x,y)
    float* __restrict__ o)             // [LQ,256]
{
    const int q = blockIdx.x;
    const int h = threadIdx.x >> 5;
    const int c = threadIdx.x & 31;

    const int lsiA[4] = {0, 18432, 23040, 24192};

    // query level geometry (W=64>>l, H=48>>l, Ht=6*H)
    int lq = (q >= 24192) ? 3 : (q >= 23040) ? 2 : (q >= 18432) ? 1 : 0;
    int qi = q - lsiA[lq];
    int Wq = 64 >> lq;
    int i = qi >> (6 - lq);        // qi / Wq
    int j = qi & (Wq - 1);
    int Hq = 48 >> lq;
    int tq = i / Hq;               // frame index 0..5
    float rx_base = ((float)j + 0.5f) / (vr[2 * lq + 0] * (float)Wq);
    float ry_base = ((float)i + 0.5f) / (vr[2 * lq + 1] * (float)(Hq * 6));

    // ---- softmax over 56 logits per head (32-lane group) ----
    __shared__ float aw_s[8][56];
    const float* lg = logits + (size_t)q * 448 + h * 56;
    float l0 = lg[c];
    float l1 = (c < 24) ? lg[32 + c] : -1e30f;
    float m = fmaxf(l0, l1);
#pragma unroll
    for (int off = 16; off; off >>= 1) m = fmaxf(m, __shfl_xor(m, off, 32));
    float e0 = expf(l0 - m);
    float e1 = (c < 24) ? expf(l1 - m) : 0.f;
    float s = e0 + e1;
#pragma unroll
    for (int off = 16; off; off >>= 1) s += __shfl_xor(s, off, 32);
    float inv = 1.f / s;
    aw_s[h][c] = e0 * inv;
    if (c < 24) aw_s[h][32 + c] = e1 * inv;
    __syncthreads();

    const float* sp = samp + (size_t)q * 256 + h * 32;
    const float* tp = tsamp + (size_t)q * 640 + h * 80;

    float acc = 0.f;
#pragma unroll
    for (int l = 0; l < 4; ++l) {
        const int Wl = 64 >> l;
        const int Htl = (48 >> l) * 6;
        const int sl = lsiA[l];
        const float vrx = vr[2 * l], vry = vr[2 * l + 1];
        const float lxr = rx_base * vrx, lyr = ry_base * vry;
        const float invW = 1.f / (float)Wl, invHt = 1.f / (float)Htl;
        const float* vbase = value + (size_t)sl * 256 + h * 32 + c;

#pragma unroll
        for (int p = 0; p < 14; ++p) {
            float ox, oy, toy;
            if (p < 4) {
                ox = sp[l * 8 + p * 2];
                oy = sp[l * 8 + p * 2 + 1];
                toy = 0.f;
            } else {
                int pp = p - 4;
                int tw = pp >> 1, nt = pp & 1;
                int tt = (tw < tq) ? tw : tw + 1;
                toy = (float)(tt - tq) * (1.f / 6.f) * vry;
                ox = tp[l * 20 + tw * 4 + nt * 2];
                oy = tp[l * 20 + tw * 4 + nt * 2 + 1];
            }
            float lx = lxr + ox * invW;
            float ly = lyr + toy + oy * invHt;
            // grid-sample coords (align_corners=False)
            float x = lx * (float)Wl - 0.5f;
            float y = ly * (float)Htl - 0.5f;
            float x0f = floorf(x), y0f = floorf(y);
            int x0 = (int)x0f, y0 = (int)y0f;
            float fx = x - x0f, fy = y - y0f;
            float w00 = (1.f - fx) * (1.f - fy);
            float w10 = fx * (1.f - fy);
            float w01 = (1.f - fx) * fy;
            float w11 = fx * fy;
            bool xin0 = (x0 >= 0) && (x0 < Wl);
            bool xin1 = (x0 + 1 >= 0) && (x0 + 1 < Wl);
            bool yin0 = (y0 >= 0) && (y0 < Htl);
            bool yin1 = (y0 + 1 >= 0) && (y0 + 1 < Htl);
            float r = 0.f;
            if (yin0) {
                const float* rowp = vbase + (size_t)(y0 * Wl) * 256;
                if (xin0) r += w00 * rowp[(size_t)x0 * 256];
                if (xin1) r += w10 * rowp[(size_t)(x0 + 1) * 256];
            }
            if (yin1) {
                const float* rowp = vbase + (size_t)((y0 + 1) * Wl) * 256;
                if (xin0) r += w01 * rowp[(size_t)x0 * 256];
                if (xin1) r += w11 * rowp[(size_t)(x0 + 1) * 256];
            }
            acc += aw_s[h][l * 14 + p] * r;
        }
    }
    o[(size_t)q * 256 + h * 32 + c] = acc;
}

// ---------------------------------------------------------------------------
// out = LayerNorm(a + b) * g + be   (rows of 256, one block per row)
// ---------------------------------------------------------------------------
__global__ __launch_bounds__(256) void add_ln(
    const float* __restrict__ a, const float* __restrict__ b,
    const float* __restrict__ g, const float* __restrict__ be,
    float* __restrict__ out)
{
    const int row = blockIdx.x;
    const int t = threadIdx.x;
    float v = a[(size_t)row * 256 + t] + b[(size_t)row * 256 + t];

    __shared__ float red[4];
    float s = v;
#pragma unroll
    for (int off = 32; off; off >>= 1) s += __shfl_xor(s, off, 64);
    int wid = t >> 6;
    if ((t & 63) == 0) red[wid] = s;
    __syncthreads();
    float mean = (red[0] + red[1] + red[2] + red[3]) * (1.f / 256.f);
    float d = v - mean;
    float s2 = d * d;
#pragma unroll
    for (int off = 32; off; off >>= 1) s2 += __shfl_xor(s2, off, 64);
    __syncthreads();
    if ((t & 63) == 0) red[wid] = s2;
    __syncthreads();
    float var = (red[0] + red[1] + red[2] + red[3]) * (1.f / 256.f);
    out[(size_t)row * 256 + t] = d * rsqrtf(var + 1e-5f) * g[t] + be[t];
}

// ---------------------------------------------------------------------------
extern "C" void kernel_launch(void* const* d_in, const int* in_sizes, int n_in,
                              void* d_out, int out_size, void* d_ws, size_t ws_size,
                              hipStream_t stream)
{
    const float* src    = (const float*)d_in[0];
    const float* pos    = (const float*)d_in[1];
    // d_in[2] spatial_shapes, d_in[3] level_start_index: static, hardcoded
    const float* vr     = (const float*)d_in[4];
    const float* W_samp = (const float*)d_in[5];
    const float* b_samp = (const float*)d_in[6];
    const float* W_tsamp= (const float*)d_in[7];
    const float* b_tsamp= (const float*)d_in[8];
    const float* W_attn = (const float*)d_in[9];
    const float* b_attn = (const float*)d_in[10];
    const float* W_val  = (const float*)d_in[11];
    const float* b_val  = (const float*)d_in[12];
    const float* W_out  = (const float*)d_in[13];
    const float* b_out  = (const float*)d_in[14];
    const float* W_ff1  = (const float*)d_in[15];
    const float* b_ff1  = (const float*)d_in[16];
    const float* W_ff2  = (const float*)d_in[17];
    const float* b_ff2  = (const float*)d_in[18];
    const float* n1g    = (const float*)d_in[19];
    const float* n1b    = (const float*)d_in[20];
    const float* n2g    = (const float*)d_in[21];
    const float* n2b    = (const float*)d_in[22];

    float* ws = (float*)d_ws;
    float* valueB = ws;                                 // LQ*256
    float* sampB  = valueB + (size_t)LQ * 256;          // LQ*256
    float* tsampB = sampB  + (size_t)LQ * 256;          // LQ*640
    float* attnB  = tsampB + (size_t)LQ * 640;          // LQ*448
    float* oB     = attnB  + (size_t)LQ * 448;          // LQ*256
    // region reuse after deform:
    float* src2B = valueB;   // value dead after deform
    float* xB    = sampB;    // samp dead after deform
    float* hB    = tsampB;   // LQ*1024 fits in tsamp+attn (LQ*1088)
    float* ffB   = oB;       // o dead after out-proj

    dim3 blk(16, 16);
    auto grd = [](int M, int N) { return dim3(N / 64, (M + 63) / 64); };

    // projections
    gemm_f32<0><<<grd(LQ, 256),  blk, 0, stream>>>(src, nullptr, W_val,   b_val,   valueB, LQ, 256,  256);
    gemm_f32<0><<<grd(LQ, 256),  blk, 0, stream>>>(src, pos,     W_samp,  b_samp,  sampB,  LQ, 256,  256);
    gemm_f32<0><<<grd(LQ, 640),  blk, 0, stream>>>(src, pos,     W_tsamp, b_tsamp, tsampB, LQ, 640,  256);
    gemm_f32<0><<<grd(LQ, 448),  blk, 0, stream>>>(src, pos,     W_attn,  b_attn,  attnB,  LQ, 448,  256);

    // deformable attention
    deform_kernel<<<LQ, 256, 0, stream>>>(valueB, sampB, tsampB, attnB, vr, oB);

    // output proj + residual LN
    gemm_f32<0><<<grd(LQ, 256),  blk, 0, stream>>>(oB, nullptr, W_out, b_out, src2B, LQ, 256, 256);
    add_ln<<<LQ, 256, 0, stream>>>(src, src2B, n1g, n1b, xB);

    // FFN + residual LN
    gemm_f32<1><<<grd(LQ, 1024), blk, 0, stream>>>(xB, nullptr, W_ff1, b_ff1, hB, LQ, 1024, 256);
    gemm_f32<0><<<grd(LQ, 256),  blk, 0, stream>>>(hB, nullptr, W_ff2, b_ff2, ffB, LQ, 256, 1024);
    add_ln<<<LQ, 256, 0, stream>>>(xB, ffB, n2g, n2b, (float*)d_out);
}

// Round 2
// 1798.178 us; speedup vs baseline: 1.9749x; 1.9749x over previous
//
#include <hip/hip_runtime.h>
#include <math.h>

#define LQ 24480

// ---------------------------------------------------------------------------
// Generic f32 GEMM: C[M,N] = (A (+A2)) @ W^T + bias, optional ReLU.
// A: [M,K] row-major, W: [N,K] row-major. N%64==0, K%16==0 guaranteed here.
// Block 16x16 threads, 64x64 tile, 4x4 per thread, K-chunk 16.
// ---------------------------------------------------------------------------
template <int RELU>
__global__ __launch_bounds__(256) void gemm_f32(
    const float* __restrict__ A, const float* __restrict__ A2,
    const float* __restrict__ W, const float* __restrict__ bias,
    float* __restrict__ C, int M, int N, int K)
{
    __shared__ float As[64][17];
    __shared__ float Ws[64][17];
    const int tid = threadIdx.y * 16 + threadIdx.x;
    const int row0 = blockIdx.y * 64;
    const int col0 = blockIdx.x * 64;
    float acc[4][4] = {};

    for (int kk = 0; kk < K; kk += 16) {
#pragma unroll
        for (int i = 0; i < 4; ++i) {
            int idx = tid + i * 256;       // 0..1023
            int r = idx >> 4, cc = idx & 15;
            int gr = row0 + r;
            float av = 0.f;
            if (gr < M) {
                av = A[(size_t)gr * K + kk + cc];
                if (A2) av += A2[(size_t)gr * K + kk + cc];
            }
            As[r][cc] = av;
            Ws[r][cc] = W[(size_t)(col0 + r) * K + kk + cc];
        }
        __syncthreads();
#pragma unroll
        for (int k = 0; k < 16; ++k) {
            float a[4], w[4];
#pragma unroll
            for (int i = 0; i < 4; ++i) a[i] = As[threadIdx.y * 4 + i][k];
#pragma unroll
            for (int j = 0; j < 4; ++j) w[j] = Ws[threadIdx.x * 4 + j][k];
#pragma unroll
            for (int i = 0; i < 4; ++i)
#pragma unroll
                for (int j = 0; j < 4; ++j) acc[i][j] += a[i] * w[j];
        }
        __syncthreads();
    }

#pragma unroll
    for (int i = 0; i < 4; ++i) {
        int gr = row0 + threadIdx.y * 4 + i;
        if (gr >= M) break;
#pragma unroll
        for (int j = 0; j < 4; ++j) {
            int gc = col0 + threadIdx.x * 4 + j;
            float v = acc[i][j] + bias[gc];
            if (RELU) v = fmaxf(v, 0.f);
            C[(size_t)gr * N + gc] = v;
        }
    }
}

// ---------------------------------------------------------------------------
// Deformable attention core. One block per query; 8 heads x 32 channels.
// All bilinear corner loads are UNCONDITIONAL (indices clamped in-range,
// weights zeroed for out-of-bounds corners) so the compiler can batch
// global loads instead of serializing them under divergent branches.
// ---------------------------------------------------------------------------
__global__ __launch_bounds__(256) void deform_kernel(
    const float* __restrict__ value,   // [LQ,256] = [LQ,8,32]
    const float* __restrict__ samp,    // [LQ,256] = [LQ,8,4,4,2]
    const float* __restrict__ tsamp,   // [LQ,640] = [LQ,8,4,5,2,2]
    const float* __restrict__ logits,  // [LQ,448] = [LQ,8,56]
    const float* __restrict__ vr,      // [4,2] valid_ratios (x,y)
    float* __restrict__ o)             // [LQ,256]
{
    const int q = blockIdx.x;
    const int h = threadIdx.x >> 5;
    const int c = threadIdx.x & 31;

    const int lsiA[4] = {0, 18432, 23040, 24192};

    // query level geometry (W=64>>l, H=48>>l, Ht=6*H)
    int lq = (q >= 24192) ? 3 : (q >= 23040) ? 2 : (q >= 18432) ? 1 : 0;
    int qi = q - lsiA[lq];
    int Wq = 64 >> lq;
    int i = qi >> (6 - lq);        // qi / Wq
    int j = qi & (Wq - 1);
    int Hq = 48 >> lq;
    int tq = i / Hq;               // frame index 0..5
    float rx_base = ((float)j + 0.5f) / (vr[2 * lq + 0] * (float)Wq);
    float ry_base = ((float)i + 0.5f) / (vr[2 * lq + 1] * (float)(Hq * 6));

    // ---- softmax over 56 logits per head (32-lane group) ----
    __shared__ float aw_s[8][56];
    const float* lg = logits + (size_t)q * 448 + h * 56;
    float l0 = lg[c];
    float l1 = (c < 24) ? lg[32 + c] : -1e30f;
    float m = fmaxf(l0, l1);
#pragma unroll
    for (int off = 16; off; off >>= 1) m = fmaxf(m, __shfl_xor(m, off, 32));
    float e0 = expf(l0 - m);
    float e1 = (c < 24) ? expf(l1 - m) : 0.f;
    float s = e0 + e1;
#pragma unroll
    for (int off = 16; off; off >>= 1) s += __shfl_xor(s, off, 32);
    float inv = 1.f / s;
    aw_s[h][c] = e0 * inv;
    if (c < 24) aw_s[h][32 + c] = e1 * inv;
    __syncthreads();

    const float* sp = samp + (size_t)q * 256 + h * 32;
    const float* tp = tsamp + (size_t)q * 640 + h * 80;

    float acc = 0.f;
#pragma unroll
    for (int l = 0; l < 4; ++l) {
        const int Wl = 64 >> l;
        const int Hl = 48 >> l;
        const int Htl = Hl * 6;
        const int sl = lsiA[l];
        const float vrx = vr[2 * l], vry = vr[2 * l + 1];
        // grid coords: x = lx*Wl - 0.5 = rx_base*vrx*Wl + ox - 0.5
        const float bx = rx_base * vrx * (float)Wl - 0.5f;
        const float by = ry_base * vry * (float)Htl - 0.5f;
        const float tscale = vry * (float)Hl;   // (tt-tq)/6 * vry * Htl
        const float* vbase = value + (size_t)sl * 256 + h * 32 + c;

#pragma unroll
        for (int p = 0; p < 14; ++p) {
            float ox, oy, ty;
            if (p < 4) {
                ox = sp[l * 8 + p * 2];
                oy = sp[l * 8 + p * 2 + 1];
                ty = 0.f;
            } else {
                int pp = p - 4;
                int tw = pp >> 1, nt = pp & 1;
                int tt = (tw < tq) ? tw : tw + 1;
                ty = (float)(tt - tq) * tscale;
                ox = tp[l * 20 + tw * 4 + nt * 2];
                oy = tp[l * 20 + tw * 4 + nt * 2 + 1];
            }
            float x = bx + ox;
            float y = by + ty + oy;
            float x0f = floorf(x), y0f = floorf(y);
            int x0 = (int)x0f, y0 = (int)y0f;
            float fx = x - x0f, fy = y - y0f;

            // clamped indices (always in-bounds) + zeroed weights for OOB
            int xi0 = min(max(x0, 0), Wl - 1);
            int xi1 = min(max(x0 + 1, 0), Wl - 1);
            int yi0 = min(max(y0, 0), Htl - 1);
            int yi1 = min(max(y0 + 1, 0), Htl - 1);
            float mx0 = (x0 >= 0 && x0 < Wl) ? 1.f : 0.f;
            float mx1 = (x0 >= -1 && x0 + 1 < Wl) ? 1.f : 0.f;
            float my0 = (y0 >= 0 && y0 < Htl) ? 1.f : 0.f;
            float my1 = (y0 >= -1 && y0 + 1 < Htl) ? 1.f : 0.f;
            float gx0 = (1.f - fx) * mx0;
            float gx1 = fx * mx1;
            float gy0 = (1.f - fy) * my0;
            float gy1 = fy * my1;

            const float* r0 = vbase + (size_t)(yi0 * Wl) * 256;
            const float* r1 = vbase + (size_t)(yi1 * Wl) * 256;
            float v00 = r0[(size_t)xi0 * 256];
            float v10 = r0[(size_t)xi1 * 256];
            float v01 = r1[(size_t)xi0 * 256];
            float v11 = r1[(size_t)xi1 * 256];

            float bil = gy0 * (gx0 * v00 + gx1 * v10)
                      + gy1 * (gx0 * v01 + gx1 * v11);
            acc += aw_s[h][l * 14 + p] * bil;
        }
    }
    o[(size_t)q * 256 + h * 32 + c] = acc;
}

// ---------------------------------------------------------------------------
// out = LayerNorm(a + b) * g + be   (rows of 256, one block per row)
// ---------------------------------------------------------------------------
__global__ __launch_bounds__(256) void add_ln(
    const float* __restrict__ a, const float* __restrict__ b,
    const float* __restrict__ g, const float* __restrict__ be,
    float* __restrict__ out)
{
    const int row = blockIdx.x;
    const int t = threadIdx.x;
    float v = a[(size_t)row * 256 + t] + b[(size_t)row * 256 + t];

    __shared__ float red[4];
    float s = v;
#pragma unroll
    for (int off = 32; off; off >>= 1) s += __shfl_xor(s, off, 64);
    int wid = t >> 6;
    if ((t & 63) == 0) red[wid] = s;
    __syncthreads();
    float mean = (red[0] + red[1] + red[2] + red[3]) * (1.f / 256.f);
    float d = v - mean;
    float s2 = d * d;
#pragma unroll
    for (int off = 32; off; off >>= 1) s2 += __shfl_xor(s2, off, 64);
    __syncthreads();
    if ((t & 63) == 0) red[wid] = s2;
    __syncthreads();
    float var = (red[0] + red[1] + red[2] + red[3]) * (1.f / 256.f);
    out[(size_t)row * 256 + t] = d * rsqrtf(var + 1e-5f) * g[t] + be[t];
}

// ---------------------------------------------------------------------------
extern "C" void kernel_launch(void* const* d_in, const int* in_sizes, int n_in,
                              void* d_out, int out_size, void* d_ws, size_t ws_size,
                              hipStream_t stream)
{
    const float* src    = (const float*)d_in[0];
    const float* pos    = (const float*)d_in[1];
    // d_in[2] spatial_shapes, d_in[3] level_start_index: static, hardcoded
    const float* vr     = (const float*)d_in[4];
    const float* W_samp = (const float*)d_in[5];
    const float* b_samp = (const float*)d_in[6];
    const float* W_tsamp= (const float*)d_in[7];
    const float* b_tsamp= (const float*)d_in[8];
    const float* W_attn = (const float*)d_in[9];
    const float* b_attn = (const float*)d_in[10];
    const float* W_val  = (const float*)d_in[11];
    const float* b_val  = (const float*)d_in[12];
    const float* W_out  = (const float*)d_in[13];
    const float* b_out  = (const float*)d_in[14];
    const float* W_ff1  = (const float*)d_in[15];
    const float* b_ff1  = (const float*)d_in[16];
    const float* W_ff2  = (const float*)d_in[17];
    const float* b_ff2  = (const float*)d_in[18];
    const float* n1g    = (const float*)d_in[19];
    const float* n1b    = (const float*)d_in[20];
    const float* n2g    = (const float*)d_in[21];
    const float* n2b    = (const float*)d_in[22];

    float* ws = (float*)d_ws;
    float* valueB = ws;                                 // LQ*256
    float* sampB  = valueB + (size_t)LQ * 256;          // LQ*256
    float* tsampB = sampB  + (size_t)LQ * 256;          // LQ*640
    float* attnB  = tsampB + (size_t)LQ * 640;          // LQ*448
    float* oB     = attnB  + (size_t)LQ * 448;          // LQ*256
    // region reuse after deform:
    float* src2B = valueB;   // value dead after deform
    float* xB    = sampB;    // samp dead after deform
    float* hB    = tsampB;   // LQ*1024 fits in tsamp+attn (LQ*1088)
    float* ffB   = oB;       // o dead after out-proj

    dim3 blk(16, 16);
    auto grd = [](int M, int N) { return dim3(N / 64, (M + 63) / 64); };

    // projections
    gemm_f32<0><<<grd(LQ, 256),  blk, 0, stream>>>(src, nullptr, W_val,   b_val,   valueB, LQ, 256,  256);
    gemm_f32<0><<<grd(LQ, 256),  blk, 0, stream>>>(src, pos,     W_samp,  b_samp,  sampB,  LQ, 256,  256);
    gemm_f32<0><<<grd(LQ, 640),  blk, 0, stream>>>(src, pos,     W_tsamp, b_tsamp, tsampB, LQ, 640,  256);
    gemm_f32<0><<<grd(LQ, 448),  blk, 0, stream>>>(src, pos,     W_attn,  b_attn,  attnB,  LQ, 448,  256);

    // deformable attention
    deform_kernel<<<LQ, 256, 0, stream>>>(valueB, sampB, tsampB, attnB, vr, oB);

    // output proj + residual LN
    gemm_f32<0><<<grd(LQ, 256),  blk, 0, stream>>>(oB, nullptr, W_out, b_out, src2B, LQ, 256, 256);
    add_ln<<<LQ, 256, 0, stream>>>(src, src2B, n1g, n1b, xB);

    // FFN + residual LN
    gemm_f32<1><<<grd(LQ, 1024), blk, 0, stream>>>(xB, nullptr, W_ff1, b_ff1, hB, LQ, 1024, 256);
    gemm_f32<0><<<grd(LQ, 256),  blk, 0, stream>>>(hB, nullptr, W_ff2, b_ff2, ffB, LQ, 256, 1024);
    add_ln<<<LQ, 256, 0, stream>>>(xB, ffB, n2g, n2b, (float*)d_out);
}

// Round 3
// 762.851 us; speedup vs baseline: 4.6552x; 2.3572x over previous
//
#include <hip/hip_runtime.h>
#include <hip/hip_bf16.h>
#include <math.h>

#define LQ 24480

typedef short bf16x8 __attribute__((ext_vector_type(8)));   // 8 bf16 = 16B
typedef float f32x4 __attribute__((ext_vector_type(4)));
typedef float f32x4v __attribute__((ext_vector_type(4)));

static __device__ __forceinline__ float bf2f(ushort u) {
    union { unsigned int i; float f; } v; v.i = ((unsigned int)u) << 16; return v.f;
}
static __device__ __forceinline__ ushort f2bf(float f) {
    __hip_bfloat16 h = __float2bfloat16(f);
    return *reinterpret_cast<ushort*>(&h);
}

// ---------------------------------------------------------------------------
// bf16 MFMA GEMM: C[M,N] = A @ W^T + bias; A [M,K] bf16, W [N,K] bf16.
// Block = 4 waves; tile BM=128 x BN=64; wave w owns rows w*32..+32 (2 m-frags)
// and all 64 cols (4 n-frags). Fragments loaded directly from global
// (everything is L2/L3 resident; K is small).
// ---------------------------------------------------------------------------
template <int RELU, int WF32, int WBF16>
__global__ __launch_bounds__(256) void gemm_mfma(
    const ushort* __restrict__ A, const ushort* __restrict__ W,
    const float* __restrict__ bias,
    float* __restrict__ Cf, ushort* __restrict__ Cb,
    int M, int N, int K)
{
    const int wave = threadIdx.x >> 6;
    const int lane = threadIdx.x & 63;
    const int r = lane & 15;
    const int kblk = lane >> 4;
    const int bm = blockIdx.y * 128;
    const int bn = blockIdx.x * 64;

    f32x4 acc[2][4] = {};

    int row0 = bm + wave * 32 + r;
    int row1 = row0 + 16;
    row0 = min(row0, M - 1);          // clamp (partial last M-block); stores guarded
    row1 = min(row1, M - 1);
    const ushort* a0p = A + (size_t)row0 * K + kblk * 8;
    const ushort* a1p = A + (size_t)row1 * K + kblk * 8;
    const ushort* bp  = W + (size_t)(bn + r) * K + kblk * 8;
    const size_t nK = (size_t)16 * K;

#pragma unroll 4
    for (int k = 0; k < K; k += 32) {
        bf16x8 a0 = *(const bf16x8*)(a0p + k);
        bf16x8 a1 = *(const bf16x8*)(a1p + k);
        bf16x8 b0 = *(const bf16x8*)(bp + k);
        bf16x8 b1 = *(const bf16x8*)(bp + nK + k);
        bf16x8 b2 = *(const bf16x8*)(bp + 2 * nK + k);
        bf16x8 b3 = *(const bf16x8*)(bp + 3 * nK + k);
        acc[0][0] = __builtin_amdgcn_mfma_f32_16x16x32_bf16(a0, b0, acc[0][0], 0, 0, 0);
        acc[0][1] = __builtin_amdgcn_mfma_f32_16x16x32_bf16(a0, b1, acc[0][1], 0, 0, 0);
        acc[0][2] = __builtin_amdgcn_mfma_f32_16x16x32_bf16(a0, b2, acc[0][2], 0, 0, 0);
        acc[0][3] = __builtin_amdgcn_mfma_f32_16x16x32_bf16(a0, b3, acc[0][3], 0, 0, 0);
        acc[1][0] = __builtin_amdgcn_mfma_f32_16x16x32_bf16(a1, b0, acc[1][0], 0, 0, 0);
        acc[1][1] = __builtin_amdgcn_mfma_f32_16x16x32_bf16(a1, b1, acc[1][1], 0, 0, 0);
        acc[1][2] = __builtin_amdgcn_mfma_f32_16x16x32_bf16(a1, b2, acc[1][2], 0, 0, 0);
        acc[1][3] = __builtin_amdgcn_mfma_f32_16x16x32_bf16(a1, b3, acc[1][3], 0, 0, 0);
    }

    const int orow = (lane >> 4) * 4;
    const int ocol = lane & 15;
#pragma unroll
    for (int mi = 0; mi < 2; ++mi)
#pragma unroll
        for (int ni = 0; ni < 4; ++ni) {
            int cc = bn + ni * 16 + ocol;
            float bv = bias[cc];
#pragma unroll
            for (int j = 0; j < 4; ++j) {
                int rr = bm + wave * 32 + mi * 16 + orow + j;
                if (rr < M) {
                    float v = acc[mi][ni][j] + bv;
                    if (RELU) v = fmaxf(v, 0.f);
                    if (WF32) Cf[(size_t)rr * N + cc] = v;
                    if (WBF16) Cb[(size_t)rr * N + cc] = f2bf(v);
                }
            }
        }
}

// ---------------------------------------------------------------------------
// src/q -> bf16 (vectorized), q = src + pos
// ---------------------------------------------------------------------------
__global__ __launch_bounds__(256) void cvt_src_q(
    const float* __restrict__ src, const float* __restrict__ pos,
    ushort* __restrict__ srcb, ushort* __restrict__ qb, int n4)
{
    int i = blockIdx.x * 256 + threadIdx.x;
    if (i >= n4) return;
    f32x4v s = *(const f32x4v*)(src + (size_t)i * 4);
    f32x4v p = *(const f32x4v*)(pos + (size_t)i * 4);
    ushort us[4], uq[4];
#pragma unroll
    for (int j = 0; j < 4; ++j) { us[j] = f2bf(s[j]); uq[j] = f2bf(s[j] + p[j]); }
    *(ulong1*)(srcb + (size_t)i * 4) = *(ulong1*)us;
    *(ulong1*)(qb   + (size_t)i * 4) = *(ulong1*)uq;
}

__global__ __launch_bounds__(256) void cvt_w(const float* __restrict__ w,
                                             ushort* __restrict__ o, int n)
{
    int i = blockIdx.x * 256 + threadIdx.x;
    if (i < n) o[i] = f2bf(w[i]);
}

// ---------------------------------------------------------------------------
// Deformable attention core. One block per query; 8 heads x 32 channels.
// qout (bf16, stride 1344) = [samp(256) | tsamp(640) | logits(448)].
// Unconditional clamped bilinear loads; writes bf16 output for out-proj.
// ---------------------------------------------------------------------------
__global__ __launch_bounds__(256) void deform_kernel(
    const float* __restrict__ value,   // [LQ,256] f32
    const ushort* __restrict__ qout,   // [LQ,1344] bf16
    const float* __restrict__ vr,      // [4,2]
    ushort* __restrict__ ob)           // [LQ,256] bf16
{
    const int q = blockIdx.x;
    const int h = threadIdx.x >> 5;
    const int c = threadIdx.x & 31;

    const int lsiA[4] = {0, 18432, 23040, 24192};

    int lq = (q >= 24192) ? 3 : (q >= 23040) ? 2 : (q >= 18432) ? 1 : 0;
    int qi = q - lsiA[lq];
    int Wq = 64 >> lq;
    int i = qi >> (6 - lq);
    int j = qi & (Wq - 1);
    int Hq = 48 >> lq;
    int tq = i / Hq;
    float rx_base = ((float)j + 0.5f) / (vr[2 * lq + 0] * (float)Wq);
    float ry_base = ((float)i + 0.5f) / (vr[2 * lq + 1] * (float)(Hq * 6));

    // ---- softmax over 56 bf16 logits per head ----
    __shared__ float aw_s[8][56];
    const ushort* lg = qout + (size_t)q * 1344 + 896 + h * 56;
    float l0 = bf2f(lg[c]);
    float l1 = (c < 24) ? bf2f(lg[32 + c]) : -1e30f;
    float m = fmaxf(l0, l1);
#pragma unroll
    for (int off = 16; off; off >>= 1) m = fmaxf(m, __shfl_xor(m, off, 32));
    float e0 = expf(l0 - m);
    float e1 = (c < 24) ? expf(l1 - m) : 0.f;
    float s = e0 + e1;
#pragma unroll
    for (int off = 16; off; off >>= 1) s += __shfl_xor(s, off, 32);
    float inv = 1.f / s;
    aw_s[h][c] = e0 * inv;
    if (c < 24) aw_s[h][32 + c] = e1 * inv;
    __syncthreads();

    const ushort* sp = qout + (size_t)q * 1344 + h * 32;
    const ushort* tp = qout + (size_t)q * 1344 + 256 + h * 80;

    float acc = 0.f;
#pragma unroll
    for (int l = 0; l < 4; ++l) {
        const int Wl = 64 >> l;
        const int Hl = 48 >> l;
        const int Htl = Hl * 6;
        const int sl = lsiA[l];
        const float vrx = vr[2 * l], vry = vr[2 * l + 1];
        const float bx = rx_base * vrx * (float)Wl - 0.5f;
        const float by = ry_base * vry * (float)Htl - 0.5f;
        const float tscale = vry * (float)Hl;
        const float* vbase = value + (size_t)sl * 256 + h * 32 + c;

#pragma unroll
        for (int p = 0; p < 14; ++p) {
            float ox, oy, ty;
            if (p < 4) {
                ox = bf2f(sp[l * 8 + p * 2]);
                oy = bf2f(sp[l * 8 + p * 2 + 1]);
                ty = 0.f;
            } else {
                int pp = p - 4;
                int tw = pp >> 1, nt = pp & 1;
                int tt = (tw < tq) ? tw : tw + 1;
                ty = (float)(tt - tq) * tscale;
                ox = bf2f(tp[l * 20 + tw * 4 + nt * 2]);
                oy = bf2f(tp[l * 20 + tw * 4 + nt * 2 + 1]);
            }
            float x = bx + ox;
            float y = by + ty + oy;
            float x0f = floorf(x), y0f = floorf(y);
            int x0 = (int)x0f, y0 = (int)y0f;
            float fx = x - x0f, fy = y - y0f;

            int xi0 = min(max(x0, 0), Wl - 1);
            int xi1 = min(max(x0 + 1, 0), Wl - 1);
            int yi0 = min(max(y0, 0), Htl - 1);
            int yi1 = min(max(y0 + 1, 0), Htl - 1);
            float mx0 = (x0 >= 0 && x0 < Wl) ? 1.f : 0.f;
            float mx1 = (x0 >= -1 && x0 + 1 < Wl) ? 1.f : 0.f;
            float my0 = (y0 >= 0 && y0 < Htl) ? 1.f : 0.f;
            float my1 = (y0 >= -1 && y0 + 1 < Htl) ? 1.f : 0.f;
            float gx0 = (1.f - fx) * mx0;
            float gx1 = fx * mx1;
            float gy0 = (1.f - fy) * my0;
            float gy1 = fy * my1;

            const float* r0 = vbase + (size_t)(yi0 * Wl) * 256;
            const float* r1 = vbase + (size_t)(yi1 * Wl) * 256;
            float v00 = r0[(size_t)xi0 * 256];
            float v10 = r0[(size_t)xi1 * 256];
            float v01 = r1[(size_t)xi0 * 256];
            float v11 = r1[(size_t)xi1 * 256];

            float bil = gy0 * (gx0 * v00 + gx1 * v10)
                      + gy1 * (gx0 * v01 + gx1 * v11);
            acc += aw_s[h][l * 14 + p] * bil;
        }
    }
    ob[(size_t)q * 256 + h * 32 + c] = f2bf(acc);
}

// ---------------------------------------------------------------------------
// out = LayerNorm(a + b); writes f32 always, bf16 optionally.
// ---------------------------------------------------------------------------
__global__ __launch_bounds__(256) void add_ln(
    const float* __restrict__ a, const float* __restrict__ b,
    const float* __restrict__ g, const float* __restrict__ be,
    float* __restrict__ out, ushort* __restrict__ out16)
{
    const int row = blockIdx.x;
    const int t = threadIdx.x;
    float v = a[(size_t)row * 256 + t] + b[(size_t)row * 256 + t];

    __shared__ float red[4];
    float s = v;
#pragma unroll
    for (int off = 32; off; off >>= 1) s += __shfl_xor(s, off, 64);
    int wid = t >> 6;
    if ((t & 63) == 0) red[wid] = s;
    __syncthreads();
    float mean = (red[0] + red[1] + red[2] + red[3]) * (1.f / 256.f);
    float d = v - mean;
    float s2 = d * d;
#pragma unroll
    for (int off = 32; off; off >>= 1) s2 += __shfl_xor(s2, off, 64);
    __syncthreads();
    if ((t & 63) == 0) red[wid] = s2;
    __syncthreads();
    float var = (red[0] + red[1] + red[2] + red[3]) * (1.f / 256.f);
    float o = d * rsqrtf(var + 1e-5f) * g[t] + be[t];
    out[(size_t)row * 256 + t] = o;
    if (out16) out16[(size_t)row * 256 + t] = f2bf(o);
}

// ---------------------------------------------------------------------------
extern "C" void kernel_launch(void* const* d_in, const int* in_sizes, int n_in,
                              void* d_out, int out_size, void* d_ws, size_t ws_size,
                              hipStream_t stream)
{
    const float* src    = (const float*)d_in[0];
    const float* pos    = (const float*)d_in[1];
    const float* vr     = (const float*)d_in[4];
    const float* W_samp = (const float*)d_in[5];
    const float* b_samp = (const float*)d_in[6];
    const float* W_tsamp= (const float*)d_in[7];
    const float* b_tsamp= (const float*)d_in[8];
    const float* W_attn = (const float*)d_in[9];
    const float* b_attn = (const float*)d_in[10];
    const float* W_val  = (const float*)d_in[11];
    const float* b_val  = (const float*)d_in[12];
    const float* W_out  = (const float*)d_in[13];
    const float* b_out  = (const float*)d_in[14];
    const float* W_ff1  = (const float*)d_in[15];
    const float* b_ff1  = (const float*)d_in[16];
    const float* W_ff2  = (const float*)d_in[17];
    const float* b_ff2  = (const float*)d_in[18];
    const float* n1g    = (const float*)d_in[19];
    const float* n1b    = (const float*)d_in[20];
    const float* n2g    = (const float*)d_in[21];
    const float* n2b    = (const float*)d_in[22];

    // ---- workspace layout (f32 units) ----
    float* ws = (float*)d_ws;
    ushort* qout  = (ushort*)ws;                         // LQ*1344 bf16 = LQ*672 f32
    float* valueB = ws + (size_t)LQ * 672;               // LQ*256 f32
    ushort* srcb  = (ushort*)(valueB + (size_t)LQ * 256);// LQ*256 bf16
    ushort* qb    = srcb + (size_t)LQ * 256;             // LQ*256 bf16
    ushort* obuf  = qb + (size_t)LQ * 256;               // LQ*256 bf16
    float* ffB    = (float*)(obuf + (size_t)LQ * 256);   // LQ*256 f32
    ushort* Wq    = (ushort*)(ffB + (size_t)LQ * 256);   // 1344*256 bf16
    ushort* Wv    = Wq + 1344 * 256;                     // 256*256
    ushort* Wo    = Wv + 256 * 256;                      // 256*256
    ushort* Wf1   = Wo + 256 * 256;                      // 1024*256
    ushort* Wf2   = Wf1 + 1024 * 256;                    // 256*1024
    float* bq     = (float*)(Wf2 + 1024 * 256);          // 1344 f32
    // region reuse after deform:
    float* src2B  = valueB;                              // value dead after deform
    float* xF     = (float*)qout;                        // LQ*256 f32 (qout dead)
    ushort* xB16  = (ushort*)((float*)qout + (size_t)LQ * 256); // LQ*256 bf16
    ushort* hB16  = (ushort*)valueB;                     // LQ*1024 bf16 spans valueB+srcb+qb

    // ---- input conversions ----
    cvt_src_q<<<(LQ * 64 + 255) / 256, 256, 0, stream>>>(src, pos, srcb, qb, LQ * 64);
    cvt_w<<<(256 * 256 + 255) / 256, 256, 0, stream>>>(W_samp,  Wq,              256 * 256);
    cvt_w<<<(640 * 256 + 255) / 256, 256, 0, stream>>>(W_tsamp, Wq + 256 * 256,  640 * 256);
    cvt_w<<<(448 * 256 + 255) / 256, 256, 0, stream>>>(W_attn,  Wq + 896 * 256,  448 * 256);
    cvt_w<<<(256 * 256 + 255) / 256, 256, 0, stream>>>(W_val,   Wv,              256 * 256);
    cvt_w<<<(256 * 256 + 255) / 256, 256, 0, stream>>>(W_out,   Wo,              256 * 256);
    cvt_w<<<(1024 * 256 + 255) / 256, 256, 0, stream>>>(W_ff1,  Wf1,             1024 * 256);
    cvt_w<<<(256 * 1024 + 255) / 256, 256, 0, stream>>>(W_ff2,  Wf2,             256 * 1024);
    hipMemcpyAsync(bq,        b_samp,  256 * sizeof(float), hipMemcpyDeviceToDevice, stream);
    hipMemcpyAsync(bq + 256,  b_tsamp, 640 * sizeof(float), hipMemcpyDeviceToDevice, stream);
    hipMemcpyAsync(bq + 896,  b_attn,  448 * sizeof(float), hipMemcpyDeviceToDevice, stream);

    const int GM = (LQ + 127) / 128;   // 192

    // value = src @ Wv^T (f32 out); qout = (src+pos) @ Wq^T (bf16 out)
    gemm_mfma<0, 1, 0><<<dim3(4, GM),  256, 0, stream>>>(srcb, Wv, b_val, valueB, nullptr, LQ, 256, 256);
    gemm_mfma<0, 0, 1><<<dim3(21, GM), 256, 0, stream>>>(qb, Wq, bq, nullptr, qout, LQ, 1344, 256);

    // deformable attention (bf16 out)
    deform_kernel<<<LQ, 256, 0, stream>>>(valueB, qout, vr, obuf);

    // out-proj + residual LN1 (xF f32 + xB16 bf16)
    gemm_mfma<0, 1, 0><<<dim3(4, GM),  256, 0, stream>>>(obuf, Wo, b_out, src2B, nullptr, LQ, 256, 256);
    add_ln<<<LQ, 256, 0, stream>>>(src, src2B, n1g, n1b, xF, xB16);

    // FFN
    gemm_mfma<1, 0, 1><<<dim3(16, GM), 256, 0, stream>>>(xB16, Wf1, b_ff1, nullptr, hB16, LQ, 1024, 256);
    gemm_mfma<0, 1, 0><<<dim3(4, GM),  256, 0, stream>>>(hB16, Wf2, b_ff2, ffB, nullptr, LQ, 256, 1024);
    add_ln<<<LQ, 256, 0, stream>>>(xF, ffB, n2g, n2b, (float*)d_out, nullptr);
}

// Round 4
// 570.061 us; speedup vs baseline: 6.2296x; 1.3382x over previous
//
#include <hip/hip_runtime.h>
#include <hip/hip_bf16.h>
#include <math.h>

#define LQ 24480

typedef short bf16x8 __attribute__((ext_vector_type(8)));   // 8 bf16 = 16B
typedef float f32x4 __attribute__((ext_vector_type(4)));
typedef float f32x4v __attribute__((ext_vector_type(4)));

static __device__ __forceinline__ float bf2f(ushort u) {
    union { unsigned int i; float f; } v; v.i = ((unsigned int)u) << 16; return v.f;
}
static __device__ __forceinline__ ushort f2bf(float f) {
    __hip_bfloat16 h = __float2bfloat16(f);
    return *reinterpret_cast<ushort*>(&h);
}

// ---------------------------------------------------------------------------
// bf16 MFMA GEMM: C[M,N] = A @ W^T + bias; A [M,K] bf16, W [N,K] bf16.
// Block = 4 waves; tile BM=128 x BN=64; direct-from-global fragments.
// ---------------------------------------------------------------------------
template <int RELU, int WF32, int WBF16>
__global__ __launch_bounds__(256) void gemm_mfma(
    const ushort* __restrict__ A, const ushort* __restrict__ W,
    const float* __restrict__ bias,
    float* __restrict__ Cf, ushort* __restrict__ Cb,
    int M, int N, int K)
{
    const int wave = threadIdx.x >> 6;
    const int lane = threadIdx.x & 63;
    const int r = lane & 15;
    const int kblk = lane >> 4;
    const int bm = blockIdx.y * 128;
    const int bn = blockIdx.x * 64;

    f32x4 acc[2][4] = {};

    int row0 = bm + wave * 32 + r;
    int row1 = row0 + 16;
    row0 = min(row0, M - 1);
    row1 = min(row1, M - 1);
    const ushort* a0p = A + (size_t)row0 * K + kblk * 8;
    const ushort* a1p = A + (size_t)row1 * K + kblk * 8;
    const ushort* bp  = W + (size_t)(bn + r) * K + kblk * 8;
    const size_t nK = (size_t)16 * K;

#pragma unroll 4
    for (int k = 0; k < K; k += 32) {
        bf16x8 a0 = *(const bf16x8*)(a0p + k);
        bf16x8 a1 = *(const bf16x8*)(a1p + k);
        bf16x8 b0 = *(const bf16x8*)(bp + k);
        bf16x8 b1 = *(const bf16x8*)(bp + nK + k);
        bf16x8 b2 = *(const bf16x8*)(bp + 2 * nK + k);
        bf16x8 b3 = *(const bf16x8*)(bp + 3 * nK + k);
        acc[0][0] = __builtin_amdgcn_mfma_f32_16x16x32_bf16(a0, b0, acc[0][0], 0, 0, 0);
        acc[0][1] = __builtin_amdgcn_mfma_f32_16x16x32_bf16(a0, b1, acc[0][1], 0, 0, 0);
        acc[0][2] = __builtin_amdgcn_mfma_f32_16x16x32_bf16(a0, b2, acc[0][2], 0, 0, 0);
        acc[0][3] = __builtin_amdgcn_mfma_f32_16x16x32_bf16(a0, b3, acc[0][3], 0, 0, 0);
        acc[1][0] = __builtin_amdgcn_mfma_f32_16x16x32_bf16(a1, b0, acc[1][0], 0, 0, 0);
        acc[1][1] = __builtin_amdgcn_mfma_f32_16x16x32_bf16(a1, b1, acc[1][1], 0, 0, 0);
        acc[1][2] = __builtin_amdgcn_mfma_f32_16x16x32_bf16(a1, b2, acc[1][2], 0, 0, 0);
        acc[1][3] = __builtin_amdgcn_mfma_f32_16x16x32_bf16(a1, b3, acc[1][3], 0, 0, 0);
    }

    const int orow = (lane >> 4) * 4;
    const int ocol = lane & 15;
#pragma unroll
    for (int mi = 0; mi < 2; ++mi)
#pragma unroll
        for (int ni = 0; ni < 4; ++ni) {
            int cc = bn + ni * 16 + ocol;
            float bv = bias[cc];
#pragma unroll
            for (int j = 0; j < 4; ++j) {
                int rr = bm + wave * 32 + mi * 16 + orow + j;
                if (rr < M) {
                    float v = acc[mi][ni][j] + bv;
                    if (RELU) v = fmaxf(v, 0.f);
                    if (WF32) Cf[(size_t)rr * N + cc] = v;
                    if (WBF16) Cb[(size_t)rr * N + cc] = f2bf(v);
                }
            }
        }
}

// ---------------------------------------------------------------------------
// src/q -> bf16 (vectorized), q = src + pos
// ---------------------------------------------------------------------------
__global__ __launch_bounds__(256) void cvt_src_q(
    const float* __restrict__ src, const float* __restrict__ pos,
    ushort* __restrict__ srcb, ushort* __restrict__ qb, int n4)
{
    int i = blockIdx.x * 256 + threadIdx.x;
    if (i >= n4) return;
    f32x4v s = *(const f32x4v*)(src + (size_t)i * 4);
    f32x4v p = *(const f32x4v*)(pos + (size_t)i * 4);
    ushort us[4], uq[4];
#pragma unroll
    for (int j = 0; j < 4; ++j) { us[j] = f2bf(s[j]); uq[j] = f2bf(s[j] + p[j]); }
    *(ulong1*)(srcb + (size_t)i * 4) = *(ulong1*)us;
    *(ulong1*)(qb   + (size_t)i * 4) = *(ulong1*)uq;
}

// all weight conversions in ONE launch: seg = blockIdx.y
struct CvtArgs { const float* s[8]; ushort* d[8]; int n[8]; };
__global__ __launch_bounds__(256) void cvt_w8(CvtArgs a)
{
    int seg = blockIdx.y;
    int i = blockIdx.x * 256 + threadIdx.x;
    if (i < a.n[seg]) a.d[seg][i] = f2bf(a.s[seg][i]);
}

// ---------------------------------------------------------------------------
// Deformable attention, phase-split.
// Phase 1: 256 threads compute softmax + 448 (h,p) items' 4 offsets + 4
//          aw-premultiplied bilinear weights into LDS.
// Phase 2: thread (h,c) accumulates 56 points x 4 corners from bf16 value.
// ---------------------------------------------------------------------------
__global__ __launch_bounds__(256) void deform_kernel(
    const ushort* __restrict__ valb,   // [LQ,256] bf16
    const ushort* __restrict__ qout,   // [LQ,1344] bf16: samp|tsamp|logits
    const float* __restrict__ vr,      // [4,2]
    ushort* __restrict__ ob)           // [LQ,256] bf16
{
    const int q = blockIdx.x;
    const int tid = threadIdx.x;

    __shared__ float aw_s[448];
    __shared__ int4   offs_s[448];
    __shared__ float4 wts_s[448];

    const int lsiA[4] = {0, 18432, 23040, 24192};

    // query geometry (uniform per block)
    int lq = (q >= 24192) ? 3 : (q >= 23040) ? 2 : (q >= 18432) ? 1 : 0;
    int qi = q - lsiA[lq];
    int Wq = 64 >> lq;
    int iy = qi >> (6 - lq);
    int jx = qi & (Wq - 1);
    int Hq = 48 >> lq;
    int tq = iy / Hq;
    float rx_base = ((float)jx + 0.5f) / (vr[2 * lq + 0] * (float)Wq);
    float ry_base = ((float)iy + 0.5f) / (vr[2 * lq + 1] * (float)(Hq * 6));

    // ---- softmax over 56 bf16 logits per head (8 groups of 32 lanes) ----
    {
        const int h = tid >> 5, c = tid & 31;
        const ushort* lg = qout + (size_t)q * 1344 + 896 + h * 56;
        float l0 = bf2f(lg[c]);
        float l1 = (c < 24) ? bf2f(lg[32 + c]) : -1e30f;
        float m = fmaxf(l0, l1);
#pragma unroll
        for (int off = 16; off; off >>= 1) m = fmaxf(m, __shfl_xor(m, off, 32));
        float e0 = expf(l0 - m);
        float e1 = (c < 24) ? expf(l1 - m) : 0.f;
        float s = e0 + e1;
#pragma unroll
        for (int off = 16; off; off >>= 1) s += __shfl_xor(s, off, 32);
        float inv = 1.f / s;
        aw_s[h * 56 + c] = e0 * inv;
        if (c < 24) aw_s[h * 56 + 32 + c] = e1 * inv;
    }
    __syncthreads();

    // ---- phase 1: coords for 448 items ----
    const ushort* qrow = qout + (size_t)q * 1344;
    for (int it = tid; it < 448; it += 256) {
        int h = it / 56;
        int p = it - h * 56;
        int l = p / 14;
        int pp = p - l * 14;

        int Wl = 64 >> l;
        int Hl = 48 >> l;
        int Htl = Hl * 6;
        float vrx = vr[2 * l], vry = vr[2 * l + 1];

        float ox, oy, ty;
        if (pp < 4) {
            ox = bf2f(qrow[h * 32 + l * 8 + pp * 2]);
            oy = bf2f(qrow[h * 32 + l * 8 + pp * 2 + 1]);
            ty = 0.f;
        } else {
            int pq = pp - 4;
            int tw = pq >> 1, nt = pq & 1;
            int tt = (tw < tq) ? tw : tw + 1;
            ty = (float)(tt - tq) * vry * (float)Hl;
            ox = bf2f(qrow[256 + h * 80 + l * 20 + tw * 4 + nt * 2]);
            oy = bf2f(qrow[256 + h * 80 + l * 20 + tw * 4 + nt * 2 + 1]);
        }
        float x = rx_base * vrx * (float)Wl - 0.5f + ox;
        float y = ry_base * vry * (float)Htl - 0.5f + ty + oy;
        float x0f = floorf(x), y0f = floorf(y);
        int x0 = (int)x0f, y0 = (int)y0f;
        float fx = x - x0f, fy = y - y0f;

        int xi0 = min(max(x0, 0), Wl - 1);
        int xi1 = min(max(x0 + 1, 0), Wl - 1);
        int yi0 = min(max(y0, 0), Htl - 1);
        int yi1 = min(max(y0 + 1, 0), Htl - 1);
        float mx0 = (x0 >= 0 && x0 < Wl) ? 1.f : 0.f;
        float mx1 = (x0 >= -1 && x0 + 1 < Wl) ? 1.f : 0.f;
        float my0 = (y0 >= 0 && y0 < Htl) ? 1.f : 0.f;
        float my1 = (y0 >= -1 && y0 + 1 < Htl) ? 1.f : 0.f;

        float aw = aw_s[it];
        float gx0 = (1.f - fx) * mx0;
        float gx1 = fx * mx1;
        float gy0 = (1.f - fy) * my0 * aw;
        float gy1 = fy * my1 * aw;

        int sl = lsiA[l];
        int rb0 = (sl + yi0 * Wl) * 256;
        int rb1 = (sl + yi1 * Wl) * 256;
        offs_s[it] = make_int4(rb0 + xi0 * 256, rb0 + xi1 * 256,
                               rb1 + xi0 * 256, rb1 + xi1 * 256);
        wts_s[it] = make_float4(gy0 * gx0, gy0 * gx1, gy1 * gx0, gy1 * gx1);
    }
    __syncthreads();

    // ---- phase 2: gather + accumulate ----
    const int h = tid >> 5, c = tid & 31;
    const ushort* vb = valb + h * 32 + c;
    const int4* op = offs_s + h * 56;
    const float4* wp = wts_s + h * 56;
    float acc = 0.f;
#pragma unroll 4
    for (int p = 0; p < 56; ++p) {
        int4 o4 = op[p];
        float4 w4 = wp[p];
        acc += w4.x * bf2f(vb[o4.x]);
        acc += w4.y * bf2f(vb[o4.y]);
        acc += w4.z * bf2f(vb[o4.z]);
        acc += w4.w * bf2f(vb[o4.w]);
    }
    ob[(size_t)q * 256 + h * 32 + c] = f2bf(acc);
}

// ---------------------------------------------------------------------------
// out = LayerNorm(a + b); writes f32 always, bf16 optionally.
// ---------------------------------------------------------------------------
__global__ __launch_bounds__(256) void add_ln(
    const float* __restrict__ a, const float* __restrict__ b,
    const float* __restrict__ g, const float* __restrict__ be,
    float* __restrict__ out, ushort* __restrict__ out16)
{
    const int row = blockIdx.x;
    const int t = threadIdx.x;
    float v = a[(size_t)row * 256 + t] + b[(size_t)row * 256 + t];

    __shared__ float red[4];
    float s = v;
#pragma unroll
    for (int off = 32; off; off >>= 1) s += __shfl_xor(s, off, 64);
    int wid = t >> 6;
    if ((t & 63) == 0) red[wid] = s;
    __syncthreads();
    float mean = (red[0] + red[1] + red[2] + red[3]) * (1.f / 256.f);
    float d = v - mean;
    float s2 = d * d;
#pragma unroll
    for (int off = 32; off; off >>= 1) s2 += __shfl_xor(s2, off, 64);
    __syncthreads();
    if ((t & 63) == 0) red[wid] = s2;
    __syncthreads();
    float var = (red[0] + red[1] + red[2] + red[3]) * (1.f / 256.f);
    float o = d * rsqrtf(var + 1e-5f) * g[t] + be[t];
    out[(size_t)row * 256 + t] = o;
    if (out16) out16[(size_t)row * 256 + t] = f2bf(o);
}

// ---------------------------------------------------------------------------
extern "C" void kernel_launch(void* const* d_in, const int* in_sizes, int n_in,
                              void* d_out, int out_size, void* d_ws, size_t ws_size,
                              hipStream_t stream)
{
    const float* src    = (const float*)d_in[0];
    const float* pos    = (const float*)d_in[1];
    const float* vr     = (const float*)d_in[4];
    const float* W_samp = (const float*)d_in[5];
    const float* b_samp = (const float*)d_in[6];
    const float* W_tsamp= (const float*)d_in[7];
    const float* b_tsamp= (const float*)d_in[8];
    const float* W_attn = (const float*)d_in[9];
    const float* b_attn = (const float*)d_in[10];
    const float* W_val  = (const float*)d_in[11];
    const float* b_val  = (const float*)d_in[12];
    const float* W_out  = (const float*)d_in[13];
    const float* b_out  = (const float*)d_in[14];
    const float* W_ff1  = (const float*)d_in[15];
    const float* b_ff1  = (const float*)d_in[16];
    const float* W_ff2  = (const float*)d_in[17];
    const float* b_ff2  = (const float*)d_in[18];
    const float* n1g    = (const float*)d_in[19];
    const float* n1b    = (const float*)d_in[20];
    const float* n2g    = (const float*)d_in[21];
    const float* n2b    = (const float*)d_in[22];

    // ---- workspace layout (f32 units) ----
    float* ws = (float*)d_ws;
    ushort* qout  = (ushort*)ws;                         // LQ*1344 bf16
    float* valueR = ws + (size_t)LQ * 672;               // region: LQ*256 f32
    ushort* valb  = (ushort*)valueR;                     // LQ*256 bf16 (first half)
    ushort* srcb  = (ushort*)(valueR + (size_t)LQ * 256);// LQ*256 bf16
    ushort* qb    = srcb + (size_t)LQ * 256;             // LQ*256 bf16
    ushort* obuf  = qb + (size_t)LQ * 256;               // LQ*256 bf16
    float* ffB    = (float*)(obuf + (size_t)LQ * 256);   // LQ*256 f32
    ushort* Wq    = (ushort*)(ffB + (size_t)LQ * 256);   // 1344*256 bf16
    ushort* Wv    = Wq + 1344 * 256;
    ushort* Wo    = Wv + 256 * 256;
    ushort* Wf1   = Wo + 256 * 256;
    ushort* Wf2   = Wf1 + 1024 * 256;
    float* bq     = (float*)(Wf2 + 1024 * 256);          // 1344 f32
    // region reuse after deform:
    float* src2B  = valueR;                              // value dead after deform
    float* xF     = (float*)qout;                        // qout dead after deform
    ushort* xB16  = (ushort*)((float*)qout + (size_t)LQ * 256);
    ushort* hB16  = (ushort*)valueR;                     // LQ*1024 bf16 spans valueR..qb

    // ---- input conversions ----
    cvt_src_q<<<(LQ * 64 + 255) / 256, 256, 0, stream>>>(src, pos, srcb, qb, LQ * 64);
    CvtArgs ca;
    ca.s[0] = W_samp;  ca.d[0] = Wq;             ca.n[0] = 256 * 256;
    ca.s[1] = W_tsamp; ca.d[1] = Wq + 256 * 256; ca.n[1] = 640 * 256;
    ca.s[2] = W_attn;  ca.d[2] = Wq + 896 * 256; ca.n[2] = 448 * 256;
    ca.s[3] = W_val;   ca.d[3] = Wv;             ca.n[3] = 256 * 256;
    ca.s[4] = W_out;   ca.d[4] = Wo;             ca.n[4] = 256 * 256;
    ca.s[5] = W_ff1;   ca.d[5] = Wf1;            ca.n[5] = 1024 * 256;
    ca.s[6] = W_ff2;   ca.d[6] = Wf2;            ca.n[6] = 256 * 1024;
    ca.s[7] = W_ff2;   ca.d[7] = Wf2;            ca.n[7] = 0;   // unused
    cvt_w8<<<dim3(1024, 8), 256, 0, stream>>>(ca);
    hipMemcpyAsync(bq,        b_samp,  256 * sizeof(float), hipMemcpyDeviceToDevice, stream);
    hipMemcpyAsync(bq + 256,  b_tsamp, 640 * sizeof(float), hipMemcpyDeviceToDevice, stream);
    hipMemcpyAsync(bq + 896,  b_attn,  448 * sizeof(float), hipMemcpyDeviceToDevice, stream);

    const int GM = (LQ + 127) / 128;   // 192

    // value = src @ Wv^T (bf16 out); qout = (src+pos) @ Wq^T (bf16 out)
    gemm_mfma<0, 0, 1><<<dim3(4, GM),  256, 0, stream>>>(srcb, Wv, b_val, nullptr, valb, LQ, 256, 256);
    gemm_mfma<0, 0, 1><<<dim3(21, GM), 256, 0, stream>>>(qb, Wq, bq, nullptr, qout, LQ, 1344, 256);

    // deformable attention (bf16 out)
    deform_kernel<<<LQ, 256, 0, stream>>>(valb, qout, vr, obuf);

    // out-proj + residual LN1
    gemm_mfma<0, 1, 0><<<dim3(4, GM),  256, 0, stream>>>(obuf, Wo, b_out, src2B, nullptr, LQ, 256, 256);
    add_ln<<<LQ, 256, 0, stream>>>(src, src2B, n1g, n1b, xF, xB16);

    // FFN
    gemm_mfma<1, 0, 1><<<dim3(16, GM), 256, 0, stream>>>(xB16, Wf1, b_ff1, nullptr, hB16, LQ, 1024, 256);
    gemm_mfma<0, 1, 0><<<dim3(4, GM),  256, 0, stream>>>(hB16, Wf2, b_ff2, ffB, nullptr, LQ, 256, 1024);
    add_ln<<<LQ, 256, 0, stream>>>(xF, ffB, n2g, n2b, (float*)d_out, nullptr);
}

// Round 5
// 510.584 us; speedup vs baseline: 6.9553x; 1.1165x over previous
//
#include <hip/hip_runtime.h>
#include <hip/hip_bf16.h>
#include <math.h>

#define LQ 24480

typedef short bf16x8 __attribute__((ext_vector_type(8)));   // 8 bf16 = 16B
typedef float f32x4 __attribute__((ext_vector_type(4)));
typedef float f32x4v __attribute__((ext_vector_type(4)));

static __device__ __forceinline__ float bf2f(ushort u) {
    union { unsigned int i; float f; } v; v.i = ((unsigned int)u) << 16; return v.f;
}
static __device__ __forceinline__ ushort f2bf(float f) {
    __hip_bfloat16 h = __float2bfloat16(f);
    return *reinterpret_cast<ushort*>(&h);
}
static __device__ __forceinline__ float u2f_lo(unsigned int u) {
    union { unsigned int i; float f; } v; v.i = u << 16; return v.f;
}
static __device__ __forceinline__ float u2f_hi(unsigned int u) {
    union { unsigned int i; float f; } v; v.i = u & 0xffff0000u; return v.f;
}

// ---------------------------------------------------------------------------
// bf16 MFMA GEMM: C[M,N] = A @ W^T + bias; BM=128 x BN=64 tiles.
// ---------------------------------------------------------------------------
template <int RELU, int WF32, int WBF16>
__global__ __launch_bounds__(256) void gemm_mfma(
    const ushort* __restrict__ A, const ushort* __restrict__ W,
    const float* __restrict__ bias,
    float* __restrict__ Cf, ushort* __restrict__ Cb,
    int M, int N, int K)
{
    const int wave = threadIdx.x >> 6;
    const int lane = threadIdx.x & 63;
    const int r = lane & 15;
    const int kblk = lane >> 4;
    const int bm = blockIdx.y * 128;
    const int bn = blockIdx.x * 64;

    f32x4 acc[2][4] = {};

    int row0 = bm + wave * 32 + r;
    int row1 = row0 + 16;
    row0 = min(row0, M - 1);
    row1 = min(row1, M - 1);
    const ushort* a0p = A + (size_t)row0 * K + kblk * 8;
    const ushort* a1p = A + (size_t)row1 * K + kblk * 8;
    const ushort* bp  = W + (size_t)(bn + r) * K + kblk * 8;
    const size_t nK = (size_t)16 * K;

#pragma unroll 4
    for (int k = 0; k < K; k += 32) {
        bf16x8 a0 = *(const bf16x8*)(a0p + k);
        bf16x8 a1 = *(const bf16x8*)(a1p + k);
        bf16x8 b0 = *(const bf16x8*)(bp + k);
        bf16x8 b1 = *(const bf16x8*)(bp + nK + k);
        bf16x8 b2 = *(const bf16x8*)(bp + 2 * nK + k);
        bf16x8 b3 = *(const bf16x8*)(bp + 3 * nK + k);
        acc[0][0] = __builtin_amdgcn_mfma_f32_16x16x32_bf16(a0, b0, acc[0][0], 0, 0, 0);
        acc[0][1] = __builtin_amdgcn_mfma_f32_16x16x32_bf16(a0, b1, acc[0][1], 0, 0, 0);
        acc[0][2] = __builtin_amdgcn_mfma_f32_16x16x32_bf16(a0, b2, acc[0][2], 0, 0, 0);
        acc[0][3] = __builtin_amdgcn_mfma_f32_16x16x32_bf16(a0, b3, acc[0][3], 0, 0, 0);
        acc[1][0] = __builtin_amdgcn_mfma_f32_16x16x32_bf16(a1, b0, acc[1][0], 0, 0, 0);
        acc[1][1] = __builtin_amdgcn_mfma_f32_16x16x32_bf16(a1, b1, acc[1][1], 0, 0, 0);
        acc[1][2] = __builtin_amdgcn_mfma_f32_16x16x32_bf16(a1, b2, acc[1][2], 0, 0, 0);
        acc[1][3] = __builtin_amdgcn_mfma_f32_16x16x32_bf16(a1, b3, acc[1][3], 0, 0, 0);
    }

    const int orow = (lane >> 4) * 4;
    const int ocol = lane & 15;
#pragma unroll
    for (int mi = 0; mi < 2; ++mi)
#pragma unroll
        for (int ni = 0; ni < 4; ++ni) {
            int cc = bn + ni * 16 + ocol;
            float bv = bias[cc];
#pragma unroll
            for (int j = 0; j < 4; ++j) {
                int rr = bm + wave * 32 + mi * 16 + orow + j;
                if (rr < M) {
                    float v = acc[mi][ni][j] + bv;
                    if (RELU) v = fmaxf(v, 0.f);
                    if (WF32) Cf[(size_t)rr * N + cc] = v;
                    if (WBF16) Cb[(size_t)rr * N + cc] = f2bf(v);
                }
            }
        }
}

// ---------------------------------------------------------------------------
// Fused GEMM (N=256) + residual + LayerNorm.
// out = LN(res + A@W^T + bias) * g + be. BM=128, BN=256 (full row in block).
// Wave owns 32 rows x 256 cols: acc[2][16] f32x4. LN reduce: 16 in-register
// adds + shfl_xor width-16 (lanes 0..15 of each quarter hold the row's cols).
// ---------------------------------------------------------------------------
template <int WBF16>
__global__ __launch_bounds__(256) void gemm_ln(
    const ushort* __restrict__ A, const ushort* __restrict__ W,
    const float* __restrict__ bias, const float* __restrict__ res,
    const float* __restrict__ g, const float* __restrict__ be,
    float* __restrict__ outF, ushort* __restrict__ outB,
    int M, int K)
{
    const int wave = threadIdx.x >> 6;
    const int lane = threadIdx.x & 63;
    const int r = lane & 15;
    const int kblk = lane >> 4;
    const int bm = blockIdx.x * 128;

    f32x4 acc[2][16] = {};

    int row0 = bm + wave * 32 + r;
    int row1 = row0 + 16;
    row0 = min(row0, M - 1);
    row1 = min(row1, M - 1);
    const ushort* ap0 = A + (size_t)row0 * K + kblk * 8;
    const ushort* ap1 = A + (size_t)row1 * K + kblk * 8;
    const ushort* bp  = W + (size_t)r * K + kblk * 8;
    const size_t nK = (size_t)16 * K;

#pragma unroll 2
    for (int k = 0; k < K; k += 32) {
        bf16x8 a0 = *(const bf16x8*)(ap0 + k);
        bf16x8 a1 = *(const bf16x8*)(ap1 + k);
#pragma unroll
        for (int ni = 0; ni < 16; ++ni) {
            bf16x8 b = *(const bf16x8*)(bp + (size_t)ni * nK + k);
            acc[0][ni] = __builtin_amdgcn_mfma_f32_16x16x32_bf16(a0, b, acc[0][ni], 0, 0, 0);
            acc[1][ni] = __builtin_amdgcn_mfma_f32_16x16x32_bf16(a1, b, acc[1][ni], 0, 0, 0);
        }
    }

    const int orow = kblk * 4;
    const int ocol = r;

    float bv[16];
#pragma unroll
    for (int ni = 0; ni < 16; ++ni) bv[ni] = bias[ni * 16 + ocol];

    float mean_[2][4], rstd_[2][4];
#pragma unroll
    for (int mi = 0; mi < 2; ++mi)
#pragma unroll
        for (int j = 0; j < 4; ++j) {
            int rr = bm + wave * 32 + mi * 16 + orow + j;
            int rl = min(rr, M - 1);
            const float* rp = res + (size_t)rl * 256 + ocol;
            float s = 0.f, s2 = 0.f;
#pragma unroll
            for (int ni = 0; ni < 16; ++ni) {
                float v = acc[mi][ni][j] + bv[ni] + rp[ni * 16];
                acc[mi][ni][j] = v;
                s += v; s2 += v * v;
            }
#pragma unroll
            for (int off = 8; off; off >>= 1) {
                s  += __shfl_xor(s,  off, 16);
                s2 += __shfl_xor(s2, off, 16);
            }
            float mu = s * (1.f / 256.f);
            float var = s2 * (1.f / 256.f) - mu * mu;
            mean_[mi][j] = mu;
            rstd_[mi][j] = rsqrtf(var + 1e-5f);
        }

    float gv[16], bev[16];
#pragma unroll
    for (int ni = 0; ni < 16; ++ni) {
        gv[ni] = g[ni * 16 + ocol];
        bev[ni] = be[ni * 16 + ocol];
    }

#pragma unroll
    for (int mi = 0; mi < 2; ++mi)
#pragma unroll
        for (int j = 0; j < 4; ++j) {
            int rr = bm + wave * 32 + mi * 16 + orow + j;
            if (rr < M) {
#pragma unroll
                for (int ni = 0; ni < 16; ++ni) {
                    float o = (acc[mi][ni][j] - mean_[mi][j]) * rstd_[mi][j] * gv[ni] + bev[ni];
                    outF[(size_t)rr * 256 + ni * 16 + ocol] = o;
                    if (WBF16) outB[(size_t)rr * 256 + ni * 16 + ocol] = f2bf(o);
                }
            }
        }
}

// ---------------------------------------------------------------------------
// src/q -> bf16 (vectorized), q = src + pos
// ---------------------------------------------------------------------------
__global__ __launch_bounds__(256) void cvt_src_q(
    const float* __restrict__ src, const float* __restrict__ pos,
    ushort* __restrict__ srcb, ushort* __restrict__ qb, int n4)
{
    int i = blockIdx.x * 256 + threadIdx.x;
    if (i >= n4) return;
    f32x4v s = *(const f32x4v*)(src + (size_t)i * 4);
    f32x4v p = *(const f32x4v*)(pos + (size_t)i * 4);
    ushort us[4], uq[4];
#pragma unroll
    for (int j = 0; j < 4; ++j) { us[j] = f2bf(s[j]); uq[j] = f2bf(s[j] + p[j]); }
    *(ulong1*)(srcb + (size_t)i * 4) = *(ulong1*)us;
    *(ulong1*)(qb   + (size_t)i * 4) = *(ulong1*)uq;
}

// all weight conversions in ONE launch: seg = blockIdx.y
struct CvtArgs { const float* s[8]; ushort* d[8]; int n[8]; };
__global__ __launch_bounds__(256) void cvt_w8(CvtArgs a)
{
    int seg = blockIdx.y;
    int i = blockIdx.x * 256 + threadIdx.x;
    if (i < a.n[seg]) a.d[seg][i] = f2bf(a.s[seg][i]);
}

// ---------------------------------------------------------------------------
// Deformable attention, phase-split, 2 queries per block, 2 channels/thread.
// Phase 0: softmax (16-lane groups, one per (query, head)).
// Phase 1: 896 items -> 4 offsets (uint-index) + 4 aw-premultiplied weights.
// Phase 2: thread (ql,h,c2) gathers uint (2xbf16) corners, 2 channels.
// ---------------------------------------------------------------------------
__global__ __launch_bounds__(256) void deform_kernel(
    const ushort* __restrict__ valb,   // [LQ,256] bf16
    const ushort* __restrict__ qout,   // [LQ,1344] bf16: samp|tsamp|logits
    const float* __restrict__ vr,      // [4,2]
    ushort* __restrict__ ob)           // [LQ,256] bf16
{
    const int q0 = blockIdx.x * 2;
    const int tid = threadIdx.x;

    __shared__ float  aw_s[2][448];
    __shared__ int4   offs_s[2][448];
    __shared__ float4 wts_s[2][448];

    const int lsiA[4] = {0, 18432, 23040, 24192};

    // ---- phase 0: softmax, group = (ql,h) = tid>>4, lanes = tid&15 ----
    {
        int grp = tid >> 4;
        int ql = grp >> 3, h = grp & 7;
        int ln = tid & 15;
        const ushort* lg = qout + (size_t)(q0 + ql) * 1344 + 896 + h * 56;
        float l0 = bf2f(lg[ln]);
        float l1 = bf2f(lg[16 + ln]);
        float l2 = bf2f(lg[32 + ln]);
        float l3 = (ln < 8) ? bf2f(lg[48 + ln]) : -1e30f;
        float m = fmaxf(fmaxf(l0, l1), fmaxf(l2, l3));
#pragma unroll
        for (int off = 8; off; off >>= 1) m = fmaxf(m, __shfl_xor(m, off, 16));
        float e0 = expf(l0 - m), e1 = expf(l1 - m), e2 = expf(l2 - m);
        float e3 = (ln < 8) ? expf(l3 - m) : 0.f;
        float s = e0 + e1 + e2 + e3;
#pragma unroll
        for (int off = 8; off; off >>= 1) s += __shfl_xor(s, off, 16);
        float inv = 1.f / s;
        aw_s[ql][h * 56 + ln]      = e0 * inv;
        aw_s[ql][h * 56 + 16 + ln] = e1 * inv;
        aw_s[ql][h * 56 + 32 + ln] = e2 * inv;
        if (ln < 8) aw_s[ql][h * 56 + 48 + ln] = e3 * inv;
    }
    __syncthreads();

    // ---- phase 1: coords for 2x448 items ----
    for (int it = tid; it < 896; it += 256) {
        int ql = (it >= 448) ? 1 : 0;
        int item = it - ql * 448;
        int q = q0 + ql;

        int lq = (q >= 24192) ? 3 : (q >= 23040) ? 2 : (q >= 18432) ? 1 : 0;
        int qi = q - lsiA[lq];
        int Wq = 64 >> lq;
        int iy = qi >> (6 - lq);
        int jx = qi & (Wq - 1);
        int Hq = 48 >> lq;
        int tq = iy / Hq;
        float rx_base = ((float)jx + 0.5f) / (vr[2 * lq + 0] * (float)Wq);
        float ry_base = ((float)iy + 0.5f) / (vr[2 * lq + 1] * (float)(Hq * 6));

        int h = item / 56;
        int p = item - h * 56;
        int l = p / 14;
        int pp = p - l * 14;

        int Wl = 64 >> l;
        int Hl = 48 >> l;
        int Htl = Hl * 6;
        float vrx = vr[2 * l], vry = vr[2 * l + 1];

        const ushort* qrow = qout + (size_t)q * 1344;
        float ox, oy, ty;
        if (pp < 4) {
            ox = bf2f(qrow[h * 32 + l * 8 + pp * 2]);
            oy = bf2f(qrow[h * 32 + l * 8 + pp * 2 + 1]);
            ty = 0.f;
        } else {
            int pq = pp - 4;
            int tw = pq >> 1, nt = pq & 1;
            int tt = (tw < tq) ? tw : tw + 1;
            ty = (float)(tt - tq) * vry * (float)Hl;
            ox = bf2f(qrow[256 + h * 80 + l * 20 + tw * 4 + nt * 2]);
            oy = bf2f(qrow[256 + h * 80 + l * 20 + tw * 4 + nt * 2 + 1]);
        }
        float x = rx_base * vrx * (float)Wl - 0.5f + ox;
        float y = ry_base * vry * (float)Htl - 0.5f + ty + oy;
        float x0f = floorf(x), y0f = floorf(y);
        int x0 = (int)x0f, y0 = (int)y0f;
        float fx = x - x0f, fy = y - y0f;

        int xi0 = min(max(x0, 0), Wl - 1);
        int xi1 = min(max(x0 + 1, 0), Wl - 1);
        int yi0 = min(max(y0, 0), Htl - 1);
        int yi1 = min(max(y0 + 1, 0), Htl - 1);
        float mx0 = (x0 >= 0 && x0 < Wl) ? 1.f : 0.f;
        float mx1 = (x0 >= -1 && x0 + 1 < Wl) ? 1.f : 0.f;
        float my0 = (y0 >= 0 && y0 < Htl) ? 1.f : 0.f;
        float my1 = (y0 >= -1 && y0 + 1 < Htl) ? 1.f : 0.f;

        float aw = aw_s[ql][item];
        float gx0 = (1.f - fx) * mx0;
        float gx1 = fx * mx1;
        float gy0 = (1.f - fy) * my0 * aw;
        float gy1 = fy * my1 * aw;

        int sl = lsiA[l];
        // uint-index offsets (2 bf16 per uint; row stride = 128 uints)
        int rb0 = (sl + yi0 * Wl) * 128;
        int rb1 = (sl + yi1 * Wl) * 128;
        offs_s[ql][item] = make_int4(rb0 + xi0 * 128, rb0 + xi1 * 128,
                                     rb1 + xi0 * 128, rb1 + xi1 * 128);
        wts_s[ql][item] = make_float4(gy0 * gx0, gy0 * gx1, gy1 * gx0, gy1 * gx1);
    }
    __syncthreads();

    // ---- phase 2: gather 2 channels per thread ----
    const int ql = tid >> 7;
    const int h = (tid >> 4) & 7;
    const int c2 = tid & 15;
    const unsigned int* vb = (const unsigned int*)valb + h * 16 + c2;
    const int4* op = offs_s[ql] + h * 56;
    const float4* wp = wts_s[ql] + h * 56;
    float acc0 = 0.f, acc1 = 0.f;
#pragma unroll 4
    for (int p = 0; p < 56; ++p) {
        int4 o4 = op[p];
        float4 w4 = wp[p];
        unsigned int u0 = vb[o4.x];
        unsigned int u1 = vb[o4.y];
        unsigned int u2 = vb[o4.z];
        unsigned int u3 = vb[o4.w];
        acc0 += w4.x * u2f_lo(u0); acc1 += w4.x * u2f_hi(u0);
        acc0 += w4.y * u2f_lo(u1); acc1 += w4.y * u2f_hi(u1);
        acc0 += w4.z * u2f_lo(u2); acc1 += w4.z * u2f_hi(u2);
        acc0 += w4.w * u2f_lo(u3); acc1 += w4.w * u2f_hi(u3);
    }
    unsigned int packed = (unsigned int)f2bf(acc0) | ((unsigned int)f2bf(acc1) << 16);
    *(unsigned int*)(ob + (size_t)(q0 + ql) * 256 + h * 32 + c2 * 2) = packed;
}

// ---------------------------------------------------------------------------
extern "C" void kernel_launch(void* const* d_in, const int* in_sizes, int n_in,
                              void* d_out, int out_size, void* d_ws, size_t ws_size,
                              hipStream_t stream)
{
    const float* src    = (const float*)d_in[0];
    const float* pos    = (const float*)d_in[1];
    const float* vr     = (const float*)d_in[4];
    const float* W_samp = (const float*)d_in[5];
    const float* b_samp = (const float*)d_in[6];
    const float* W_tsamp= (const float*)d_in[7];
    const float* b_tsamp= (const float*)d_in[8];
    const float* W_attn = (const float*)d_in[9];
    const float* b_attn = (const float*)d_in[10];
    const float* W_val  = (const float*)d_in[11];
    const float* b_val  = (const float*)d_in[12];
    const float* W_out  = (const float*)d_in[13];
    const float* b_out  = (const float*)d_in[14];
    const float* W_ff1  = (const float*)d_in[15];
    const float* b_ff1  = (const float*)d_in[16];
    const float* W_ff2  = (const float*)d_in[17];
    const float* b_ff2  = (const float*)d_in[18];
    const float* n1g    = (const float*)d_in[19];
    const float* n1b    = (const float*)d_in[20];
    const float* n2g    = (const float*)d_in[21];
    const float* n2b    = (const float*)d_in[22];

    // ---- workspace layout (f32 units) ----
    float* ws = (float*)d_ws;
    ushort* qout  = (ushort*)ws;                         // LQ*1344 bf16
    float* valueR = ws + (size_t)LQ * 672;               // region: LQ*256 f32
    ushort* valb  = (ushort*)valueR;                     // LQ*256 bf16
    ushort* srcb  = (ushort*)(valueR + (size_t)LQ * 256);// LQ*256 bf16
    ushort* qb    = srcb + (size_t)LQ * 256;             // LQ*256 bf16
    ushort* obuf  = qb + (size_t)LQ * 256;               // LQ*256 bf16
    float* ffB    = (float*)(obuf + (size_t)LQ * 256);   // LQ*256 f32 (unused now)
    ushort* Wq    = (ushort*)(ffB + (size_t)LQ * 256);   // 1344*256 bf16
    ushort* Wv    = Wq + 1344 * 256;
    ushort* Wo    = Wv + 256 * 256;
    ushort* Wf1   = Wo + 256 * 256;
    ushort* Wf2   = Wf1 + 1024 * 256;
    float* bq     = (float*)(Wf2 + 1024 * 256);          // 1344 f32
    // region reuse after deform:
    float* xF     = (float*)qout;                        // LQ*256 f32 (qout dead)
    ushort* xB16  = (ushort*)((float*)qout + (size_t)LQ * 256); // LQ*256 bf16
    ushort* hB16  = (ushort*)valueR;                     // LQ*1024 bf16 spans valueR..qb

    // ---- input conversions ----
    cvt_src_q<<<(LQ * 64 + 255) / 256, 256, 0, stream>>>(src, pos, srcb, qb, LQ * 64);
    CvtArgs ca;
    ca.s[0] = W_samp;  ca.d[0] = Wq;             ca.n[0] = 256 * 256;
    ca.s[1] = W_tsamp; ca.d[1] = Wq + 256 * 256; ca.n[1] = 640 * 256;
    ca.s[2] = W_attn;  ca.d[2] = Wq + 896 * 256; ca.n[2] = 448 * 256;
    ca.s[3] = W_val;   ca.d[3] = Wv;             ca.n[3] = 256 * 256;
    ca.s[4] = W_out;   ca.d[4] = Wo;             ca.n[4] = 256 * 256;
    ca.s[5] = W_ff1;   ca.d[5] = Wf1;            ca.n[5] = 1024 * 256;
    ca.s[6] = W_ff2;   ca.d[6] = Wf2;            ca.n[6] = 256 * 1024;
    ca.s[7] = W_ff2;   ca.d[7] = Wf2;            ca.n[7] = 0;   // unused
    cvt_w8<<<dim3(1024, 8), 256, 0, stream>>>(ca);
    hipMemcpyAsync(bq,        b_samp,  256 * sizeof(float), hipMemcpyDeviceToDevice, stream);
    hipMemcpyAsync(bq + 256,  b_tsamp, 640 * sizeof(float), hipMemcpyDeviceToDevice, stream);
    hipMemcpyAsync(bq + 896,  b_attn,  448 * sizeof(float), hipMemcpyDeviceToDevice, stream);

    const int GM = (LQ + 127) / 128;   // 192

    // value = src @ Wv^T (bf16 out); qout = (src+pos) @ Wq^T (bf16 out)
    gemm_mfma<0, 0, 1><<<dim3(4, GM),  256, 0, stream>>>(srcb, Wv, b_val, nullptr, valb, LQ, 256, 256);
    gemm_mfma<0, 0, 1><<<dim3(21, GM), 256, 0, stream>>>(qb, Wq, bq, nullptr, qout, LQ, 1344, 256);

    // deformable attention (bf16 out), 2 queries per block
    deform_kernel<<<LQ / 2, 256, 0, stream>>>(valb, qout, vr, obuf);

    // out-proj + residual + LN1 fused (writes xF f32 + xB16 bf16)
    gemm_ln<1><<<GM, 256, 0, stream>>>(obuf, Wo, b_out, src, n1g, n1b, xF, xB16, LQ, 256);

    // FFN: ff1 (relu, bf16 out) ; ff2 + residual + LN2 fused -> d_out
    gemm_mfma<1, 0, 1><<<dim3(16, GM), 256, 0, stream>>>(xB16, Wf1, b_ff1, nullptr, hB16, LQ, 1024, 256);
    gemm_ln<0><<<GM, 256, 0, stream>>>(hB16, Wf2, b_ff2, xF, n2g, n2b, (float*)d_out, nullptr, LQ, 1024);
}

// Round 6
// 510.372 us; speedup vs baseline: 6.9582x; 1.0004x over previous
//
#include <hip/hip_runtime.h>
#include <hip/hip_bf16.h>
#include <math.h>

#define LQ 24480

typedef short bf16x8 __attribute__((ext_vector_type(8)));   // 8 bf16 = 16B
typedef float f32x4 __attribute__((ext_vector_type(4)));
typedef float f32x4v __attribute__((ext_vector_type(4)));

static __device__ __forceinline__ float bf2f(ushort u) {
    union { unsigned int i; float f; } v; v.i = ((unsigned int)u) << 16; return v.f;
}
static __device__ __forceinline__ ushort f2bf(float f) {
    __hip_bfloat16 h = __float2bfloat16(f);
    return *reinterpret_cast<ushort*>(&h);
}
static __device__ __forceinline__ float u2f_lo(unsigned int u) {
    union { unsigned int i; float f; } v; v.i = u << 16; return v.f;
}
static __device__ __forceinline__ float u2f_hi(unsigned int u) {
    union { unsigned int i; float f; } v; v.i = u & 0xffff0000u; return v.f;
}

// ---------------------------------------------------------------------------
// bf16 MFMA GEMM: C[M,N] = A @ W^T + bias; BM=128 x BN=64 tiles.
// ---------------------------------------------------------------------------
template <int RELU, int WF32, int WBF16>
__global__ __launch_bounds__(256) void gemm_mfma(
    const ushort* __restrict__ A, const ushort* __restrict__ W,
    const float* __restrict__ bias,
    float* __restrict__ Cf, ushort* __restrict__ Cb,
    int M, int N, int K)
{
    const int wave = threadIdx.x >> 6;
    const int lane = threadIdx.x & 63;
    const int r = lane & 15;
    const int kblk = lane >> 4;
    const int bm = blockIdx.y * 128;
    const int bn = blockIdx.x * 64;

    f32x4 acc[2][4] = {};

    int row0 = bm + wave * 32 + r;
    int row1 = row0 + 16;
    row0 = min(row0, M - 1);
    row1 = min(row1, M - 1);
    const ushort* a0p = A + (size_t)row0 * K + kblk * 8;
    const ushort* a1p = A + (size_t)row1 * K + kblk * 8;
    const ushort* bp  = W + (size_t)(bn + r) * K + kblk * 8;
    const size_t nK = (size_t)16 * K;

#pragma unroll 4
    for (int k = 0; k < K; k += 32) {
        bf16x8 a0 = *(const bf16x8*)(a0p + k);
        bf16x8 a1 = *(const bf16x8*)(a1p + k);
        bf16x8 b0 = *(const bf16x8*)(bp + k);
        bf16x8 b1 = *(const bf16x8*)(bp + nK + k);
        bf16x8 b2 = *(const bf16x8*)(bp + 2 * nK + k);
        bf16x8 b3 = *(const bf16x8*)(bp + 3 * nK + k);
        acc[0][0] = __builtin_amdgcn_mfma_f32_16x16x32_bf16(a0, b0, acc[0][0], 0, 0, 0);
        acc[0][1] = __builtin_amdgcn_mfma_f32_16x16x32_bf16(a0, b1, acc[0][1], 0, 0, 0);
        acc[0][2] = __builtin_amdgcn_mfma_f32_16x16x32_bf16(a0, b2, acc[0][2], 0, 0, 0);
        acc[0][3] = __builtin_amdgcn_mfma_f32_16x16x32_bf16(a0, b3, acc[0][3], 0, 0, 0);
        acc[1][0] = __builtin_amdgcn_mfma_f32_16x16x32_bf16(a1, b0, acc[1][0], 0, 0, 0);
        acc[1][1] = __builtin_amdgcn_mfma_f32_16x16x32_bf16(a1, b1, acc[1][1], 0, 0, 0);
        acc[1][2] = __builtin_amdgcn_mfma_f32_16x16x32_bf16(a1, b2, acc[1][2], 0, 0, 0);
        acc[1][3] = __builtin_amdgcn_mfma_f32_16x16x32_bf16(a1, b3, acc[1][3], 0, 0, 0);
    }

    const int orow = (lane >> 4) * 4;
    const int ocol = lane & 15;
#pragma unroll
    for (int mi = 0; mi < 2; ++mi)
#pragma unroll
        for (int ni = 0; ni < 4; ++ni) {
            int cc = bn + ni * 16 + ocol;
            float bv = bias[cc];
#pragma unroll
            for (int j = 0; j < 4; ++j) {
                int rr = bm + wave * 32 + mi * 16 + orow + j;
                if (rr < M) {
                    float v = acc[mi][ni][j] + bv;
                    if (RELU) v = fmaxf(v, 0.f);
                    if (WF32) Cf[(size_t)rr * N + cc] = v;
                    if (WBF16) Cb[(size_t)rr * N + cc] = f2bf(v);
                }
            }
        }
}

// ---------------------------------------------------------------------------
// Fused GEMM (N=256) + residual + LayerNorm.
// out = LN(res + A@W^T + bias) * g + be. BM=128, BN=256 (full row in block).
// Wave owns 32 rows x 256 cols: acc[2][16] f32x4. LN reduce: 16 in-register
// adds + shfl_xor width-16 (lanes 0..15 of each quarter hold the row's cols).
// ---------------------------------------------------------------------------
template <int WBF16>
__global__ __launch_bounds__(256) void gemm_ln(
    const ushort* __restrict__ A, const ushort* __restrict__ W,
    const float* __restrict__ bias, const float* __restrict__ res,
    const float* __restrict__ g, const float* __restrict__ be,
    float* __restrict__ outF, ushort* __restrict__ outB,
    int M, int K)
{
    const int wave = threadIdx.x >> 6;
    const int lane = threadIdx.x & 63;
    const int r = lane & 15;
    const int kblk = lane >> 4;
    const int bm = blockIdx.x * 128;

    f32x4 acc[2][16] = {};

    int row0 = bm + wave * 32 + r;
    int row1 = row0 + 16;
    row0 = min(row0, M - 1);
    row1 = min(row1, M - 1);
    const ushort* ap0 = A + (size_t)row0 * K + kblk * 8;
    const ushort* ap1 = A + (size_t)row1 * K + kblk * 8;
    const ushort* bp  = W + (size_t)r * K + kblk * 8;
    const size_t nK = (size_t)16 * K;

#pragma unroll 2
    for (int k = 0; k < K; k += 32) {
        bf16x8 a0 = *(const bf16x8*)(ap0 + k);
        bf16x8 a1 = *(const bf16x8*)(ap1 + k);
#pragma unroll
        for (int ni = 0; ni < 16; ++ni) {
            bf16x8 b = *(const bf16x8*)(bp + (size_t)ni * nK + k);
            acc[0][ni] = __builtin_amdgcn_mfma_f32_16x16x32_bf16(a0, b, acc[0][ni], 0, 0, 0);
            acc[1][ni] = __builtin_amdgcn_mfma_f32_16x16x32_bf16(a1, b, acc[1][ni], 0, 0, 0);
        }
    }

    const int orow = kblk * 4;
    const int ocol = r;

    float bv[16];
#pragma unroll
    for (int ni = 0; ni < 16; ++ni) bv[ni] = bias[ni * 16 + ocol];

    float mean_[2][4], rstd_[2][4];
#pragma unroll
    for (int mi = 0; mi < 2; ++mi)
#pragma unroll
        for (int j = 0; j < 4; ++j) {
            int rr = bm + wave * 32 + mi * 16 + orow + j;
            int rl = min(rr, M - 1);
            const float* rp = res + (size_t)rl * 256 + ocol;
            float s = 0.f, s2 = 0.f;
#pragma unroll
            for (int ni = 0; ni < 16; ++ni) {
                float v = acc[mi][ni][j] + bv[ni] + rp[ni * 16];
                acc[mi][ni][j] = v;
                s += v; s2 += v * v;
            }
#pragma unroll
            for (int off = 8; off; off >>= 1) {
                s  += __shfl_xor(s,  off, 16);
                s2 += __shfl_xor(s2, off, 16);
            }
            float mu = s * (1.f / 256.f);
            float var = s2 * (1.f / 256.f) - mu * mu;
            mean_[mi][j] = mu;
            rstd_[mi][j] = rsqrtf(var + 1e-5f);
        }

    float gv[16], bev[16];
#pragma unroll
    for (int ni = 0; ni < 16; ++ni) {
        gv[ni] = g[ni * 16 + ocol];
        bev[ni] = be[ni * 16 + ocol];
    }

#pragma unroll
    for (int mi = 0; mi < 2; ++mi)
#pragma unroll
        for (int j = 0; j < 4; ++j) {
            int rr = bm + wave * 32 + mi * 16 + orow + j;
            if (rr < M) {
#pragma unroll
                for (int ni = 0; ni < 16; ++ni) {
                    float o = (acc[mi][ni][j] - mean_[mi][j]) * rstd_[mi][j] * gv[ni] + bev[ni];
                    outF[(size_t)rr * 256 + ni * 16 + ocol] = o;
                    if (WBF16) outB[(size_t)rr * 256 + ni * 16 + ocol] = f2bf(o);
                }
            }
        }
}

// ---------------------------------------------------------------------------
// src/q -> bf16 (vectorized), q = src + pos
// ---------------------------------------------------------------------------
__global__ __launch_bounds__(256) void cvt_src_q(
    const float* __restrict__ src, const float* __restrict__ pos,
    ushort* __restrict__ srcb, ushort* __restrict__ qb, int n4)
{
    int i = blockIdx.x * 256 + threadIdx.x;
    if (i >= n4) return;
    f32x4v s = *(const f32x4v*)(src + (size_t)i * 4);
    f32x4v p = *(const f32x4v*)(pos + (size_t)i * 4);
    ushort us[4], uq[4];
#pragma unroll
    for (int j = 0; j < 4; ++j) { us[j] = f2bf(s[j]); uq[j] = f2bf(s[j] + p[j]); }
    *(ulong1*)(srcb + (size_t)i * 4) = *(ulong1*)us;
    *(ulong1*)(qb   + (size_t)i * 4) = *(ulong1*)uq;
}

// all weight conversions in ONE launch: seg = blockIdx.y
struct CvtArgs { const float* s[8]; ushort* d[8]; int n[8]; };
__global__ __launch_bounds__(256) void cvt_w8(CvtArgs a)
{
    int seg = blockIdx.y;
    int i = blockIdx.x * 256 + threadIdx.x;
    if (i < a.n[seg]) a.d[seg][i] = f2bf(a.s[seg][i]);
}

// ---------------------------------------------------------------------------
// Deformable attention, phase-split, 2 queries per block, 2 channels/thread.
// Phase 0: softmax (16-lane groups, one per (query, head)).
// Phase 1: 896 items -> 4 offsets (uint-index) + 4 aw-premultiplied weights.
// Phase 2: thread (ql,h,c2) gathers uint (2xbf16) corners, 2 channels.
// ---------------------------------------------------------------------------
__global__ __launch_bounds__(256) void deform_kernel(
    const ushort* __restrict__ valb,   // [LQ,256] bf16
    const ushort* __restrict__ qout,   // [LQ,1344] bf16: samp|tsamp|logits
    const float* __restrict__ vr,      // [4,2]
    ushort* __restrict__ ob)           // [LQ,256] bf16
{
    const int q0 = blockIdx.x * 2;
    const int tid = threadIdx.x;

    __shared__ float  aw_s[2][448];
    __shared__ int4   offs_s[2][448];
    __shared__ float4 wts_s[2][448];

    const int lsiA[4] = {0, 18432, 23040, 24192};

    // ---- phase 0: softmax, group = (ql,h) = tid>>4, lanes = tid&15 ----
    {
        int grp = tid >> 4;
        int ql = grp >> 3, h = grp & 7;
        int ln = tid & 15;
        const ushort* lg = qout + (size_t)(q0 + ql) * 1344 + 896 + h * 56;
        float l0 = bf2f(lg[ln]);
        float l1 = bf2f(lg[16 + ln]);
        float l2 = bf2f(lg[32 + ln]);
        float l3 = (ln < 8) ? bf2f(lg[48 + ln]) : -1e30f;
        float m = fmaxf(fmaxf(l0, l1), fmaxf(l2, l3));
#pragma unroll
        for (int off = 8; off; off >>= 1) m = fmaxf(m, __shfl_xor(m, off, 16));
        float e0 = expf(l0 - m), e1 = expf(l1 - m), e2 = expf(l2 - m);
        float e3 = (ln < 8) ? expf(l3 - m) : 0.f;
        float s = e0 + e1 + e2 + e3;
#pragma unroll
        for (int off = 8; off; off >>= 1) s += __shfl_xor(s, off, 16);
        float inv = 1.f / s;
        aw_s[ql][h * 56 + ln]      = e0 * inv;
        aw_s[ql][h * 56 + 16 + ln] = e1 * inv;
        aw_s[ql][h * 56 + 32 + ln] = e2 * inv;
        if (ln < 8) aw_s[ql][h * 56 + 48 + ln] = e3 * inv;
    }
    __syncthreads();

    // ---- phase 1: coords for 2x448 items ----
    for (int it = tid; it < 896; it += 256) {
        int ql = (it >= 448) ? 1 : 0;
        int item = it - ql * 448;
        int q = q0 + ql;

        int lq = (q >= 24192) ? 3 : (q >= 23040) ? 2 : (q >= 18432) ? 1 : 0;
        int qi = q - lsiA[lq];
        int Wq = 64 >> lq;
        int iy = qi >> (6 - lq);
        int jx = qi & (Wq - 1);
        int Hq = 48 >> lq;
        int tq = iy / Hq;
        float rx_base = ((float)jx + 0.5f) / (vr[2 * lq + 0] * (float)Wq);
        float ry_base = ((float)iy + 0.5f) / (vr[2 * lq + 1] * (float)(Hq * 6));

        int h = item / 56;
        int p = item - h * 56;
        int l = p / 14;
        int pp = p - l * 14;

        int Wl = 64 >> l;
        int Hl = 48 >> l;
        int Htl = Hl * 6;
        float vrx = vr[2 * l], vry = vr[2 * l + 1];

        const ushort* qrow = qout + (size_t)q * 1344;
        float ox, oy, ty;
        if (pp < 4) {
            ox = bf2f(qrow[h * 32 + l * 8 + pp * 2]);
            oy = bf2f(qrow[h * 32 + l * 8 + pp * 2 + 1]);
            ty = 0.f;
        } else {
            int pq = pp - 4;
            int tw = pq >> 1, nt = pq & 1;
            int tt = (tw < tq) ? tw : tw + 1;
            ty = (float)(tt - tq) * vry * (float)Hl;
            ox = bf2f(qrow[256 + h * 80 + l * 20 + tw * 4 + nt * 2]);
            oy = bf2f(qrow[256 + h * 80 + l * 20 + tw * 4 + nt * 2 + 1]);
        }
        float x = rx_base * vrx * (float)Wl - 0.5f + ox;
        float y = ry_base * vry * (float)Htl - 0.5f + ty + oy;
        float x0f = floorf(x), y0f = floorf(y);
        int x0 = (int)x0f, y0 = (int)y0f;
        float fx = x - x0f, fy = y - y0f;

        int xi0 = min(max(x0, 0), Wl - 1);
        int xi1 = min(max(x0 + 1, 0), Wl - 1);
        int yi0 = min(max(y0, 0), Htl - 1);
        int yi1 = min(max(y0 + 1, 0), Htl - 1);
        float mx0 = (x0 >= 0 && x0 < Wl) ? 1.f : 0.f;
        float mx1 = (x0 >= -1 && x0 + 1 < Wl) ? 1.f : 0.f;
        float my0 = (y0 >= 0 && y0 < Htl) ? 1.f : 0.f;
        float my1 = (y0 >= -1 && y0 + 1 < Htl) ? 1.f : 0.f;

        float aw = aw_s[ql][item];
        float gx0 = (1.f - fx) * mx0;
        float gx1 = fx * mx1;
        float gy0 = (1.f - fy) * my0 * aw;
        float gy1 = fy * my1 * aw;

        int sl = lsiA[l];
        // uint-index offsets (2 bf16 per uint; row stride = 128 uints)
        int rb0 = (sl + yi0 * Wl) * 128;
        int rb1 = (sl + yi1 * Wl) * 128;
        offs_s[ql][item] = make_int4(rb0 + xi0 * 128, rb0 + xi1 * 128,
                                     rb1 + xi0 * 128, rb1 + xi1 * 128);
        wts_s[ql][item] = make_float4(gy0 * gx0, gy0 * gx1, gy1 * gx0, gy1 * gx1);
    }
    __syncthreads();

    // ---- phase 2: gather 2 channels per thread ----
    const int ql = tid >> 7;
    const int h = (tid >> 4) & 7;
    const int c2 = tid & 15;
    const unsigned int* vb = (const unsigned int*)valb + h * 16 + c2;
    const int4* op = offs_s[ql] + h * 56;
    const float4* wp = wts_s[ql] + h * 56;
    float acc0 = 0.f, acc1 = 0.f;
#pragma unroll 4
    for (int p = 0; p < 56; ++p) {
        int4 o4 = op[p];
        float4 w4 = wp[p];
        unsigned int u0 = vb[o4.x];
        unsigned int u1 = vb[o4.y];
        unsigned int u2 = vb[o4.z];
        unsigned int u3 = vb[o4.w];
        acc0 += w4.x * u2f_lo(u0); acc1 += w4.x * u2f_hi(u0);
        acc0 += w4.y * u2f_lo(u1); acc1 += w4.y * u2f_hi(u1);
        acc0 += w4.z * u2f_lo(u2); acc1 += w4.z * u2f_hi(u2);
        acc0 += w4.w * u2f_lo(u3); acc1 += w4.w * u2f_hi(u3);
    }
    unsigned int packed = (unsigned int)f2bf(acc0) | ((unsigned int)f2bf(acc1) << 16);
    *(unsigned int*)(ob + (size_t)(q0 + ql) * 256 + h * 32 + c2 * 2) = packed;
}

// ---------------------------------------------------------------------------
extern "C" void kernel_launch(void* const* d_in, const int* in_sizes, int n_in,
                              void* d_out, int out_size, void* d_ws, size_t ws_size,
                              hipStream_t stream)
{
    const float* src    = (const float*)d_in[0];
    const float* pos    = (const float*)d_in[1];
    const float* vr     = (const float*)d_in[4];
    const float* W_samp = (const float*)d_in[5];
    const float* b_samp = (const float*)d_in[6];
    const float* W_tsamp= (const float*)d_in[7];
    const float* b_tsamp= (const float*)d_in[8];
    const float* W_attn = (const float*)d_in[9];
    const float* b_attn = (const float*)d_in[10];
    const float* W_val  = (const float*)d_in[11];
    const float* b_val  = (const float*)d_in[12];
    const float* W_out  = (const float*)d_in[13];
    const float* b_out  = (const float*)d_in[14];
    const float* W_ff1  = (const float*)d_in[15];
    const float* b_ff1  = (const float*)d_in[16];
    const float* W_ff2  = (const float*)d_in[17];
    const float* b_ff2  = (const float*)d_in[18];
    const float* n1g    = (const float*)d_in[19];
    const float* n1b    = (const float*)d_in[20];
    const float* n2g    = (const float*)d_in[21];
    const float* n2b    = (const float*)d_in[22];

    // ---- workspace layout (f32 units) ----
    float* ws = (float*)d_ws;
    ushort* qout  = (ushort*)ws;                         // LQ*1344 bf16
    float* valueR = ws + (size_t)LQ * 672;               // region: LQ*256 f32
    ushort* valb  = (ushort*)valueR;                     // LQ*256 bf16
    ushort* srcb  = (ushort*)(valueR + (size_t)LQ * 256);// LQ*256 bf16
    ushort* qb    = srcb + (size_t)LQ * 256;             // LQ*256 bf16
    ushort* obuf  = qb + (size_t)LQ * 256;               // LQ*256 bf16
    float* ffB    = (float*)(obuf + (size_t)LQ * 256);   // LQ*256 f32 (unused now)
    ushort* Wq    = (ushort*)(ffB + (size_t)LQ * 256);   // 1344*256 bf16
    ushort* Wv    = Wq + 1344 * 256;
    ushort* Wo    = Wv + 256 * 256;
    ushort* Wf1   = Wo + 256 * 256;
    ushort* Wf2   = Wf1 + 1024 * 256;
    float* bq     = (float*)(Wf2 + 1024 * 256);          // 1344 f32
    // region reuse after deform:
    float* xF     = (float*)qout;                        // LQ*256 f32 (qout dead)
    ushort* xB16  = (ushort*)((float*)qout + (size_t)LQ * 256); // LQ*256 bf16
    ushort* hB16  = (ushort*)valueR;                     // LQ*1024 bf16 spans valueR..qb

    // ---- input conversions ----
    cvt_src_q<<<(LQ * 64 + 255) / 256, 256, 0, stream>>>(src, pos, srcb, qb, LQ * 64);
    CvtArgs ca;
    ca.s[0] = W_samp;  ca.d[0] = Wq;             ca.n[0] = 256 * 256;
    ca.s[1] = W_tsamp; ca.d[1] = Wq + 256 * 256; ca.n[1] = 640 * 256;
    ca.s[2] = W_attn;  ca.d[2] = Wq + 896 * 256; ca.n[2] = 448 * 256;
    ca.s[3] = W_val;   ca.d[3] = Wv;             ca.n[3] = 256 * 256;
    ca.s[4] = W_out;   ca.d[4] = Wo;             ca.n[4] = 256 * 256;
    ca.s[5] = W_ff1;   ca.d[5] = Wf1;            ca.n[5] = 1024 * 256;
    ca.s[6] = W_ff2;   ca.d[6] = Wf2;            ca.n[6] = 256 * 1024;
    ca.s[7] = W_ff2;   ca.d[7] = Wf2;            ca.n[7] = 0;   // unused
    cvt_w8<<<dim3(1024, 8), 256, 0, stream>>>(ca);
    hipMemcpyAsync(bq,        b_samp,  256 * sizeof(float), hipMemcpyDeviceToDevice, stream);
    hipMemcpyAsync(bq + 256,  b_tsamp, 640 * sizeof(float), hipMemcpyDeviceToDevice, stream);
    hipMemcpyAsync(bq + 896,  b_attn,  448 * sizeof(float), hipMemcpyDeviceToDevice, stream);

    const int GM = (LQ + 127) / 128;   // 192

    // value = src @ Wv^T (bf16 out); qout = (src+pos) @ Wq^T (bf16 out)
    gemm_mfma<0, 0, 1><<<dim3(4, GM),  256, 0, stream>>>(srcb, Wv, b_val, nullptr, valb, LQ, 256, 256);
    gemm_mfma<0, 0, 1><<<dim3(21, GM), 256, 0, stream>>>(qb, Wq, bq, nullptr, qout, LQ, 1344, 256);

    // deformable attention (bf16 out), 2 queries per block
    deform_kernel<<<LQ / 2, 256, 0, stream>>>(valb, qout, vr, obuf);

    // out-proj + residual + LN1 fused (writes xF f32 + xB16 bf16)
    gemm_ln<1><<<GM, 256, 0, stream>>>(obuf, Wo, b_out, src, n1g, n1b, xF, xB16, LQ, 256);

    // FFN: ff1 (relu, bf16 out) ; ff2 + residual + LN2 fused -> d_out
    gemm_mfma<1, 0, 1><<<dim3(16, GM), 256, 0, stream>>>(xB16, Wf1, b_ff1, nullptr, hB16, LQ, 1024, 256);
    gemm_ln<0><<<GM, 256, 0, stream>>>(hB16, Wf2, b_ff2, xF, n2g, n2b, (float*)d_out, nullptr, LQ, 1024);
}

// Round 7
// 463.392 us; speedup vs baseline: 7.6636x; 1.1014x over previous
//
#include <hip/hip_runtime.h>
#include <hip/hip_bf16.h>
#include <math.h>

#define LQ 24480

typedef short bf16x8 __attribute__((ext_vector_type(8)));   // 8 bf16 = 16B
typedef float f32x4 __attribute__((ext_vector_type(4)));
typedef float f32x4v __attribute__((ext_vector_type(4)));

static __device__ __forceinline__ float bf2f(ushort u) {
    union { unsigned int i; float f; } v; v.i = ((unsigned int)u) << 16; return v.f;
}
static __device__ __forceinline__ ushort f2bf(float f) {
    __hip_bfloat16 h = __float2bfloat16(f);
    return *reinterpret_cast<ushort*>(&h);
}
static __device__ __forceinline__ float u2f_lo(unsigned int u) {
    union { unsigned int i; float f; } v; v.i = u << 16; return v.f;
}
static __device__ __forceinline__ float u2f_hi(unsigned int u) {
    union { unsigned int i; float f; } v; v.i = u & 0xffff0000u; return v.f;
}

// ---------------------------------------------------------------------------
// GEMM core body (BM=128 x BN=64), shared by gemm_mfma and gemm_valq.
// ---------------------------------------------------------------------------
template <int RELU, int WF32, int WBF16>
static __device__ __forceinline__ void gemm_body(
    const ushort* __restrict__ A, const ushort* __restrict__ W,
    const float* __restrict__ bias,
    float* __restrict__ Cf, ushort* __restrict__ Cb,
    int M, int N, int K, int bm, int bn, int wave, int lane)
{
    const int r = lane & 15;
    const int kblk = lane >> 4;

    f32x4 acc[2][4] = {};

    int row0 = bm + wave * 32 + r;
    int row1 = row0 + 16;
    row0 = min(row0, M - 1);
    row1 = min(row1, M - 1);
    const ushort* a0p = A + (size_t)row0 * K + kblk * 8;
    const ushort* a1p = A + (size_t)row1 * K + kblk * 8;
    const ushort* bp  = W + (size_t)(bn + r) * K + kblk * 8;
    const size_t nK = (size_t)16 * K;

#pragma unroll 4
    for (int k = 0; k < K; k += 32) {
        bf16x8 a0 = *(const bf16x8*)(a0p + k);
        bf16x8 a1 = *(const bf16x8*)(a1p + k);
        bf16x8 b0 = *(const bf16x8*)(bp + k);
        bf16x8 b1 = *(const bf16x8*)(bp + nK + k);
        bf16x8 b2 = *(const bf16x8*)(bp + 2 * nK + k);
        bf16x8 b3 = *(const bf16x8*)(bp + 3 * nK + k);
        acc[0][0] = __builtin_amdgcn_mfma_f32_16x16x32_bf16(a0, b0, acc[0][0], 0, 0, 0);
        acc[0][1] = __builtin_amdgcn_mfma_f32_16x16x32_bf16(a0, b1, acc[0][1], 0, 0, 0);
        acc[0][2] = __builtin_amdgcn_mfma_f32_16x16x32_bf16(a0, b2, acc[0][2], 0, 0, 0);
        acc[0][3] = __builtin_amdgcn_mfma_f32_16x16x32_bf16(a0, b3, acc[0][3], 0, 0, 0);
        acc[1][0] = __builtin_amdgcn_mfma_f32_16x16x32_bf16(a1, b0, acc[1][0], 0, 0, 0);
        acc[1][1] = __builtin_amdgcn_mfma_f32_16x16x32_bf16(a1, b1, acc[1][1], 0, 0, 0);
        acc[1][2] = __builtin_amdgcn_mfma_f32_16x16x32_bf16(a1, b2, acc[1][2], 0, 0, 0);
        acc[1][3] = __builtin_amdgcn_mfma_f32_16x16x32_bf16(a1, b3, acc[1][3], 0, 0, 0);
    }

    const int orow = kblk * 4;
    const int ocol = r;
#pragma unroll
    for (int mi = 0; mi < 2; ++mi)
#pragma unroll
        for (int ni = 0; ni < 4; ++ni) {
            int cc = bn + ni * 16 + ocol;
            float bv = bias[cc];
#pragma unroll
            for (int j = 0; j < 4; ++j) {
                int rr = bm + wave * 32 + mi * 16 + orow + j;
                if (rr < M) {
                    float v = acc[mi][ni][j] + bv;
                    if (RELU) v = fmaxf(v, 0.f);
                    if (WF32) Cf[(size_t)rr * N + cc] = v;
                    if (WBF16) Cb[(size_t)rr * N + cc] = f2bf(v);
                }
            }
        }
}

template <int RELU, int WF32, int WBF16>
__global__ __launch_bounds__(256) void gemm_mfma(
    const ushort* __restrict__ A, const ushort* __restrict__ W,
    const float* __restrict__ bias,
    float* __restrict__ Cf, ushort* __restrict__ Cb,
    int M, int N, int K)
{
    gemm_body<RELU, WF32, WBF16>(A, W, bias, Cf, Cb, M, N, K,
                                 blockIdx.y * 128, blockIdx.x * 64,
                                 threadIdx.x >> 6, threadIdx.x & 63);
}

// Fused value-proj (cols 0..255 -> valb) + q-proj (1344 cols -> qout).
__global__ __launch_bounds__(256) void gemm_valq(
    const ushort* __restrict__ srcb, const ushort* __restrict__ qb,
    const ushort* __restrict__ Wv, const ushort* __restrict__ Wq,
    const float* __restrict__ b_val, const float* __restrict__ bq,
    ushort* __restrict__ valb, ushort* __restrict__ qout)
{
    const int bx = blockIdx.x;   // 0..24
    if (bx < 4) {
        gemm_body<0, 0, 1>(srcb, Wv, b_val, nullptr, valb, LQ, 256, 256,
                           blockIdx.y * 128, bx * 64,
                           threadIdx.x >> 6, threadIdx.x & 63);
    } else {
        gemm_body<0, 0, 1>(qb, Wq, bq, nullptr, qout, LQ, 1344, 256,
                           blockIdx.y * 128, (bx - 4) * 64,
                           threadIdx.x >> 6, threadIdx.x & 63);
    }
}

// ---------------------------------------------------------------------------
// Fused GEMM (N=256) + residual + LayerNorm.
// ---------------------------------------------------------------------------
template <int WBF16>
__global__ __launch_bounds__(256) void gemm_ln(
    const ushort* __restrict__ A, const ushort* __restrict__ W,
    const float* __restrict__ bias, const float* __restrict__ res,
    const float* __restrict__ g, const float* __restrict__ be,
    float* __restrict__ outF, ushort* __restrict__ outB,
    int M, int K)
{
    const int wave = threadIdx.x >> 6;
    const int lane = threadIdx.x & 63;
    const int r = lane & 15;
    const int kblk = lane >> 4;
    const int bm = blockIdx.x * 128;

    f32x4 acc[2][16] = {};

    int row0 = bm + wave * 32 + r;
    int row1 = row0 + 16;
    row0 = min(row0, M - 1);
    row1 = min(row1, M - 1);
    const ushort* ap0 = A + (size_t)row0 * K + kblk * 8;
    const ushort* ap1 = A + (size_t)row1 * K + kblk * 8;
    const ushort* bp  = W + (size_t)r * K + kblk * 8;
    const size_t nK = (size_t)16 * K;

#pragma unroll 2
    for (int k = 0; k < K; k += 32) {
        bf16x8 a0 = *(const bf16x8*)(ap0 + k);
        bf16x8 a1 = *(const bf16x8*)(ap1 + k);
#pragma unroll
        for (int ni = 0; ni < 16; ++ni) {
            bf16x8 b = *(const bf16x8*)(bp + (size_t)ni * nK + k);
            acc[0][ni] = __builtin_amdgcn_mfma_f32_16x16x32_bf16(a0, b, acc[0][ni], 0, 0, 0);
            acc[1][ni] = __builtin_amdgcn_mfma_f32_16x16x32_bf16(a1, b, acc[1][ni], 0, 0, 0);
        }
    }

    const int orow = kblk * 4;
    const int ocol = r;

    float bv[16];
#pragma unroll
    for (int ni = 0; ni < 16; ++ni) bv[ni] = bias[ni * 16 + ocol];

    float mean_[2][4], rstd_[2][4];
#pragma unroll
    for (int mi = 0; mi < 2; ++mi)
#pragma unroll
        for (int j = 0; j < 4; ++j) {
            int rr = bm + wave * 32 + mi * 16 + orow + j;
            int rl = min(rr, M - 1);
            const float* rp = res + (size_t)rl * 256 + ocol;
            float s = 0.f, s2 = 0.f;
#pragma unroll
            for (int ni = 0; ni < 16; ++ni) {
                float v = acc[mi][ni][j] + bv[ni] + rp[ni * 16];
                acc[mi][ni][j] = v;
                s += v; s2 += v * v;
            }
#pragma unroll
            for (int off = 8; off; off >>= 1) {
                s  += __shfl_xor(s,  off, 16);
                s2 += __shfl_xor(s2, off, 16);
            }
            float mu = s * (1.f / 256.f);
            float var = s2 * (1.f / 256.f) - mu * mu;
            mean_[mi][j] = mu;
            rstd_[mi][j] = rsqrtf(var + 1e-5f);
        }

    float gv[16], bev[16];
#pragma unroll
    for (int ni = 0; ni < 16; ++ni) {
        gv[ni] = g[ni * 16 + ocol];
        bev[ni] = be[ni * 16 + ocol];
    }

#pragma unroll
    for (int mi = 0; mi < 2; ++mi)
#pragma unroll
        for (int j = 0; j < 4; ++j) {
            int rr = bm + wave * 32 + mi * 16 + orow + j;
            if (rr < M) {
#pragma unroll
                for (int ni = 0; ni < 16; ++ni) {
                    float o = (acc[mi][ni][j] - mean_[mi][j]) * rstd_[mi][j] * gv[ni] + bev[ni];
                    outF[(size_t)rr * 256 + ni * 16 + ocol] = o;
                    if (WBF16) outB[(size_t)rr * 256 + ni * 16 + ocol] = f2bf(o);
                }
            }
        }
}

// ---------------------------------------------------------------------------
// src/q -> bf16 (vectorized), q = src + pos
// ---------------------------------------------------------------------------
__global__ __launch_bounds__(256) void cvt_src_q(
    const float* __restrict__ src, const float* __restrict__ pos,
    ushort* __restrict__ srcb, ushort* __restrict__ qb, int n4)
{
    int i = blockIdx.x * 256 + threadIdx.x;
    if (i >= n4) return;
    f32x4v s = *(const f32x4v*)(src + (size_t)i * 4);
    f32x4v p = *(const f32x4v*)(pos + (size_t)i * 4);
    ushort us[4], uq[4];
#pragma unroll
    for (int j = 0; j < 4; ++j) { us[j] = f2bf(s[j]); uq[j] = f2bf(s[j] + p[j]); }
    *(ulong1*)(srcb + (size_t)i * 4) = *(ulong1*)us;
    *(ulong1*)(qb   + (size_t)i * 4) = *(ulong1*)uq;
}

// weight conversions + bias concat in ONE launch: seg = blockIdx.y
struct CvtArgs { const float* s[11]; void* d[11]; int n[11]; int isbf[11]; };
__global__ __launch_bounds__(256) void cvt_multi(CvtArgs a)
{
    int seg = blockIdx.y;
    int i = blockIdx.x * 256 + threadIdx.x;
    if (i >= a.n[seg]) return;
    float v = a.s[seg][i];
    if (a.isbf[seg]) ((ushort*)a.d[seg])[i] = f2bf(v);
    else             ((float*)a.d[seg])[i]  = v;
}

// ---------------------------------------------------------------------------
// Deformable attention, phase-split, 2 queries/block, 2 channels/thread.
// Phase 1 stores corner offsets in BYTES; phase 2 uses uniform-base + 32-bit
// voffset loads (SADDR form: 1 VALU add per corner instead of 64-bit math).
// ---------------------------------------------------------------------------
__global__ __launch_bounds__(256) void deform_kernel(
    const ushort* __restrict__ valb,   // [LQ,256] bf16
    const ushort* __restrict__ qout,   // [LQ,1344] bf16: samp|tsamp|logits
    const float* __restrict__ vr,      // [4,2]
    ushort* __restrict__ ob)           // [LQ,256] bf16
{
    const int q0 = blockIdx.x * 2;
    const int tid = threadIdx.x;

    __shared__ float  aw_s[2][448];
    __shared__ int4   offs_s[2][448];
    __shared__ float4 wts_s[2][448];

    const int lsiA[4] = {0, 18432, 23040, 24192};

    // ---- phase 0: softmax, group = (ql,h) = tid>>4, lanes = tid&15 ----
    {
        int grp = tid >> 4;
        int ql = grp >> 3, h = grp & 7;
        int ln = tid & 15;
        const ushort* lg = qout + (size_t)(q0 + ql) * 1344 + 896 + h * 56;
        float l0 = bf2f(lg[ln]);
        float l1 = bf2f(lg[16 + ln]);
        float l2 = bf2f(lg[32 + ln]);
        float l3 = (ln < 8) ? bf2f(lg[48 + ln]) : -1e30f;
        float m = fmaxf(fmaxf(l0, l1), fmaxf(l2, l3));
#pragma unroll
        for (int off = 8; off; off >>= 1) m = fmaxf(m, __shfl_xor(m, off, 16));
        float e0 = expf(l0 - m), e1 = expf(l1 - m), e2 = expf(l2 - m);
        float e3 = (ln < 8) ? expf(l3 - m) : 0.f;
        float s = e0 + e1 + e2 + e3;
#pragma unroll
        for (int off = 8; off; off >>= 1) s += __shfl_xor(s, off, 16);
        float inv = 1.f / s;
        aw_s[ql][h * 56 + ln]      = e0 * inv;
        aw_s[ql][h * 56 + 16 + ln] = e1 * inv;
        aw_s[ql][h * 56 + 32 + ln] = e2 * inv;
        if (ln < 8) aw_s[ql][h * 56 + 48 + ln] = e3 * inv;
    }

    // ---- hoisted per-query geometry (q0, q0+1 share the level) ----
    int lqv = (q0 >= 24192) ? 3 : (q0 >= 23040) ? 2 : (q0 >= 18432) ? 1 : 0;
    int Wqv = 64 >> lqv, Hqv = 48 >> lqv;
    int slq = lsiA[lqv];
    float vrxq = vr[2 * lqv], vryq = vr[2 * lqv + 1];
    float rxb0, ryb0, rxb1, ryb1; int tq0, tq1;
    {
        int qi = q0 - slq;
        int iy = qi >> (6 - lqv);
        int jx = qi & (Wqv - 1);
        tq0 = iy / Hqv;
        rxb0 = ((float)jx + 0.5f) / (vrxq * (float)Wqv);
        ryb0 = ((float)iy + 0.5f) / (vryq * (float)(Hqv * 6));
        qi += 1;
        iy = qi >> (6 - lqv);
        jx = qi & (Wqv - 1);
        tq1 = iy / Hqv;
        rxb1 = ((float)jx + 0.5f) / (vrxq * (float)Wqv);
        ryb1 = ((float)iy + 0.5f) / (vryq * (float)(Hqv * 6));
    }
    __syncthreads();

    // ---- phase 1: coords for 2x448 items ----
    for (int it = tid; it < 896; it += 256) {
        int ql = (it >= 448) ? 1 : 0;
        int item = it - ql * 448;
        float rx_base = ql ? rxb1 : rxb0;
        float ry_base = ql ? ryb1 : ryb0;
        int tq = ql ? tq1 : tq0;

        int h = item / 56;
        int p = item - h * 56;
        int l = p / 14;
        int pp = p - l * 14;

        int Wl = 64 >> l;
        int Hl = 48 >> l;
        int Htl = Hl * 6;
        float vrx = vr[2 * l], vry = vr[2 * l + 1];

        const ushort* qrow = qout + (size_t)(q0 + ql) * 1344;
        float ox, oy, ty;
        if (pp < 4) {
            ox = bf2f(qrow[h * 32 + l * 8 + pp * 2]);
            oy = bf2f(qrow[h * 32 + l * 8 + pp * 2 + 1]);
            ty = 0.f;
        } else {
            int pq = pp - 4;
            int tw = pq >> 1, nt = pq & 1;
            int tt = (tw < tq) ? tw : tw + 1;
            ty = (float)(tt - tq) * vry * (float)Hl;
            ox = bf2f(qrow[256 + h * 80 + l * 20 + tw * 4 + nt * 2]);
            oy = bf2f(qrow[256 + h * 80 + l * 20 + tw * 4 + nt * 2 + 1]);
        }
        float x = rx_base * vrx * (float)Wl - 0.5f + ox;
        float y = ry_base * vry * (float)Htl - 0.5f + ty + oy;
        float x0f = floorf(x), y0f = floorf(y);
        int x0 = (int)x0f, y0 = (int)y0f;
        float fx = x - x0f, fy = y - y0f;

        int xi0 = min(max(x0, 0), Wl - 1);
        int xi1 = min(max(x0 + 1, 0), Wl - 1);
        int yi0 = min(max(y0, 0), Htl - 1);
        int yi1 = min(max(y0 + 1, 0), Htl - 1);
        float mx0 = (x0 >= 0 && x0 < Wl) ? 1.f : 0.f;
        float mx1 = (x0 >= -1 && x0 + 1 < Wl) ? 1.f : 0.f;
        float my0 = (y0 >= 0 && y0 < Htl) ? 1.f : 0.f;
        float my1 = (y0 >= -1 && y0 + 1 < Htl) ? 1.f : 0.f;

        float aw = aw_s[ql][item];
        float gx0 = (1.f - fx) * mx0;
        float gx1 = fx * mx1;
        float gy0 = (1.f - fy) * my0 * aw;
        float gy1 = fy * my1 * aw;

        int sl = lsiA[l];
        // BYTE offsets into valb (row = 256 bf16 = 512 B)
        int rb0 = (sl + yi0 * Wl) * 512;
        int rb1 = (sl + yi1 * Wl) * 512;
        offs_s[ql][item] = make_int4(rb0 + xi0 * 512, rb0 + xi1 * 512,
                                     rb1 + xi0 * 512, rb1 + xi1 * 512);
        wts_s[ql][item] = make_float4(gy0 * gx0, gy0 * gx1, gy1 * gx0, gy1 * gx1);
    }
    __syncthreads();

    // ---- phase 2: gather 2 channels per thread (SADDR 32-bit voffsets) ----
    const int ql = tid >> 7;
    const int h = (tid >> 4) & 7;
    const int c2 = tid & 15;
    const unsigned laneByte = (unsigned)(h * 64 + c2 * 4);
    const char* vbase = (const char*)valb;
    const int4* op = offs_s[ql] + h * 56;
    const float4* wp = wts_s[ql] + h * 56;
    float acc0 = 0.f, acc1 = 0.f;
#pragma unroll 8
    for (int p = 0; p < 56; ++p) {
        int4 o4 = op[p];
        float4 w4 = wp[p];
        unsigned int u0 = *(const unsigned int*)(vbase + (size_t)(unsigned)(o4.x + laneByte));
        unsigned int u1 = *(const unsigned int*)(vbase + (size_t)(unsigned)(o4.y + laneByte));
        unsigned int u2 = *(const unsigned int*)(vbase + (size_t)(unsigned)(o4.z + laneByte));
        unsigned int u3 = *(const unsigned int*)(vbase + (size_t)(unsigned)(o4.w + laneByte));
        acc0 += w4.x * u2f_lo(u0); acc1 += w4.x * u2f_hi(u0);
        acc0 += w4.y * u2f_lo(u1); acc1 += w4.y * u2f_hi(u1);
        acc0 += w4.z * u2f_lo(u2); acc1 += w4.z * u2f_hi(u2);
        acc0 += w4.w * u2f_lo(u3); acc1 += w4.w * u2f_hi(u3);
    }
    unsigned int packed = (unsigned int)f2bf(acc0) | ((unsigned int)f2bf(acc1) << 16);
    *(unsigned int*)(ob + (size_t)(q0 + ql) * 256 + h * 32 + c2 * 2) = packed;
}

// ---------------------------------------------------------------------------
extern "C" void kernel_launch(void* const* d_in, const int* in_sizes, int n_in,
                              void* d_out, int out_size, void* d_ws, size_t ws_size,
                              hipStream_t stream)
{
    const float* src    = (const float*)d_in[0];
    const float* pos    = (const float*)d_in[1];
    const float* vr     = (const float*)d_in[4];
    const float* W_samp = (const float*)d_in[5];
    const float* b_samp = (const float*)d_in[6];
    const float* W_tsamp= (const float*)d_in[7];
    const float* b_tsamp= (const float*)d_in[8];
    const float* W_attn = (const float*)d_in[9];
    const float* b_attn = (const float*)d_in[10];
    const float* W_val  = (const float*)d_in[11];
    const float* b_val  = (const float*)d_in[12];
    const float* W_out  = (const float*)d_in[13];
    const float* b_out  = (const float*)d_in[14];
    const float* W_ff1  = (const float*)d_in[15];
    const float* b_ff1  = (const float*)d_in[16];
    const float* W_ff2  = (const float*)d_in[17];
    const float* b_ff2  = (const float*)d_in[18];
    const float* n1g    = (const float*)d_in[19];
    const float* n1b    = (const float*)d_in[20];
    const float* n2g    = (const float*)d_in[21];
    const float* n2b    = (const float*)d_in[22];

    // ---- workspace layout (f32 units) ----
    float* ws = (float*)d_ws;
    ushort* qout  = (ushort*)ws;                         // LQ*1344 bf16
    float* valueR = ws + (size_t)LQ * 672;               // region: LQ*256 f32
    ushort* valb  = (ushort*)valueR;                     // LQ*256 bf16
    ushort* srcb  = (ushort*)(valueR + (size_t)LQ * 256);// LQ*256 bf16
    ushort* qb    = srcb + (size_t)LQ * 256;             // LQ*256 bf16
    ushort* obuf  = qb + (size_t)LQ * 256;               // LQ*256 bf16
    float* ffB    = (float*)(obuf + (size_t)LQ * 256);   // LQ*256 f32 (spacer)
    ushort* Wq    = (ushort*)(ffB + (size_t)LQ * 256);   // 1344*256 bf16
    ushort* Wv    = Wq + 1344 * 256;
    ushort* Wo    = Wv + 256 * 256;
    ushort* Wf1   = Wo + 256 * 256;
    ushort* Wf2   = Wf1 + 1024 * 256;
    float* bq     = (float*)(Wf2 + 1024 * 256);          // 1344 f32
    // region reuse after deform:
    float* xF     = (float*)qout;                        // LQ*256 f32 (qout dead)
    ushort* xB16  = (ushort*)((float*)qout + (size_t)LQ * 256); // LQ*256 bf16
    ushort* hB16  = (ushort*)valueR;                     // LQ*1024 bf16 spans valueR..qb

    // ---- input conversions (2 launches) ----
    cvt_src_q<<<(LQ * 64 + 255) / 256, 256, 0, stream>>>(src, pos, srcb, qb, LQ * 64);
    CvtArgs ca;
    ca.s[0] = W_samp;  ca.d[0] = Wq;             ca.n[0] = 256 * 256;  ca.isbf[0] = 1;
    ca.s[1] = W_tsamp; ca.d[1] = Wq + 256 * 256; ca.n[1] = 640 * 256;  ca.isbf[1] = 1;
    ca.s[2] = W_attn;  ca.d[2] = Wq + 896 * 256; ca.n[2] = 448 * 256;  ca.isbf[2] = 1;
    ca.s[3] = W_val;   ca.d[3] = Wv;             ca.n[3] = 256 * 256;  ca.isbf[3] = 1;
    ca.s[4] = W_out;   ca.d[4] = Wo;             ca.n[4] = 256 * 256;  ca.isbf[4] = 1;
    ca.s[5] = W_ff1;   ca.d[5] = Wf1;            ca.n[5] = 1024 * 256; ca.isbf[5] = 1;
    ca.s[6] = W_ff2;   ca.d[6] = Wf2;            ca.n[6] = 256 * 1024; ca.isbf[6] = 1;
    ca.s[7] = b_samp;  ca.d[7] = bq;             ca.n[7] = 256;        ca.isbf[7] = 0;
    ca.s[8] = b_tsamp; ca.d[8] = bq + 256;       ca.n[8] = 640;        ca.isbf[8] = 0;
    ca.s[9] = b_attn;  ca.d[9] = bq + 896;       ca.n[9] = 448;        ca.isbf[9] = 0;
    ca.s[10] = b_attn; ca.d[10] = bq + 896;      ca.n[10] = 0;         ca.isbf[10] = 0;
    cvt_multi<<<dim3(1024, 11), 256, 0, stream>>>(ca);

    const int GM = (LQ + 127) / 128;   // 192

    // fused: value-proj + q-proj (bf16 out)
    gemm_valq<<<dim3(25, GM), 256, 0, stream>>>(srcb, qb, Wv, Wq, b_val, bq, valb, qout);

    // deformable attention (bf16 out), 2 queries per block
    deform_kernel<<<LQ / 2, 256, 0, stream>>>(valb, qout, vr, obuf);

    // out-proj + residual + LN1 fused (writes xF f32 + xB16 bf16)
    gemm_ln<1><<<GM, 256, 0, stream>>>(obuf, Wo, b_out, src, n1g, n1b, xF, xB16, LQ, 256);

    // FFN: ff1 (relu, bf16 out) ; ff2 + residual + LN2 fused -> d_out
    gemm_mfma<1, 0, 1><<<dim3(16, GM), 256, 0, stream>>>(xB16, Wf1, b_ff1, nullptr, hB16, LQ, 1024, 256);
    gemm_ln<0><<<GM, 256, 0, stream>>>(hB16, Wf2, b_ff2, xF, n2g, n2b, (float*)d_out, nullptr, LQ, 1024);
}

// Round 8
// 458.254 us; speedup vs baseline: 7.7496x; 1.0112x over previous
//
#include <hip/hip_runtime.h>
#include <hip/hip_bf16.h>
#include <math.h>

#define LQ 24480

typedef short bf16x8 __attribute__((ext_vector_type(8)));   // 8 bf16 = 16B
typedef float f32x4 __attribute__((ext_vector_type(4)));
typedef float f32x4v __attribute__((ext_vector_type(4)));

static __device__ __forceinline__ float bf2f(ushort u) {
    union { unsigned int i; float f; } v; v.i = ((unsigned int)u) << 16; return v.f;
}
static __device__ __forceinline__ ushort f2bf(float f) {
    __hip_bfloat16 h = __float2bfloat16(f);
    return *reinterpret_cast<ushort*>(&h);
}
static __device__ __forceinline__ float u2f_lo(unsigned int u) {
    union { unsigned int i; float f; } v; v.i = u << 16; return v.f;
}
static __device__ __forceinline__ float u2f_hi(unsigned int u) {
    union { unsigned int i; float f; } v; v.i = u & 0xffff0000u; return v.f;
}

// ---------------------------------------------------------------------------
// Fat-tile GEMM body: block 128x128, 4 waves in 2x2, wave tile 64x64
// (4x4 fragments, 16 MFMA per K=32 step vs 8 operand loads -> 2:1 ratio).
// ---------------------------------------------------------------------------
template <int RELU, int WF32, int WBF16>
static __device__ __forceinline__ void gemm_body128(
    const ushort* __restrict__ A, const ushort* __restrict__ W,
    const float* __restrict__ bias,
    float* __restrict__ Cf, ushort* __restrict__ Cb,
    int M, int N, int K, int bm, int bn, int wave, int lane)
{
    const int wm = wave >> 1, wn = wave & 1;
    const int r = lane & 15, kblk = lane >> 4;

    f32x4 acc[4][4] = {};

    const ushort* ap[4];
    const ushort* bp[4];
#pragma unroll
    for (int i = 0; i < 4; ++i) {
        int rr = min(bm + wm * 64 + i * 16 + r, M - 1);
        ap[i] = A + (size_t)rr * K + kblk * 8;
    }
#pragma unroll
    for (int j = 0; j < 4; ++j) {
        int cc = min(bn + wn * 64 + j * 16 + r, N - 1);
        bp[j] = W + (size_t)cc * K + kblk * 8;
    }

#pragma unroll 2
    for (int k = 0; k < K; k += 32) {
        bf16x8 a[4], b[4];
#pragma unroll
        for (int i = 0; i < 4; ++i) a[i] = *(const bf16x8*)(ap[i] + k);
#pragma unroll
        for (int j = 0; j < 4; ++j) b[j] = *(const bf16x8*)(bp[j] + k);
#pragma unroll
        for (int i = 0; i < 4; ++i)
#pragma unroll
            for (int j = 0; j < 4; ++j)
                acc[i][j] = __builtin_amdgcn_mfma_f32_16x16x32_bf16(a[i], b[j], acc[i][j], 0, 0, 0);
    }

    const int orow = kblk * 4;
#pragma unroll
    for (int j = 0; j < 4; ++j) {
        int cc = bn + wn * 64 + j * 16 + r;
        if (cc < N) {
            float bv = bias[cc];
#pragma unroll
            for (int i = 0; i < 4; ++i)
#pragma unroll
                for (int t = 0; t < 4; ++t) {
                    int rr = bm + wm * 64 + i * 16 + orow + t;
                    if (rr < M) {
                        float v = acc[i][j][t] + bv;
                        if (RELU) v = fmaxf(v, 0.f);
                        if (WF32) Cf[(size_t)rr * N + cc] = v;
                        if (WBF16) Cb[(size_t)rr * N + cc] = f2bf(v);
                    }
                }
        }
    }
}

// Fused value-proj (2 col-blocks -> valb) + q-proj (11 col-blocks -> qout).
__global__ __launch_bounds__(256) void gemm_valq(
    const ushort* __restrict__ srcb, const ushort* __restrict__ qb,
    const ushort* __restrict__ Wv, const ushort* __restrict__ Wq,
    const float* __restrict__ b_val, const float* __restrict__ bq,
    ushort* __restrict__ valb, ushort* __restrict__ qout)
{
    const int bx = blockIdx.x;   // 0..12
    if (bx < 2) {
        gemm_body128<0, 0, 1>(srcb, Wv, b_val, nullptr, valb, LQ, 256, 256,
                              blockIdx.y * 128, bx * 128,
                              threadIdx.x >> 6, threadIdx.x & 63);
    } else {
        gemm_body128<0, 0, 1>(qb, Wq, bq, nullptr, qout, LQ, 1344, 256,
                              blockIdx.y * 128, (bx - 2) * 128,
                              threadIdx.x >> 6, threadIdx.x & 63);
    }
}

// ff1: relu, bf16 out
__global__ __launch_bounds__(256) void gemm_ff1(
    const ushort* __restrict__ A, const ushort* __restrict__ W,
    const float* __restrict__ bias, ushort* __restrict__ Cb)
{
    gemm_body128<1, 0, 1>(A, W, bias, nullptr, Cb, LQ, 1024, 256,
                          blockIdx.y * 128, blockIdx.x * 128,
                          threadIdx.x >> 6, threadIdx.x & 63);
}

// ---------------------------------------------------------------------------
// Fused GEMM (N=256) + residual + LayerNorm.
// ---------------------------------------------------------------------------
template <int WBF16>
__global__ __launch_bounds__(256) void gemm_ln(
    const ushort* __restrict__ A, const ushort* __restrict__ W,
    const float* __restrict__ bias, const float* __restrict__ res,
    const float* __restrict__ g, const float* __restrict__ be,
    float* __restrict__ outF, ushort* __restrict__ outB,
    int M, int K)
{
    const int wave = threadIdx.x >> 6;
    const int lane = threadIdx.x & 63;
    const int r = lane & 15;
    const int kblk = lane >> 4;
    const int bm = blockIdx.x * 128;

    f32x4 acc[2][16] = {};

    int row0 = bm + wave * 32 + r;
    int row1 = row0 + 16;
    row0 = min(row0, M - 1);
    row1 = min(row1, M - 1);
    const ushort* ap0 = A + (size_t)row0 * K + kblk * 8;
    const ushort* ap1 = A + (size_t)row1 * K + kblk * 8;
    const ushort* bp  = W + (size_t)r * K + kblk * 8;
    const size_t nK = (size_t)16 * K;

#pragma unroll 2
    for (int k = 0; k < K; k += 32) {
        bf16x8 a0 = *(const bf16x8*)(ap0 + k);
        bf16x8 a1 = *(const bf16x8*)(ap1 + k);
#pragma unroll
        for (int ni = 0; ni < 16; ++ni) {
            bf16x8 b = *(const bf16x8*)(bp + (size_t)ni * nK + k);
            acc[0][ni] = __builtin_amdgcn_mfma_f32_16x16x32_bf16(a0, b, acc[0][ni], 0, 0, 0);
            acc[1][ni] = __builtin_amdgcn_mfma_f32_16x16x32_bf16(a1, b, acc[1][ni], 0, 0, 0);
        }
    }

    const int orow = kblk * 4;
    const int ocol = r;

    float bv[16];
#pragma unroll
    for (int ni = 0; ni < 16; ++ni) bv[ni] = bias[ni * 16 + ocol];

    float mean_[2][4], rstd_[2][4];
#pragma unroll
    for (int mi = 0; mi < 2; ++mi)
#pragma unroll
        for (int j = 0; j < 4; ++j) {
            int rr = bm + wave * 32 + mi * 16 + orow + j;
            int rl = min(rr, M - 1);
            const float* rp = res + (size_t)rl * 256 + ocol;
            float s = 0.f, s2 = 0.f;
#pragma unroll
            for (int ni = 0; ni < 16; ++ni) {
                float v = acc[mi][ni][j] + bv[ni] + rp[ni * 16];
                acc[mi][ni][j] = v;
                s += v; s2 += v * v;
            }
#pragma unroll
            for (int off = 8; off; off >>= 1) {
                s  += __shfl_xor(s,  off, 16);
                s2 += __shfl_xor(s2, off, 16);
            }
            float mu = s * (1.f / 256.f);
            float var = s2 * (1.f / 256.f) - mu * mu;
            mean_[mi][j] = mu;
            rstd_[mi][j] = rsqrtf(var + 1e-5f);
        }

    float gv[16], bev[16];
#pragma unroll
    for (int ni = 0; ni < 16; ++ni) {
        gv[ni] = g[ni * 16 + ocol];
        bev[ni] = be[ni * 16 + ocol];
    }

#pragma unroll
    for (int mi = 0; mi < 2; ++mi)
#pragma unroll
        for (int j = 0; j < 4; ++j) {
            int rr = bm + wave * 32 + mi * 16 + orow + j;
            if (rr < M) {
#pragma unroll
                for (int ni = 0; ni < 16; ++ni) {
                    float o = (acc[mi][ni][j] - mean_[mi][j]) * rstd_[mi][j] * gv[ni] + bev[ni];
                    outF[(size_t)rr * 256 + ni * 16 + ocol] = o;
                    if (WBF16) outB[(size_t)rr * 256 + ni * 16 + ocol] = f2bf(o);
                }
            }
        }
}

// ---------------------------------------------------------------------------
// src/q -> bf16 (vectorized), q = src + pos
// ---------------------------------------------------------------------------
__global__ __launch_bounds__(256) void cvt_src_q(
    const float* __restrict__ src, const float* __restrict__ pos,
    ushort* __restrict__ srcb, ushort* __restrict__ qb, int n4)
{
    int i = blockIdx.x * 256 + threadIdx.x;
    if (i >= n4) return;
    f32x4v s = *(const f32x4v*)(src + (size_t)i * 4);
    f32x4v p = *(const f32x4v*)(pos + (size_t)i * 4);
    ushort us[4], uq[4];
#pragma unroll
    for (int j = 0; j < 4; ++j) { us[j] = f2bf(s[j]); uq[j] = f2bf(s[j] + p[j]); }
    *(ulong1*)(srcb + (size_t)i * 4) = *(ulong1*)us;
    *(ulong1*)(qb   + (size_t)i * 4) = *(ulong1*)uq;
}

// weight conversions + bias concat in ONE launch: seg = blockIdx.y
struct CvtArgs { const float* s[11]; void* d[11]; int n[11]; int isbf[11]; };
__global__ __launch_bounds__(256) void cvt_multi(CvtArgs a)
{
    int seg = blockIdx.y;
    int i = blockIdx.x * 256 + threadIdx.x;
    if (i >= a.n[seg]) return;
    float v = a.s[seg][i];
    if (a.isbf[seg]) ((ushort*)a.d[seg])[i] = f2bf(v);
    else             ((float*)a.d[seg])[i]  = v;
}

// ---------------------------------------------------------------------------
// Deformable attention, phase-split, 2 queries/block, 2 channels/thread.
// aw is staged in wts_s[..].x (phase-0 write / phase-1 same-index read)
// to cut LDS from 32.3 KB to 28.7 KB (5 blocks/CU).
// ---------------------------------------------------------------------------
__global__ __launch_bounds__(256) void deform_kernel(
    const ushort* __restrict__ valb,   // [LQ,256] bf16
    const ushort* __restrict__ qout,   // [LQ,1344] bf16: samp|tsamp|logits
    const float* __restrict__ vr,      // [4,2]
    ushort* __restrict__ ob)           // [LQ,256] bf16
{
    const int q0 = blockIdx.x * 2;
    const int tid = threadIdx.x;

    __shared__ int4   offs_s[2][448];
    __shared__ float4 wts_s[2][448];

    const int lsiA[4] = {0, 18432, 23040, 24192};

    // ---- phase 0: softmax -> wts_s[..].x ----
    {
        int grp = tid >> 4;
        int ql = grp >> 3, h = grp & 7;
        int ln = tid & 15;
        const ushort* lg = qout + (size_t)(q0 + ql) * 1344 + 896 + h * 56;
        float l0 = bf2f(lg[ln]);
        float l1 = bf2f(lg[16 + ln]);
        float l2 = bf2f(lg[32 + ln]);
        float l3 = (ln < 8) ? bf2f(lg[48 + ln]) : -1e30f;
        float m = fmaxf(fmaxf(l0, l1), fmaxf(l2, l3));
#pragma unroll
        for (int off = 8; off; off >>= 1) m = fmaxf(m, __shfl_xor(m, off, 16));
        float e0 = expf(l0 - m), e1 = expf(l1 - m), e2 = expf(l2 - m);
        float e3 = (ln < 8) ? expf(l3 - m) : 0.f;
        float s = e0 + e1 + e2 + e3;
#pragma unroll
        for (int off = 8; off; off >>= 1) s += __shfl_xor(s, off, 16);
        float inv = 1.f / s;
        wts_s[ql][h * 56 + ln].x      = e0 * inv;
        wts_s[ql][h * 56 + 16 + ln].x = e1 * inv;
        wts_s[ql][h * 56 + 32 + ln].x = e2 * inv;
        if (ln < 8) wts_s[ql][h * 56 + 48 + ln].x = e3 * inv;
    }

    // ---- hoisted per-query geometry (q0, q0+1 share the level) ----
    int lqv = (q0 >= 24192) ? 3 : (q0 >= 23040) ? 2 : (q0 >= 18432) ? 1 : 0;
    int Wqv = 64 >> lqv, Hqv = 48 >> lqv;
    int slq = lsiA[lqv];
    float vrxq = vr[2 * lqv], vryq = vr[2 * lqv + 1];
    float rxb0, ryb0, rxb1, ryb1; int tq0, tq1;
    {
        int qi = q0 - slq;
        int iy = qi >> (6 - lqv);
        int jx = qi & (Wqv - 1);
        tq0 = iy / Hqv;
        rxb0 = ((float)jx + 0.5f) / (vrxq * (float)Wqv);
        ryb0 = ((float)iy + 0.5f) / (vryq * (float)(Hqv * 6));
        qi += 1;
        iy = qi >> (6 - lqv);
        jx = qi & (Wqv - 1);
        tq1 = iy / Hqv;
        rxb1 = ((float)jx + 0.5f) / (vrxq * (float)Wqv);
        ryb1 = ((float)iy + 0.5f) / (vryq * (float)(Hqv * 6));
    }
    __syncthreads();

    // ---- phase 1: coords for 2x448 items ----
    for (int it = tid; it < 896; it += 256) {
        int ql = (it >= 448) ? 1 : 0;
        int item = it - ql * 448;
        float rx_base = ql ? rxb1 : rxb0;
        float ry_base = ql ? ryb1 : ryb0;
        int tq = ql ? tq1 : tq0;

        int h = item / 56;
        int p = item - h * 56;
        int l = p / 14;
        int pp = p - l * 14;

        int Wl = 64 >> l;
        int Hl = 48 >> l;
        int Htl = Hl * 6;
        float vrx = vr[2 * l], vry = vr[2 * l + 1];

        float aw = wts_s[ql][item].x;

        const ushort* qrow = qout + (size_t)(q0 + ql) * 1344;
        float ox, oy, ty;
        if (pp < 4) {
            ox = bf2f(qrow[h * 32 + l * 8 + pp * 2]);
            oy = bf2f(qrow[h * 32 + l * 8 + pp * 2 + 1]);
            ty = 0.f;
        } else {
            int pq = pp - 4;
            int tw = pq >> 1, nt = pq & 1;
            int tt = (tw < tq) ? tw : tw + 1;
            ty = (float)(tt - tq) * vry * (float)Hl;
            ox = bf2f(qrow[256 + h * 80 + l * 20 + tw * 4 + nt * 2]);
            oy = bf2f(qrow[256 + h * 80 + l * 20 + tw * 4 + nt * 2 + 1]);
        }
        float x = rx_base * vrx * (float)Wl - 0.5f + ox;
        float y = ry_base * vry * (float)Htl - 0.5f + ty + oy;
        float x0f = floorf(x), y0f = floorf(y);
        int x0 = (int)x0f, y0 = (int)y0f;
        float fx = x - x0f, fy = y - y0f;

        int xi0 = min(max(x0, 0), Wl - 1);
        int xi1 = min(max(x0 + 1, 0), Wl - 1);
        int yi0 = min(max(y0, 0), Htl - 1);
        int yi1 = min(max(y0 + 1, 0), Htl - 1);
        float mx0 = (x0 >= 0 && x0 < Wl) ? 1.f : 0.f;
        float mx1 = (x0 >= -1 && x0 + 1 < Wl) ? 1.f : 0.f;
        float my0 = (y0 >= 0 && y0 < Htl) ? 1.f : 0.f;
        float my1 = (y0 >= -1 && y0 + 1 < Htl) ? 1.f : 0.f;

        float gx0 = (1.f - fx) * mx0;
        float gx1 = fx * mx1;
        float gy0 = (1.f - fy) * my0 * aw;
        float gy1 = fy * my1 * aw;

        int sl = lsiA[l];
        // BYTE offsets into valb (row = 256 bf16 = 512 B)
        int rb0 = (sl + yi0 * Wl) * 512;
        int rb1 = (sl + yi1 * Wl) * 512;
        offs_s[ql][item] = make_int4(rb0 + xi0 * 512, rb0 + xi1 * 512,
                                     rb1 + xi0 * 512, rb1 + xi1 * 512);
        wts_s[ql][item] = make_float4(gy0 * gx0, gy0 * gx1, gy1 * gx0, gy1 * gx1);
    }
    __syncthreads();

    // ---- phase 2: gather 2 channels per thread (SADDR 32-bit voffsets) ----
    const int ql = tid >> 7;
    const int h = (tid >> 4) & 7;
    const int c2 = tid & 15;
    const unsigned laneByte = (unsigned)(h * 64 + c2 * 4);
    const char* vbase = (const char*)valb;
    const int4* op = offs_s[ql] + h * 56;
    const float4* wp = wts_s[ql] + h * 56;
    float acc0 = 0.f, acc1 = 0.f;
#pragma unroll 8
    for (int p = 0; p < 56; ++p) {
        int4 o4 = op[p];
        float4 w4 = wp[p];
        unsigned int u0 = *(const unsigned int*)(vbase + (size_t)(unsigned)(o4.x + laneByte));
        unsigned int u1 = *(const unsigned int*)(vbase + (size_t)(unsigned)(o4.y + laneByte));
        unsigned int u2 = *(const unsigned int*)(vbase + (size_t)(unsigned)(o4.z + laneByte));
        unsigned int u3 = *(const unsigned int*)(vbase + (size_t)(unsigned)(o4.w + laneByte));
        acc0 += w4.x * u2f_lo(u0); acc1 += w4.x * u2f_hi(u0);
        acc0 += w4.y * u2f_lo(u1); acc1 += w4.y * u2f_hi(u1);
        acc0 += w4.z * u2f_lo(u2); acc1 += w4.z * u2f_hi(u2);
        acc0 += w4.w * u2f_lo(u3); acc1 += w4.w * u2f_hi(u3);
    }
    unsigned int packed = (unsigned int)f2bf(acc0) | ((unsigned int)f2bf(acc1) << 16);
    *(unsigned int*)(ob + (size_t)(q0 + ql) * 256 + h * 32 + c2 * 2) = packed;
}

// ---------------------------------------------------------------------------
extern "C" void kernel_launch(void* const* d_in, const int* in_sizes, int n_in,
                              void* d_out, int out_size, void* d_ws, size_t ws_size,
                              hipStream_t stream)
{
    const float* src    = (const float*)d_in[0];
    const float* pos    = (const float*)d_in[1];
    const float* vr     = (const float*)d_in[4];
    const float* W_samp = (const float*)d_in[5];
    const float* b_samp = (const float*)d_in[6];
    const float* W_tsamp= (const float*)d_in[7];
    const float* b_tsamp= (const float*)d_in[8];
    const float* W_attn = (const float*)d_in[9];
    const float* b_attn = (const float*)d_in[10];
    const float* W_val  = (const float*)d_in[11];
    const float* b_val  = (const float*)d_in[12];
    const float* W_out  = (const float*)d_in[13];
    const float* b_out  = (const float*)d_in[14];
    const float* W_ff1  = (const float*)d_in[15];
    const float* b_ff1  = (const float*)d_in[16];
    const float* W_ff2  = (const float*)d_in[17];
    const float* b_ff2  = (const float*)d_in[18];
    const float* n1g    = (const float*)d_in[19];
    const float* n1b    = (const float*)d_in[20];
    const float* n2g    = (const float*)d_in[21];
    const float* n2b    = (const float*)d_in[22];

    // ---- workspace layout (f32 units) ----
    float* ws = (float*)d_ws;
    ushort* qout  = (ushort*)ws;                         // LQ*1344 bf16
    float* valueR = ws + (size_t)LQ * 672;               // region: LQ*256 f32
    ushort* valb  = (ushort*)valueR;                     // LQ*256 bf16
    ushort* srcb  = (ushort*)(valueR + (size_t)LQ * 256);// LQ*256 bf16
    ushort* qb    = srcb + (size_t)LQ * 256;             // LQ*256 bf16
    ushort* obuf  = qb + (size_t)LQ * 256;               // LQ*256 bf16
    float* ffB    = (float*)(obuf + (size_t)LQ * 256);   // LQ*256 f32 (spacer)
    ushort* Wq    = (ushort*)(ffB + (size_t)LQ * 256);   // 1344*256 bf16
    ushort* Wv    = Wq + 1344 * 256;
    ushort* Wo    = Wv + 256 * 256;
    ushort* Wf1   = Wo + 256 * 256;
    ushort* Wf2   = Wf1 + 1024 * 256;
    float* bq     = (float*)(Wf2 + 1024 * 256);          // 1344 f32
    // region reuse after deform:
    float* xF     = (float*)qout;                        // LQ*256 f32 (qout dead)
    ushort* xB16  = (ushort*)((float*)qout + (size_t)LQ * 256); // LQ*256 bf16
    ushort* hB16  = (ushort*)valueR;                     // LQ*1024 bf16 spans valueR..qb

    // ---- input conversions (2 launches) ----
    cvt_src_q<<<(LQ * 64 + 255) / 256, 256, 0, stream>>>(src, pos, srcb, qb, LQ * 64);
    CvtArgs ca;
    ca.s[0] = W_samp;  ca.d[0] = Wq;             ca.n[0] = 256 * 256;  ca.isbf[0] = 1;
    ca.s[1] = W_tsamp; ca.d[1] = Wq + 256 * 256; ca.n[1] = 640 * 256;  ca.isbf[1] = 1;
    ca.s[2] = W_attn;  ca.d[2] = Wq + 896 * 256; ca.n[2] = 448 * 256;  ca.isbf[2] = 1;
    ca.s[3] = W_val;   ca.d[3] = Wv;             ca.n[3] = 256 * 256;  ca.isbf[3] = 1;
    ca.s[4] = W_out;   ca.d[4] = Wo;             ca.n[4] = 256 * 256;  ca.isbf[4] = 1;
    ca.s[5] = W_ff1;   ca.d[5] = Wf1;            ca.n[5] = 1024 * 256; ca.isbf[5] = 1;
    ca.s[6] = W_ff2;   ca.d[6] = Wf2;            ca.n[6] = 256 * 1024; ca.isbf[6] = 1;
    ca.s[7] = b_samp;  ca.d[7] = bq;             ca.n[7] = 256;        ca.isbf[7] = 0;
    ca.s[8] = b_tsamp; ca.d[8] = bq + 256;       ca.n[8] = 640;        ca.isbf[8] = 0;
    ca.s[9] = b_attn;  ca.d[9] = bq + 896;       ca.n[9] = 448;        ca.isbf[9] = 0;
    ca.s[10] = b_attn; ca.d[10] = bq + 896;      ca.n[10] = 0;         ca.isbf[10] = 0;
    cvt_multi<<<dim3(1024, 11), 256, 0, stream>>>(ca);

    const int GM = (LQ + 127) / 128;   // 192

    // fused: value-proj + q-proj (bf16 out), 128x128 tiles
    gemm_valq<<<dim3(13, GM), 256, 0, stream>>>(srcb, qb, Wv, Wq, b_val, bq, valb, qout);

    // deformable attention (bf16 out), 2 queries per block
    deform_kernel<<<LQ / 2, 256, 0, stream>>>(valb, qout, vr, obuf);

    // out-proj + residual + LN1 fused (writes xF f32 + xB16 bf16)
    gemm_ln<1><<<GM, 256, 0, stream>>>(obuf, Wo, b_out, src, n1g, n1b, xF, xB16, LQ, 256);

    // FFN: ff1 (relu, bf16 out, 128x128 tiles) ; ff2 + residual + LN2 -> d_out
    gemm_ff1<<<dim3(8, GM), 256, 0, stream>>>(xB16, Wf1, b_ff1, hB16);
    gemm_ln<0><<<GM, 256, 0, stream>>>(hB16, Wf2, b_ff2, xF, n2g, n2b, (float*)d_out, nullptr, LQ, 1024);
}

// Round 9
// 425.449 us; speedup vs baseline: 8.3471x; 1.0771x over previous
//
#include <hip/hip_runtime.h>
#include <hip/hip_bf16.h>
#include <math.h>

#define LQ 24480

typedef short bf16x8 __attribute__((ext_vector_type(8)));   // 8 bf16 = 16B
typedef float f32x4 __attribute__((ext_vector_type(4)));
typedef float f32x4v __attribute__((ext_vector_type(4)));

static __device__ __forceinline__ float bf2f(ushort u) {
    union { unsigned int i; float f; } v; v.i = ((unsigned int)u) << 16; return v.f;
}
static __device__ __forceinline__ ushort f2bf(float f) {
    __hip_bfloat16 h = __float2bfloat16(f);
    return *reinterpret_cast<ushort*>(&h);
}
static __device__ __forceinline__ float u2f_lo(unsigned int u) {
    union { unsigned int i; float f; } v; v.i = u << 16; return v.f;
}
static __device__ __forceinline__ float u2f_hi(unsigned int u) {
    union { unsigned int i; float f; } v; v.i = u & 0xffff0000u; return v.f;
}

// ---------------------------------------------------------------------------
// Fat-tile GEMM body: block 128x128, 4 waves in 2x2, wave tile 64x64.
// B-fragment permutation: fragment j loads W row (bn + wn*64 + r*4 + j), so
// each thread's 4 j-values are 4 CONSECUTIVE output columns -> packed 8B
// bf16x4 stores (4x fewer, coalesced) instead of scalar 2B stores.
// ---------------------------------------------------------------------------
template <int RELU>
static __device__ __forceinline__ void gemm_body128(
    const ushort* __restrict__ A, const ushort* __restrict__ W,
    const float* __restrict__ bias,
    ushort* __restrict__ Cb,
    int M, int N, int K, int bm, int bn, int wave, int lane)
{
    const int wm = wave >> 1, wn = wave & 1;
    const int r = lane & 15, kblk = lane >> 4;

    f32x4 acc[4][4] = {};

    const ushort* ap[4];
    const ushort* bp[4];
#pragma unroll
    for (int i = 0; i < 4; ++i) {
        int rr = min(bm + wm * 64 + i * 16 + r, M - 1);
        ap[i] = A + (size_t)rr * K + kblk * 8;
    }
    const int c0 = bn + wn * 64 + r * 4;     // first of this thread's 4 cols
#pragma unroll
    for (int j = 0; j < 4; ++j) {
        int cc = min(c0 + j, N - 1);
        bp[j] = W + (size_t)cc * K + kblk * 8;
    }

#pragma unroll 2
    for (int k = 0; k < K; k += 32) {
        bf16x8 a[4], b[4];
#pragma unroll
        for (int i = 0; i < 4; ++i) a[i] = *(const bf16x8*)(ap[i] + k);
#pragma unroll
        for (int j = 0; j < 4; ++j) b[j] = *(const bf16x8*)(bp[j] + k);
#pragma unroll
        for (int i = 0; i < 4; ++i)
#pragma unroll
            for (int j = 0; j < 4; ++j)
                acc[i][j] = __builtin_amdgcn_mfma_f32_16x16x32_bf16(a[i], b[j], acc[i][j], 0, 0, 0);
    }

    if (c0 >= N) return;                     // partial last col-block (N=1344)
    const float4 bv = *(const float4*)(bias + c0);
    const int orow = kblk * 4;
#pragma unroll
    for (int i = 0; i < 4; ++i)
#pragma unroll
        for (int t = 0; t < 4; ++t) {
            int rr = bm + wm * 64 + i * 16 + orow + t;
            if (rr < M) {
                float v0 = acc[i][0][t] + bv.x;
                float v1 = acc[i][1][t] + bv.y;
                float v2 = acc[i][2][t] + bv.z;
                float v3 = acc[i][3][t] + bv.w;
                if (RELU) {
                    v0 = fmaxf(v0, 0.f); v1 = fmaxf(v1, 0.f);
                    v2 = fmaxf(v2, 0.f); v3 = fmaxf(v3, 0.f);
                }
                uint2 pk;
                pk.x = (unsigned)f2bf(v0) | ((unsigned)f2bf(v1) << 16);
                pk.y = (unsigned)f2bf(v2) | ((unsigned)f2bf(v3) << 16);
                *(uint2*)(Cb + (size_t)rr * N + c0) = pk;
            }
        }
}

// Fused value-proj (2 col-blocks -> valb) + q-proj (11 col-blocks -> qout).
__global__ __launch_bounds__(256) void gemm_valq(
    const ushort* __restrict__ srcb, const ushort* __restrict__ qb,
    const ushort* __restrict__ Wv, const ushort* __restrict__ Wq,
    const float* __restrict__ b_val, const float* __restrict__ bq,
    ushort* __restrict__ valb, ushort* __restrict__ qout)
{
    const int bx = blockIdx.x;   // 0..12
    if (bx < 2) {
        gemm_body128<0>(srcb, Wv, b_val, valb, LQ, 256, 256,
                        blockIdx.y * 128, bx * 128,
                        threadIdx.x >> 6, threadIdx.x & 63);
    } else {
        gemm_body128<0>(qb, Wq, bq, qout, LQ, 1344, 256,
                        blockIdx.y * 128, (bx - 2) * 128,
                        threadIdx.x >> 6, threadIdx.x & 63);
    }
}

// ff1: relu, bf16 out
__global__ __launch_bounds__(256) void gemm_ff1(
    const ushort* __restrict__ A, const ushort* __restrict__ W,
    const float* __restrict__ bias, ushort* __restrict__ Cb)
{
    gemm_body128<1>(A, W, bias, Cb, LQ, 1024, 256,
                    blockIdx.y * 128, blockIdx.x * 128,
                    threadIdx.x >> 6, threadIdx.x & 63);
}

// ---------------------------------------------------------------------------
// Fused GEMM (N=256) + residual + LayerNorm, column-permuted epilogue:
// fragment ni loads W row (r*16 + ni) so each thread owns 16 CONSECUTIVE
// columns [r*16, r*16+16) -> float4 stores/loads for out/res/bias/g/be.
// ---------------------------------------------------------------------------
template <int WBF16>
__global__ __launch_bounds__(256) void gemm_ln(
    const ushort* __restrict__ A, const ushort* __restrict__ W,
    const float* __restrict__ bias, const float* __restrict__ res,
    const float* __restrict__ g, const float* __restrict__ be,
    float* __restrict__ outF, ushort* __restrict__ outB,
    int M, int K)
{
    const int wave = threadIdx.x >> 6;
    const int lane = threadIdx.x & 63;
    const int r = lane & 15;
    const int kblk = lane >> 4;
    const int bm = blockIdx.x * 128;
    const int c0 = r * 16;                   // this thread's 16 columns

    f32x4 acc[2][16] = {};

    int row0 = bm + wave * 32 + r;
    int row1 = row0 + 16;
    row0 = min(row0, M - 1);
    row1 = min(row1, M - 1);
    const ushort* ap0 = A + (size_t)row0 * K + kblk * 8;
    const ushort* ap1 = A + (size_t)row1 * K + kblk * 8;
    const ushort* wp  = W + (size_t)c0 * K + kblk * 8;

#pragma unroll 2
    for (int k = 0; k < K; k += 32) {
        bf16x8 a0 = *(const bf16x8*)(ap0 + k);
        bf16x8 a1 = *(const bf16x8*)(ap1 + k);
#pragma unroll
        for (int ni = 0; ni < 16; ++ni) {
            bf16x8 b = *(const bf16x8*)(wp + (size_t)ni * K + k);
            acc[0][ni] = __builtin_amdgcn_mfma_f32_16x16x32_bf16(a0, b, acc[0][ni], 0, 0, 0);
            acc[1][ni] = __builtin_amdgcn_mfma_f32_16x16x32_bf16(a1, b, acc[1][ni], 0, 0, 0);
        }
    }

    const int orow = kblk * 4;

    float bv[16];
#pragma unroll
    for (int q = 0; q < 4; ++q)
        *(float4*)(bv + q * 4) = *(const float4*)(bias + c0 + q * 4);

    float mean_[2][4], rstd_[2][4];
#pragma unroll
    for (int mi = 0; mi < 2; ++mi)
#pragma unroll
        for (int j = 0; j < 4; ++j) {
            int rr = bm + wave * 32 + mi * 16 + orow + j;
            int rl = min(rr, M - 1);
            float rv[16];
#pragma unroll
            for (int q = 0; q < 4; ++q)
                *(float4*)(rv + q * 4) = *(const float4*)(res + (size_t)rl * 256 + c0 + q * 4);
            float s = 0.f, s2 = 0.f;
#pragma unroll
            for (int ni = 0; ni < 16; ++ni) {
                float v = acc[mi][ni][j] + bv[ni] + rv[ni];
                acc[mi][ni][j] = v;
                s += v; s2 += v * v;
            }
#pragma unroll
            for (int off = 8; off; off >>= 1) {
                s  += __shfl_xor(s,  off, 16);
                s2 += __shfl_xor(s2, off, 16);
            }
            float mu = s * (1.f / 256.f);
            float var = s2 * (1.f / 256.f) - mu * mu;
            mean_[mi][j] = mu;
            rstd_[mi][j] = rsqrtf(var + 1e-5f);
        }

    float gv[16], bev[16];
#pragma unroll
    for (int q = 0; q < 4; ++q) {
        *(float4*)(gv + q * 4)  = *(const float4*)(g + c0 + q * 4);
        *(float4*)(bev + q * 4) = *(const float4*)(be + c0 + q * 4);
    }

#pragma unroll
    for (int mi = 0; mi < 2; ++mi)
#pragma unroll
        for (int j = 0; j < 4; ++j) {
            int rr = bm + wave * 32 + mi * 16 + orow + j;
            if (rr < M) {
                float o[16];
#pragma unroll
                for (int ni = 0; ni < 16; ++ni)
                    o[ni] = (acc[mi][ni][j] - mean_[mi][j]) * rstd_[mi][j] * gv[ni] + bev[ni];
#pragma unroll
                for (int q = 0; q < 4; ++q)
                    *(float4*)(outF + (size_t)rr * 256 + c0 + q * 4) = *(float4*)(o + q * 4);
                if (WBF16) {
                    uint pk[8];
#pragma unroll
                    for (int b = 0; b < 8; ++b)
                        pk[b] = (unsigned)f2bf(o[2 * b]) | ((unsigned)f2bf(o[2 * b + 1]) << 16);
                    *(uint4*)(outB + (size_t)rr * 256 + c0)     = *(uint4*)pk;
                    *(uint4*)(outB + (size_t)rr * 256 + c0 + 8) = *(uint4*)(pk + 4);
                }
            }
        }
}

// ---------------------------------------------------------------------------
// src/q -> bf16 (vectorized), q = src + pos
// ---------------------------------------------------------------------------
__global__ __launch_bounds__(256) void cvt_src_q(
    const float* __restrict__ src, const float* __restrict__ pos,
    ushort* __restrict__ srcb, ushort* __restrict__ qb, int n4)
{
    int i = blockIdx.x * 256 + threadIdx.x;
    if (i >= n4) return;
    f32x4v s = *(const f32x4v*)(src + (size_t)i * 4);
    f32x4v p = *(const f32x4v*)(pos + (size_t)i * 4);
    ushort us[4], uq[4];
#pragma unroll
    for (int j = 0; j < 4; ++j) { us[j] = f2bf(s[j]); uq[j] = f2bf(s[j] + p[j]); }
    *(ulong1*)(srcb + (size_t)i * 4) = *(ulong1*)us;
    *(ulong1*)(qb   + (size_t)i * 4) = *(ulong1*)uq;
}

// weight conversions + bias concat in ONE launch: seg = blockIdx.y
struct CvtArgs { const float* s[11]; void* d[11]; int n[11]; int isbf[11]; };
__global__ __launch_bounds__(256) void cvt_multi(CvtArgs a)
{
    int seg = blockIdx.y;
    int i = blockIdx.x * 256 + threadIdx.x;
    if (i >= a.n[seg]) return;
    float v = a.s[seg][i];
    if (a.isbf[seg]) ((ushort*)a.d[seg])[i] = f2bf(v);
    else             ((float*)a.d[seg])[i]  = v;
}

// ---------------------------------------------------------------------------
// Deformable attention, phase-split, 2 queries/block, 2 channels/thread.
// ---------------------------------------------------------------------------
__global__ __launch_bounds__(256) void deform_kernel(
    const ushort* __restrict__ valb,   // [LQ,256] bf16
    const ushort* __restrict__ qout,   // [LQ,1344] bf16: samp|tsamp|logits
    const float* __restrict__ vr,      // [4,2]
    ushort* __restrict__ ob)           // [LQ,256] bf16
{
    const int q0 = blockIdx.x * 2;
    const int tid = threadIdx.x;

    __shared__ int4   offs_s[2][448];
    __shared__ float4 wts_s[2][448];

    const int lsiA[4] = {0, 18432, 23040, 24192};

    // ---- phase 0: softmax -> wts_s[..].x ----
    {
        int grp = tid >> 4;
        int ql = grp >> 3, h = grp & 7;
        int ln = tid & 15;
        const ushort* lg = qout + (size_t)(q0 + ql) * 1344 + 896 + h * 56;
        float l0 = bf2f(lg[ln]);
        float l1 = bf2f(lg[16 + ln]);
        float l2 = bf2f(lg[32 + ln]);
        float l3 = (ln < 8) ? bf2f(lg[48 + ln]) : -1e30f;
        float m = fmaxf(fmaxf(l0, l1), fmaxf(l2, l3));
#pragma unroll
        for (int off = 8; off; off >>= 1) m = fmaxf(m, __shfl_xor(m, off, 16));
        float e0 = expf(l0 - m), e1 = expf(l1 - m), e2 = expf(l2 - m);
        float e3 = (ln < 8) ? expf(l3 - m) : 0.f;
        float s = e0 + e1 + e2 + e3;
#pragma unroll
        for (int off = 8; off; off >>= 1) s += __shfl_xor(s, off, 16);
        float inv = 1.f / s;
        wts_s[ql][h * 56 + ln].x      = e0 * inv;
        wts_s[ql][h * 56 + 16 + ln].x = e1 * inv;
        wts_s[ql][h * 56 + 32 + ln].x = e2 * inv;
        if (ln < 8) wts_s[ql][h * 56 + 48 + ln].x = e3 * inv;
    }

    // ---- hoisted per-query geometry (q0, q0+1 share the level) ----
    int lqv = (q0 >= 24192) ? 3 : (q0 >= 23040) ? 2 : (q0 >= 18432) ? 1 : 0;
    int Wqv = 64 >> lqv, Hqv = 48 >> lqv;
    int slq = lsiA[lqv];
    float vrxq = vr[2 * lqv], vryq = vr[2 * lqv + 1];
    float rxb0, ryb0, rxb1, ryb1; int tq0, tq1;
    {
        int qi = q0 - slq;
        int iy = qi >> (6 - lqv);
        int jx = qi & (Wqv - 1);
        tq0 = iy / Hqv;
        rxb0 = ((float)jx + 0.5f) / (vrxq * (float)Wqv);
        ryb0 = ((float)iy + 0.5f) / (vryq * (float)(Hqv * 6));
        qi += 1;
        iy = qi >> (6 - lqv);
        jx = qi & (Wqv - 1);
        tq1 = iy / Hqv;
        rxb1 = ((float)jx + 0.5f) / (vrxq * (float)Wqv);
        ryb1 = ((float)iy + 0.5f) / (vryq * (float)(Hqv * 6));
    }
    __syncthreads();

    // ---- phase 1: coords for 2x448 items ----
    for (int it = tid; it < 896; it += 256) {
        int ql = (it >= 448) ? 1 : 0;
        int item = it - ql * 448;
        float rx_base = ql ? rxb1 : rxb0;
        float ry_base = ql ? ryb1 : ryb0;
        int tq = ql ? tq1 : tq0;

        int h = item / 56;
        int p = item - h * 56;
        int l = p / 14;
        int pp = p - l * 14;

        int Wl = 64 >> l;
        int Hl = 48 >> l;
        int Htl = Hl * 6;
        float vrx = vr[2 * l], vry = vr[2 * l + 1];

        float aw = wts_s[ql][item].x;

        const ushort* qrow = qout + (size_t)(q0 + ql) * 1344;
        float ox, oy, ty;
        if (pp < 4) {
            ox = bf2f(qrow[h * 32 + l * 8 + pp * 2]);
            oy = bf2f(qrow[h * 32 + l * 8 + pp * 2 + 1]);
            ty = 0.f;
        } else {
            int pq = pp - 4;
            int tw = pq >> 1, nt = pq & 1;
            int tt = (tw < tq) ? tw : tw + 1;
            ty = (float)(tt - tq) * vry * (float)Hl;
            ox = bf2f(qrow[256 + h * 80 + l * 20 + tw * 4 + nt * 2]);
            oy = bf2f(qrow[256 + h * 80 + l * 20 + tw * 4 + nt * 2 + 1]);
        }
        float x = rx_base * vrx * (float)Wl - 0.5f + ox;
        float y = ry_base * vry * (float)Htl - 0.5f + ty + oy;
        float x0f = floorf(x), y0f = floorf(y);
        int x0 = (int)x0f, y0 = (int)y0f;
        float fx = x - x0f, fy = y - y0f;

        int xi0 = min(max(x0, 0), Wl - 1);
        int xi1 = min(max(x0 + 1, 0), Wl - 1);
        int yi0 = min(max(y0, 0), Htl - 1);
        int yi1 = min(max(y0 + 1, 0), Htl - 1);
        float mx0 = (x0 >= 0 && x0 < Wl) ? 1.f : 0.f;
        float mx1 = (x0 >= -1 && x0 + 1 < Wl) ? 1.f : 0.f;
        float my0 = (y0 >= 0 && y0 < Htl) ? 1.f : 0.f;
        float my1 = (y0 >= -1 && y0 + 1 < Htl) ? 1.f : 0.f;

        float gx0 = (1.f - fx) * mx0;
        float gx1 = fx * mx1;
        float gy0 = (1.f - fy) * my0 * aw;
        float gy1 = fy * my1 * aw;

        int sl = lsiA[l];
        // BYTE offsets into valb (row = 256 bf16 = 512 B)
        int rb0 = (sl + yi0 * Wl) * 512;
        int rb1 = (sl + yi1 * Wl) * 512;
        offs_s[ql][item] = make_int4(rb0 + xi0 * 512, rb0 + xi1 * 512,
                                     rb1 + xi0 * 512, rb1 + xi1 * 512);
        wts_s[ql][item] = make_float4(gy0 * gx0, gy0 * gx1, gy1 * gx0, gy1 * gx1);
    }
    __syncthreads();

    // ---- phase 2: gather 2 channels per thread (SADDR 32-bit voffsets) ----
    const int ql = tid >> 7;
    const int h = (tid >> 4) & 7;
    const int c2 = tid & 15;
    const unsigned laneByte = (unsigned)(h * 64 + c2 * 4);
    const char* vbase = (const char*)valb;
    const int4* op = offs_s[ql] + h * 56;
    const float4* wp = wts_s[ql] + h * 56;
    float acc0 = 0.f, acc1 = 0.f;
#pragma unroll 8
    for (int p = 0; p < 56; ++p) {
        int4 o4 = op[p];
        float4 w4 = wp[p];
        unsigned int u0 = *(const unsigned int*)(vbase + (size_t)(unsigned)(o4.x + laneByte));
        unsigned int u1 = *(const unsigned int*)(vbase + (size_t)(unsigned)(o4.y + laneByte));
        unsigned int u2 = *(const unsigned int*)(vbase + (size_t)(unsigned)(o4.z + laneByte));
        unsigned int u3 = *(const unsigned int*)(vbase + (size_t)(unsigned)(o4.w + laneByte));
        acc0 += w4.x * u2f_lo(u0); acc1 += w4.x * u2f_hi(u0);
        acc0 += w4.y * u2f_lo(u1); acc1 += w4.y * u2f_hi(u1);
        acc0 += w4.z * u2f_lo(u2); acc1 += w4.z * u2f_hi(u2);
        acc0 += w4.w * u2f_lo(u3); acc1 += w4.w * u2f_hi(u3);
    }
    unsigned int packed = (unsigned int)f2bf(acc0) | ((unsigned int)f2bf(acc1) << 16);
    *(unsigned int*)(ob + (size_t)(q0 + ql) * 256 + h * 32 + c2 * 2) = packed;
}

// ---------------------------------------------------------------------------
extern "C" void kernel_launch(void* const* d_in, const int* in_sizes, int n_in,
                              void* d_out, int out_size, void* d_ws, size_t ws_size,
                              hipStream_t stream)
{
    const float* src    = (const float*)d_in[0];
    const float* pos    = (const float*)d_in[1];
    const float* vr     = (const float*)d_in[4];
    const float* W_samp = (const float*)d_in[5];
    const float* b_samp = (const float*)d_in[6];
    const float* W_tsamp= (const float*)d_in[7];
    const float* b_tsamp= (const float*)d_in[8];
    const float* W_attn = (const float*)d_in[9];
    const float* b_attn = (const float*)d_in[10];
    const float* W_val  = (const float*)d_in[11];
    const float* b_val  = (const float*)d_in[12];
    const float* W_out  = (const float*)d_in[13];
    const float* b_out  = (const float*)d_in[14];
    const float* W_ff1  = (const float*)d_in[15];
    const float* b_ff1  = (const float*)d_in[16];
    const float* W_ff2  = (const float*)d_in[17];
    const float* b_ff2  = (const float*)d_in[18];
    const float* n1g    = (const float*)d_in[19];
    const float* n1b    = (const float*)d_in[20];
    const float* n2g    = (const float*)d_in[21];
    const float* n2b    = (const float*)d_in[22];

    // ---- workspace layout (f32 units) ----
    float* ws = (float*)d_ws;
    ushort* qout  = (ushort*)ws;                         // LQ*1344 bf16
    float* valueR = ws + (size_t)LQ * 672;               // region: LQ*256 f32
    ushort* valb  = (ushort*)valueR;                     // LQ*256 bf16
    ushort* srcb  = (ushort*)(valueR + (size_t)LQ * 256);// LQ*256 bf16
    ushort* qb    = srcb + (size_t)LQ * 256;             // LQ*256 bf16
    ushort* obuf  = qb + (size_t)LQ * 256;               // LQ*256 bf16
    float* ffB    = (float*)(obuf + (size_t)LQ * 256);   // LQ*256 f32 (spacer)
    ushort* Wq    = (ushort*)(ffB + (size_t)LQ * 256);   // 1344*256 bf16
    ushort* Wv    = Wq + 1344 * 256;
    ushort* Wo    = Wv + 256 * 256;
    ushort* Wf1   = Wo + 256 * 256;
    ushort* Wf2   = Wf1 + 1024 * 256;
    float* bq     = (float*)(Wf2 + 1024 * 256);          // 1344 f32
    // region reuse after deform:
    float* xF     = (float*)qout;                        // LQ*256 f32 (qout dead)
    ushort* xB16  = (ushort*)((float*)qout + (size_t)LQ * 256); // LQ*256 bf16
    ushort* hB16  = (ushort*)valueR;                     // LQ*1024 bf16 spans valueR..qb

    // ---- input conversions (2 launches) ----
    cvt_src_q<<<(LQ * 64 + 255) / 256, 256, 0, stream>>>(src, pos, srcb, qb, LQ * 64);
    CvtArgs ca;
    ca.s[0] = W_samp;  ca.d[0] = Wq;             ca.n[0] = 256 * 256;  ca.isbf[0] = 1;
    ca.s[1] = W_tsamp; ca.d[1] = Wq + 256 * 256; ca.n[1] = 640 * 256;  ca.isbf[1] = 1;
    ca.s[2] = W_attn;  ca.d[2] = Wq + 896 * 256; ca.n[2] = 448 * 256;  ca.isbf[2] = 1;
    ca.s[3] = W_val;   ca.d[3] = Wv;             ca.n[3] = 256 * 256;  ca.isbf[3] = 1;
    ca.s[4] = W_out;   ca.d[4] = Wo;             ca.n[4] = 256 * 256;  ca.isbf[4] = 1;
    ca.s[5] = W_ff1;   ca.d[5] = Wf1;            ca.n[5] = 1024 * 256; ca.isbf[5] = 1;
    ca.s[6] = W_ff2;   ca.d[6] = Wf2;            ca.n[6] = 256 * 1024; ca.isbf[6] = 1;
    ca.s[7] = b_samp;  ca.d[7] = bq;             ca.n[7] = 256;        ca.isbf[7] = 0;
    ca.s[8] = b_tsamp; ca.d[8] = bq + 256;       ca.n[8] = 640;        ca.isbf[8] = 0;
    ca.s[9] = b_attn;  ca.d[9] = bq + 896;       ca.n[9] = 448;        ca.isbf[9] = 0;
    ca.s[10] = b_attn; ca.d[10] = bq + 896;      ca.n[10] = 0;         ca.isbf[10] = 0;
    cvt_multi<<<dim3(1024, 11), 256, 0, stream>>>(ca);

    const int GM = (LQ + 127) / 128;   // 192

    // fused: value-proj + q-proj (bf16 out), 128x128 tiles, packed stores
    gemm_valq<<<dim3(13, GM), 256, 0, stream>>>(srcb, qb, Wv, Wq, b_val, bq, valb, qout);

    // deformable attention (bf16 out), 2 queries per block
    deform_kernel<<<LQ / 2, 256, 0, stream>>>(valb, qout, vr, obuf);

    // out-proj + residual + LN1 fused (writes xF f32 + xB16 bf16)
    gemm_ln<1><<<GM, 256, 0, stream>>>(obuf, Wo, b_out, src, n1g, n1b, xF, xB16, LQ, 256);

    // FFN: ff1 (relu, bf16 out, 128x128 tiles) ; ff2 + residual + LN2 -> d_out
    gemm_ff1<<<dim3(8, GM), 256, 0, stream>>>(xB16, Wf1, b_ff1, hB16);
    gemm_ln<0><<<GM, 256, 0, stream>>>(hB16, Wf2, b_ff2, xF, n2g, n2b, (float*)d_out, nullptr, LQ, 1024);
}

// Round 10
// 409.407 us; speedup vs baseline: 8.6742x; 1.0392x over previous
//
#include <hip/hip_runtime.h>
#include <hip/hip_bf16.h>
#include <math.h>

#define LQ 24480

typedef short bf16x8 __attribute__((ext_vector_type(8)));   // 8 bf16 = 16B
typedef float f32x4 __attribute__((ext_vector_type(4)));
typedef float f32x4v __attribute__((ext_vector_type(4)));
typedef float f32x2 __attribute__((ext_vector_type(2)));

static __device__ __forceinline__ float bf2f(ushort u) {
    union { unsigned int i; float f; } v; v.i = ((unsigned int)u) << 16; return v.f;
}
static __device__ __forceinline__ ushort f2bf(float f) {
    __hip_bfloat16 h = __float2bfloat16(f);
    return *reinterpret_cast<ushort*>(&h);
}
static __device__ __forceinline__ float u2f_lo(unsigned int u) {
    union { unsigned int i; float f; } v; v.i = u << 16; return v.f;
}
static __device__ __forceinline__ float u2f_hi(unsigned int u) {
    union { unsigned int i; float f; } v; v.i = u & 0xffff0000u; return v.f;
}
// (lo,hi) f32 pair from packed 2xbf16
static __device__ __forceinline__ f32x2 unpk(unsigned int u) {
    union { unsigned int i; float f; } lo, hi;
    lo.i = u << 16; hi.i = u & 0xffff0000u;
    f32x2 r; r.x = lo.f; r.y = hi.f; return r;
}
// acc += v * broadcast(w.lo)  [packed dual f32 FMA]
static __device__ __forceinline__ void pk_fma_lo(f32x2& acc, f32x2 v, f32x2 w) {
    asm("v_pk_fma_f32 %0, %1, %2, %0 op_sel:[0,0,0] op_sel_hi:[1,0,1]"
        : "+v"(acc) : "v"(v), "v"(w));
}
// acc += v * broadcast(w.hi)
static __device__ __forceinline__ void pk_fma_hi(f32x2& acc, f32x2 v, f32x2 w) {
    asm("v_pk_fma_f32 %0, %1, %2, %0 op_sel:[0,1,0] op_sel_hi:[1,1,1]"
        : "+v"(acc) : "v"(v), "v"(w));
}

// ---------------------------------------------------------------------------
// Fat-tile GEMM body: block 128x128, 4 waves in 2x2, wave tile 64x64.
// Column-permuted B fragments -> each thread owns 4 consecutive cols ->
// packed 8B bf16x4 stores.
// ---------------------------------------------------------------------------
template <int RELU>
static __device__ __forceinline__ void gemm_body128(
    const ushort* __restrict__ A, const ushort* __restrict__ W,
    const float* __restrict__ bias,
    ushort* __restrict__ Cb,
    int M, int N, int K, int bm, int bn, int wave, int lane)
{
    const int wm = wave >> 1, wn = wave & 1;
    const int r = lane & 15, kblk = lane >> 4;

    f32x4 acc[4][4] = {};

    const ushort* ap[4];
    const ushort* bp[4];
#pragma unroll
    for (int i = 0; i < 4; ++i) {
        int rr = min(bm + wm * 64 + i * 16 + r, M - 1);
        ap[i] = A + (size_t)rr * K + kblk * 8;
    }
    const int c0 = bn + wn * 64 + r * 4;     // first of this thread's 4 cols
#pragma unroll
    for (int j = 0; j < 4; ++j) {
        int cc = min(c0 + j, N - 1);
        bp[j] = W + (size_t)cc * K + kblk * 8;
    }

#pragma unroll 2
    for (int k = 0; k < K; k += 32) {
        bf16x8 a[4], b[4];
#pragma unroll
        for (int i = 0; i < 4; ++i) a[i] = *(const bf16x8*)(ap[i] + k);
#pragma unroll
        for (int j = 0; j < 4; ++j) b[j] = *(const bf16x8*)(bp[j] + k);
#pragma unroll
        for (int i = 0; i < 4; ++i)
#pragma unroll
            for (int j = 0; j < 4; ++j)
                acc[i][j] = __builtin_amdgcn_mfma_f32_16x16x32_bf16(a[i], b[j], acc[i][j], 0, 0, 0);
    }

    if (c0 >= N) return;
    const float4 bv = *(const float4*)(bias + c0);
    const int orow = kblk * 4;
#pragma unroll
    for (int i = 0; i < 4; ++i)
#pragma unroll
        for (int t = 0; t < 4; ++t) {
            int rr = bm + wm * 64 + i * 16 + orow + t;
            if (rr < M) {
                float v0 = acc[i][0][t] + bv.x;
                float v1 = acc[i][1][t] + bv.y;
                float v2 = acc[i][2][t] + bv.z;
                float v3 = acc[i][3][t] + bv.w;
                if (RELU) {
                    v0 = fmaxf(v0, 0.f); v1 = fmaxf(v1, 0.f);
                    v2 = fmaxf(v2, 0.f); v3 = fmaxf(v3, 0.f);
                }
                uint2 pk;
                pk.x = (unsigned)f2bf(v0) | ((unsigned)f2bf(v1) << 16);
                pk.y = (unsigned)f2bf(v2) | ((unsigned)f2bf(v3) << 16);
                *(uint2*)(Cb + (size_t)rr * N + c0) = pk;
            }
        }
}

// Fused value-proj (2 col-blocks -> valb) + q-proj (11 col-blocks -> qout).
__global__ __launch_bounds__(256) void gemm_valq(
    const ushort* __restrict__ srcb, const ushort* __restrict__ qb,
    const ushort* __restrict__ Wv, const ushort* __restrict__ Wq,
    const float* __restrict__ b_val, const float* __restrict__ bq,
    ushort* __restrict__ valb, ushort* __restrict__ qout)
{
    const int bx = blockIdx.x;   // 0..12
    if (bx < 2) {
        gemm_body128<0>(srcb, Wv, b_val, valb, LQ, 256, 256,
                        blockIdx.y * 128, bx * 128,
                        threadIdx.x >> 6, threadIdx.x & 63);
    } else {
        gemm_body128<0>(qb, Wq, bq, qout, LQ, 1344, 256,
                        blockIdx.y * 128, (bx - 2) * 128,
                        threadIdx.x >> 6, threadIdx.x & 63);
    }
}

// ff1: relu, bf16 out
__global__ __launch_bounds__(256) void gemm_ff1(
    const ushort* __restrict__ A, const ushort* __restrict__ W,
    const float* __restrict__ bias, ushort* __restrict__ Cb)
{
    gemm_body128<1>(A, W, bias, Cb, LQ, 1024, 256,
                    blockIdx.y * 128, blockIdx.x * 128,
                    threadIdx.x >> 6, threadIdx.x & 63);
}

// ---------------------------------------------------------------------------
// Fused GEMM (N=256) + residual + LayerNorm, column-permuted epilogue:
// each thread owns 16 consecutive columns. RES16: residual is bf16.
// WF32/WBF16 select output format.
// ---------------------------------------------------------------------------
template <int RES16, int WF32, int WBF16>
__global__ __launch_bounds__(256) void gemm_ln(
    const ushort* __restrict__ A, const ushort* __restrict__ W,
    const float* __restrict__ bias, const void* __restrict__ res,
    const float* __restrict__ g, const float* __restrict__ be,
    float* __restrict__ outF, ushort* __restrict__ outB,
    int M, int K)
{
    const int wave = threadIdx.x >> 6;
    const int lane = threadIdx.x & 63;
    const int r = lane & 15;
    const int kblk = lane >> 4;
    const int bm = blockIdx.x * 128;
    const int c0 = r * 16;                   // this thread's 16 columns

    f32x4 acc[2][16] = {};

    int row0 = bm + wave * 32 + r;
    int row1 = row0 + 16;
    row0 = min(row0, M - 1);
    row1 = min(row1, M - 1);
    const ushort* ap0 = A + (size_t)row0 * K + kblk * 8;
    const ushort* ap1 = A + (size_t)row1 * K + kblk * 8;
    const ushort* wp  = W + (size_t)c0 * K + kblk * 8;

#pragma unroll 2
    for (int k = 0; k < K; k += 32) {
        bf16x8 a0 = *(const bf16x8*)(ap0 + k);
        bf16x8 a1 = *(const bf16x8*)(ap1 + k);
#pragma unroll
        for (int ni = 0; ni < 16; ++ni) {
            bf16x8 b = *(const bf16x8*)(wp + (size_t)ni * K + k);
            acc[0][ni] = __builtin_amdgcn_mfma_f32_16x16x32_bf16(a0, b, acc[0][ni], 0, 0, 0);
            acc[1][ni] = __builtin_amdgcn_mfma_f32_16x16x32_bf16(a1, b, acc[1][ni], 0, 0, 0);
        }
    }

    const int orow = kblk * 4;

    float bv[16];
#pragma unroll
    for (int q = 0; q < 4; ++q)
        *(float4*)(bv + q * 4) = *(const float4*)(bias + c0 + q * 4);

    float mean_[2][4], rstd_[2][4];
#pragma unroll
    for (int mi = 0; mi < 2; ++mi)
#pragma unroll
        for (int j = 0; j < 4; ++j) {
            int rr = bm + wave * 32 + mi * 16 + orow + j;
            int rl = min(rr, M - 1);
            float rv[16];
            if (RES16) {
                const ushort* r16 = (const ushort*)res + (size_t)rl * 256 + c0;
                uint4 ra = *(const uint4*)r16;
                uint4 rb = *(const uint4*)(r16 + 8);
                unsigned ru[8] = {ra.x, ra.y, ra.z, ra.w, rb.x, rb.y, rb.z, rb.w};
#pragma unroll
                for (int b = 0; b < 8; ++b) {
                    rv[2 * b]     = u2f_lo(ru[b]);
                    rv[2 * b + 1] = u2f_hi(ru[b]);
                }
            } else {
                const float* rp = (const float*)res + (size_t)rl * 256 + c0;
#pragma unroll
                for (int q = 0; q < 4; ++q)
                    *(float4*)(rv + q * 4) = *(const float4*)(rp + q * 4);
            }
            float s = 0.f, s2 = 0.f;
#pragma unroll
            for (int ni = 0; ni < 16; ++ni) {
                float v = acc[mi][ni][j] + bv[ni] + rv[ni];
                acc[mi][ni][j] = v;
                s += v; s2 += v * v;
            }
#pragma unroll
            for (int off = 8; off; off >>= 1) {
                s  += __shfl_xor(s,  off, 16);
                s2 += __shfl_xor(s2, off, 16);
            }
            float mu = s * (1.f / 256.f);
            float var = s2 * (1.f / 256.f) - mu * mu;
            mean_[mi][j] = mu;
            rstd_[mi][j] = rsqrtf(var + 1e-5f);
        }

    float gv[16], bev[16];
#pragma unroll
    for (int q = 0; q < 4; ++q) {
        *(float4*)(gv + q * 4)  = *(const float4*)(g + c0 + q * 4);
        *(float4*)(bev + q * 4) = *(const float4*)(be + c0 + q * 4);
    }

#pragma unroll
    for (int mi = 0; mi < 2; ++mi)
#pragma unroll
        for (int j = 0; j < 4; ++j) {
            int rr = bm + wave * 32 + mi * 16 + orow + j;
            if (rr < M) {
                float o[16];
#pragma unroll
                for (int ni = 0; ni < 16; ++ni)
                    o[ni] = (acc[mi][ni][j] - mean_[mi][j]) * rstd_[mi][j] * gv[ni] + bev[ni];
                if (WF32) {
#pragma unroll
                    for (int q = 0; q < 4; ++q)
                        *(float4*)(outF + (size_t)rr * 256 + c0 + q * 4) = *(float4*)(o + q * 4);
                }
                if (WBF16) {
                    uint pk[8];
#pragma unroll
                    for (int b = 0; b < 8; ++b)
                        pk[b] = (unsigned)f2bf(o[2 * b]) | ((unsigned)f2bf(o[2 * b + 1]) << 16);
                    *(uint4*)(outB + (size_t)rr * 256 + c0)     = *(uint4*)pk;
                    *(uint4*)(outB + (size_t)rr * 256 + c0 + 8) = *(uint4*)(pk + 4);
                }
            }
        }
}

// ---------------------------------------------------------------------------
// src/q -> bf16 (vectorized), q = src + pos
// ---------------------------------------------------------------------------
__global__ __launch_bounds__(256) void cvt_src_q(
    const float* __restrict__ src, const float* __restrict__ pos,
    ushort* __restrict__ srcb, ushort* __restrict__ qb, int n4)
{
    int i = blockIdx.x * 256 + threadIdx.x;
    if (i >= n4) return;
    f32x4v s = *(const f32x4v*)(src + (size_t)i * 4);
    f32x4v p = *(const f32x4v*)(pos + (size_t)i * 4);
    ushort us[4], uq[4];
#pragma unroll
    for (int j = 0; j < 4; ++j) { us[j] = f2bf(s[j]); uq[j] = f2bf(s[j] + p[j]); }
    *(ulong1*)(srcb + (size_t)i * 4) = *(ulong1*)us;
    *(ulong1*)(qb   + (size_t)i * 4) = *(ulong1*)uq;
}

// weight conversions + bias concat in ONE launch: seg = blockIdx.y
struct CvtArgs { const float* s[11]; void* d[11]; int n[11]; int isbf[11]; };
__global__ __launch_bounds__(256) void cvt_multi(CvtArgs a)
{
    int seg = blockIdx.y;
    int i = blockIdx.x * 256 + threadIdx.x;
    if (i >= a.n[seg]) return;
    float v = a.s[seg][i];
    if (a.isbf[seg]) ((ushort*)a.d[seg])[i] = f2bf(v);
    else             ((float*)a.d[seg])[i]  = v;
}

// ---------------------------------------------------------------------------
// Deformable attention, phase-split, 2 queries/block, 2 channels/thread.
// Phase 2 uses v_pk_fma_f32 with op_sel weight broadcast (4 pk_fma/point).
// ---------------------------------------------------------------------------
__global__ __launch_bounds__(256) void deform_kernel(
    const ushort* __restrict__ valb,   // [LQ,256] bf16
    const ushort* __restrict__ qout,   // [LQ,1344] bf16: samp|tsamp|logits
    const float* __restrict__ vr,      // [4,2]
    ushort* __restrict__ ob)           // [LQ,256] bf16
{
    const int q0 = blockIdx.x * 2;
    const int tid = threadIdx.x;

    __shared__ int4   offs_s[2][448];
    __shared__ float4 wts_s[2][448];

    const int lsiA[4] = {0, 18432, 23040, 24192};

    // ---- phase 0: softmax -> wts_s[..].x ----
    {
        int grp = tid >> 4;
        int ql = grp >> 3, h = grp & 7;
        int ln = tid & 15;
        const ushort* lg = qout + (size_t)(q0 + ql) * 1344 + 896 + h * 56;
        float l0 = bf2f(lg[ln]);
        float l1 = bf2f(lg[16 + ln]);
        float l2 = bf2f(lg[32 + ln]);
        float l3 = (ln < 8) ? bf2f(lg[48 + ln]) : -1e30f;
        float m = fmaxf(fmaxf(l0, l1), fmaxf(l2, l3));
#pragma unroll
        for (int off = 8; off; off >>= 1) m = fmaxf(m, __shfl_xor(m, off, 16));
        float e0 = expf(l0 - m), e1 = expf(l1 - m), e2 = expf(l2 - m);
        float e3 = (ln < 8) ? expf(l3 - m) : 0.f;
        float s = e0 + e1 + e2 + e3;
#pragma unroll
        for (int off = 8; off; off >>= 1) s += __shfl_xor(s, off, 16);
        float inv = 1.f / s;
        wts_s[ql][h * 56 + ln].x      = e0 * inv;
        wts_s[ql][h * 56 + 16 + ln].x = e1 * inv;
        wts_s[ql][h * 56 + 32 + ln].x = e2 * inv;
        if (ln < 8) wts_s[ql][h * 56 + 48 + ln].x = e3 * inv;
    }

    // ---- hoisted per-query geometry (q0, q0+1 share the level) ----
    int lqv = (q0 >= 24192) ? 3 : (q0 >= 23040) ? 2 : (q0 >= 18432) ? 1 : 0;
    int Wqv = 64 >> lqv, Hqv = 48 >> lqv;
    int slq = lsiA[lqv];
    float vrxq = vr[2 * lqv], vryq = vr[2 * lqv + 1];
    float rxb0, ryb0, rxb1, ryb1; int tq0, tq1;
    {
        int qi = q0 - slq;
        int iy = qi >> (6 - lqv);
        int jx = qi & (Wqv - 1);
        tq0 = iy / Hqv;
        rxb0 = ((float)jx + 0.5f) / (vrxq * (float)Wqv);
        ryb0 = ((float)iy + 0.5f) / (vryq * (float)(Hqv * 6));
        qi += 1;
        iy = qi >> (6 - lqv);
        jx = qi & (Wqv - 1);
        tq1 = iy / Hqv;
        rxb1 = ((float)jx + 0.5f) / (vrxq * (float)Wqv);
        ryb1 = ((float)iy + 0.5f) / (vryq * (float)(Hqv * 6));
    }
    __syncthreads();

    // ---- phase 1: coords for 2x448 items ----
    for (int it = tid; it < 896; it += 256) {
        int ql = (it >= 448) ? 1 : 0;
        int item = it - ql * 448;
        float rx_base = ql ? rxb1 : rxb0;
        float ry_base = ql ? ryb1 : ryb0;
        int tq = ql ? tq1 : tq0;

        int h = item / 56;
        int p = item - h * 56;
        int l = p / 14;
        int pp = p - l * 14;

        int Wl = 64 >> l;
        int Hl = 48 >> l;
        int Htl = Hl * 6;
        float vrx = vr[2 * l], vry = vr[2 * l + 1];

        float aw = wts_s[ql][item].x;

        const ushort* qrow = qout + (size_t)(q0 + ql) * 1344;
        float ox, oy, ty;
        if (pp < 4) {
            ox = bf2f(qrow[h * 32 + l * 8 + pp * 2]);
            oy = bf2f(qrow[h * 32 + l * 8 + pp * 2 + 1]);
            ty = 0.f;
        } else {
            int pq = pp - 4;
            int tw = pq >> 1, nt = pq & 1;
            int tt = (tw < tq) ? tw : tw + 1;
            ty = (float)(tt - tq) * vry * (float)Hl;
            ox = bf2f(qrow[256 + h * 80 + l * 20 + tw * 4 + nt * 2]);
            oy = bf2f(qrow[256 + h * 80 + l * 20 + tw * 4 + nt * 2 + 1]);
        }
        float x = rx_base * vrx * (float)Wl - 0.5f + ox;
        float y = ry_base * vry * (float)Htl - 0.5f + ty + oy;
        float x0f = floorf(x), y0f = floorf(y);
        int x0 = (int)x0f, y0 = (int)y0f;
        float fx = x - x0f, fy = y - y0f;

        int xi0 = min(max(x0, 0), Wl - 1);
        int xi1 = min(max(x0 + 1, 0), Wl - 1);
        int yi0 = min(max(y0, 0), Htl - 1);
        int yi1 = min(max(y0 + 1, 0), Htl - 1);
        float mx0 = (x0 >= 0 && x0 < Wl) ? 1.f : 0.f;
        float mx1 = (x0 >= -1 && x0 + 1 < Wl) ? 1.f : 0.f;
        float my0 = (y0 >= 0 && y0 < Htl) ? 1.f : 0.f;
        float my1 = (y0 >= -1 && y0 + 1 < Htl) ? 1.f : 0.f;

        float gx0 = (1.f - fx) * mx0;
        float gx1 = fx * mx1;
        float gy0 = (1.f - fy) * my0 * aw;
        float gy1 = fy * my1 * aw;

        int sl = lsiA[l];
        // BYTE offsets into valb (row = 256 bf16 = 512 B)
        int rb0 = (sl + yi0 * Wl) * 512;
        int rb1 = (sl + yi1 * Wl) * 512;
        offs_s[ql][item] = make_int4(rb0 + xi0 * 512, rb0 + xi1 * 512,
                                     rb1 + xi0 * 512, rb1 + xi1 * 512);
        wts_s[ql][item] = make_float4(gy0 * gx0, gy0 * gx1, gy1 * gx0, gy1 * gx1);
    }
    __syncthreads();

    // ---- phase 2: gather 2 channels per thread, packed FMA ----
    const int ql = tid >> 7;
    const int h = (tid >> 4) & 7;
    const int c2 = tid & 15;
    const unsigned laneByte = (unsigned)(h * 64 + c2 * 4);
    const char* vbase = (const char*)valb;
    const int4* op = offs_s[ql] + h * 56;
    const f32x2* wp2 = (const f32x2*)(wts_s[ql] + h * 56);   // 2 pairs per item
    f32x2 acc; acc.x = 0.f; acc.y = 0.f;
#pragma unroll 8
    for (int p = 0; p < 56; ++p) {
        int4 o4 = op[p];
        f32x2 wA = wp2[2 * p];
        f32x2 wB = wp2[2 * p + 1];
        unsigned int u0 = *(const unsigned int*)(vbase + (size_t)(unsigned)(o4.x + laneByte));
        unsigned int u1 = *(const unsigned int*)(vbase + (size_t)(unsigned)(o4.y + laneByte));
        unsigned int u2 = *(const unsigned int*)(vbase + (size_t)(unsigned)(o4.z + laneByte));
        unsigned int u3 = *(const unsigned int*)(vbase + (size_t)(unsigned)(o4.w + laneByte));
        pk_fma_lo(acc, unpk(u0), wA);   // * wA.lo = w00
        pk_fma_hi(acc, unpk(u1), wA);   // * wA.hi = w10
        pk_fma_lo(acc, unpk(u2), wB);   // * wB.lo = w01
        pk_fma_hi(acc, unpk(u3), wB);   // * wB.hi = w11
    }
    unsigned int packed = (unsigned int)f2bf(acc.x) | ((unsigned int)f2bf(acc.y) << 16);
    *(unsigned int*)(ob + (size_t)(q0 + ql) * 256 + h * 32 + c2 * 2) = packed;
}

// ---------------------------------------------------------------------------
extern "C" void kernel_launch(void* const* d_in, const int* in_sizes, int n_in,
                              void* d_out, int out_size, void* d_ws, size_t ws_size,
                              hipStream_t stream)
{
    const float* src    = (const float*)d_in[0];
    const float* pos    = (const float*)d_in[1];
    const float* vr     = (const float*)d_in[4];
    const float* W_samp = (const float*)d_in[5];
    const float* b_samp = (const float*)d_in[6];
    const float* W_tsamp= (const float*)d_in[7];
    const float* b_tsamp= (const float*)d_in[8];
    const float* W_attn = (const float*)d_in[9];
    const float* b_attn = (const float*)d_in[10];
    const float* W_val  = (const float*)d_in[11];
    const float* b_val  = (const float*)d_in[12];
    const float* W_out  = (const float*)d_in[13];
    const float* b_out  = (const float*)d_in[14];
    const float* W_ff1  = (const float*)d_in[15];
    const float* b_ff1  = (const float*)d_in[16];
    const float* W_ff2  = (const float*)d_in[17];
    const float* b_ff2  = (const float*)d_in[18];
    const float* n1g    = (const float*)d_in[19];
    const float* n1b    = (const float*)d_in[20];
    const float* n2g    = (const float*)d_in[21];
    const float* n2b    = (const float*)d_in[22];

    // ---- workspace layout (f32 units) ----
    float* ws = (float*)d_ws;
    ushort* qout  = (ushort*)ws;                         // LQ*1344 bf16
    float* valueR = ws + (size_t)LQ * 672;               // region: LQ*256 f32
    ushort* valb  = (ushort*)valueR;                     // LQ*256 bf16
    ushort* srcb  = (ushort*)(valueR + (size_t)LQ * 256);// LQ*256 bf16
    ushort* qb    = srcb + (size_t)LQ * 256;             // LQ*256 bf16
    ushort* obuf  = qb + (size_t)LQ * 256;               // LQ*256 bf16
    float* ffB    = (float*)(obuf + (size_t)LQ * 256);   // LQ*256 f32 (spacer)
    ushort* Wq    = (ushort*)(ffB + (size_t)LQ * 256);   // 1344*256 bf16
    ushort* Wv    = Wq + 1344 * 256;
    ushort* Wo    = Wv + 256 * 256;
    ushort* Wf1   = Wo + 256 * 256;
    ushort* Wf2   = Wf1 + 1024 * 256;
    float* bq     = (float*)(Wf2 + 1024 * 256);          // 1344 f32
    // region reuse after deform:
    ushort* xB16  = (ushort*)qout;                       // LQ*256 bf16 (qout dead)
    ushort* hB16  = (ushort*)valueR;                     // LQ*1024 bf16 spans valueR..qb

    // ---- input conversions (2 launches) ----
    cvt_src_q<<<(LQ * 64 + 255) / 256, 256, 0, stream>>>(src, pos, srcb, qb, LQ * 64);
    CvtArgs ca;
    ca.s[0] = W_samp;  ca.d[0] = Wq;             ca.n[0] = 256 * 256;  ca.isbf[0] = 1;
    ca.s[1] = W_tsamp; ca.d[1] = Wq + 256 * 256; ca.n[1] = 640 * 256;  ca.isbf[1] = 1;
    ca.s[2] = W_attn;  ca.d[2] = Wq + 896 * 256; ca.n[2] = 448 * 256;  ca.isbf[2] = 1;
    ca.s[3] = W_val;   ca.d[3] = Wv;             ca.n[3] = 256 * 256;  ca.isbf[3] = 1;
    ca.s[4] = W_out;   ca.d[4] = Wo;             ca.n[4] = 256 * 256;  ca.isbf[4] = 1;
    ca.s[5] = W_ff1;   ca.d[5] = Wf1;            ca.n[5] = 1024 * 256; ca.isbf[5] = 1;
    ca.s[6] = W_ff2;   ca.d[6] = Wf2;            ca.n[6] = 256 * 1024; ca.isbf[6] = 1;
    ca.s[7] = b_samp;  ca.d[7] = bq;             ca.n[7] = 256;        ca.isbf[7] = 0;
    ca.s[8] = b_tsamp; ca.d[8] = bq + 256;       ca.n[8] = 640;        ca.isbf[8] = 0;
    ca.s[9] = b_attn;  ca.d[9] = bq + 896;       ca.n[9] = 448;        ca.isbf[9] = 0;
    ca.s[10] = b_attn; ca.d[10] = bq + 896;      ca.n[10] = 0;         ca.isbf[10] = 0;
    cvt_multi<<<dim3(1024, 11), 256, 0, stream>>>(ca);

    const int GM = (LQ + 127) / 128;   // 192

    // fused: value-proj + q-proj (bf16 out), 128x128 tiles, packed stores
    gemm_valq<<<dim3(13, GM), 256, 0, stream>>>(srcb, qb, Wv, Wq, b_val, bq, valb, qout);

    // deformable attention (bf16 out), 2 queries per block
    deform_kernel<<<LQ / 2, 256, 0, stream>>>(valb, qout, vr, obuf);

    // out-proj + residual(src f32) + LN1 -> xB16 (bf16 only)
    gemm_ln<0, 0, 1><<<GM, 256, 0, stream>>>(obuf, Wo, b_out, src, n1g, n1b,
                                             nullptr, xB16, LQ, 256);

    // FFN: ff1 (relu, bf16 out) ; ff2 + residual(xB16 bf16) + LN2 -> d_out f32
    gemm_ff1<<<dim3(8, GM), 256, 0, stream>>>(xB16, Wf1, b_ff1, hB16);
    gemm_ln<1, 1, 0><<<GM, 256, 0, stream>>>(hB16, Wf2, b_ff2, xB16, n2g, n2b,
                                             (float*)d_out, nullptr, LQ, 1024);
}